// Round 1
// baseline (2381.765 us; speedup 1.0000x reference)
//
#include <hip/hip_runtime.h>
#include <hip/hip_bf16.h>
#include <cstdint>

typedef float v4f __attribute__((ext_vector_type(4)));
typedef short v8s __attribute__((ext_vector_type(8)));
typedef unsigned short u16;

#define N_SEQ 2048
#define D_MODEL 512
#define N_LAYER 6
#define N_HEAD 8
#define D_HEAD 64
#define M_FEAT 266
#define M_PAD 288
#define M_ALLOC 384
#define FF_DIM 2048
#define BATCH 4
#define ROWS 8192
#define BHN 65536   // B*H*N

__device__ __forceinline__ float b2f(u16 u) {
  return __uint_as_float(((uint32_t)u) << 16);
}
__device__ __forceinline__ u16 f2b(float f) {
  union { __hip_bfloat16 h; u16 u; } c;
  c.h = __float2bfloat16(f);
  return c.u;
}
__device__ __forceinline__ float wave_sum(float v) {
#pragma unroll
  for (int o = 1; o < 64; o <<= 1) v += __shfl_xor(v, o);
  return v;
}
__device__ __forceinline__ float wave_max(float v) {
#pragma unroll
  for (int o = 1; o < 64; o <<= 1) v = fmaxf(v, __shfl_xor(v, o));
  return v;
}

__device__ __forceinline__ void mfma_bf16(v4f& d, v8s a, v8s b) {
  asm volatile("v_mfma_f32_16x16x32_bf16 %0, %1, %2, %0" : "+v"(d) : "v"(a), "v"(b));
}

// ---------------------------------------------------------------------------
// Generic GEMM:  C[M x N] = A[M x K] * B^T   (B stored as [N x K], both bf16)
// 128x128 tile, BK=32, 256 threads (4 waves, 2x2 of 64x64), reg-staged LDS.
// EPI: 0 = plain bf16 out; 1 = f32 * scale with col<Ncap,row<Mcap masks;
//      2 = f32 residual += acc + bias; 3 = bf16 gelu(acc+bias);
//      4 = bf16 head-scatter o[(b*N+row)*512 + h*64 + col], col<64.
// ---------------------------------------------------------------------------
template <int EPI>
__global__ void __launch_bounds__(256, 2)
gemm_bt(const u16* __restrict__ A, const u16* __restrict__ B,
        void* __restrict__ Cv, const float* __restrict__ bias,
        int K, int ldc, long long sA, long long sB, long long sC,
        float scale, int Ncap, int Mcap)
{
  __shared__ u16 As[128 * 32];
  __shared__ u16 Bs[128 * 32];
  const int z = blockIdx.z;
  const u16* Ag = A + (long long)z * sA;
  const u16* Bg = B + (long long)z * sB;
  const int t = threadIdx.x;
  const int lane = t & 63;
  const int w = t >> 6;
  const int wm = (w >> 1) << 6, wn = (w & 1) << 6;
  const int tiM = blockIdx.x << 7, tiN = blockIdx.y << 7;

  const int lrow = t >> 1;
  const int lcol = (t & 1) << 4;
  const u16* Ap = Ag + (long long)(tiM + lrow) * K + lcol;
  const u16* Bp = Bg + (long long)(tiN + lrow) * K + lcol;
  u16* Asw = &As[lrow * 32 + lcol];
  u16* Bsw = &Bs[lrow * 32 + lcol];

  const int rr = lane & 15;
  const int kc = (lane >> 4) << 3;
  const u16* Asr = &As[(wm + rr) * 32 + kc];
  const u16* Bsr = &Bs[(wn + rr) * 32 + kc];

  v4f acc[4][4] = {};

  for (int k0 = 0; k0 < K; k0 += 32) {
    v8s a0 = *(const v8s*)(Ap + k0);
    v8s a1 = *(const v8s*)(Ap + k0 + 8);
    v8s b0 = *(const v8s*)(Bp + k0);
    v8s b1 = *(const v8s*)(Bp + k0 + 8);
    __syncthreads();
    *(v8s*)(Asw) = a0; *(v8s*)(Asw + 8) = a1;
    *(v8s*)(Bsw) = b0; *(v8s*)(Bsw + 8) = b1;
    __syncthreads();
    v8s af[4], bf[4];
#pragma unroll
    for (int i = 0; i < 4; i++) af[i] = *(const v8s*)(Asr + i * 16 * 32);
#pragma unroll
    for (int i = 0; i < 4; i++) bf[i] = *(const v8s*)(Bsr + i * 16 * 32);
#pragma unroll
    for (int fm = 0; fm < 4; fm++)
#pragma unroll
      for (int fn = 0; fn < 4; fn++)
        mfma_bf16(acc[fm][fn], af[fm], bf[fn]);
  }

  // hazard cushion: MFMA results -> VALU epilogue
  __builtin_amdgcn_sched_barrier(0);
  asm volatile("s_nop 7\ns_nop 7\ns_nop 7");
  __builtin_amdgcn_sched_barrier(0);

  const int r4 = (lane >> 4) << 2;
  const int cc = lane & 15;
#pragma unroll
  for (int fm = 0; fm < 4; fm++)
#pragma unroll
    for (int fn = 0; fn < 4; fn++)
#pragma unroll
      for (int i = 0; i < 4; i++) {
        int row = tiM + wm + fm * 16 + r4 + i;
        int col = tiN + wn + fn * 16 + cc;
        float v = acc[fm][fn][i];
        if (EPI == 0) {
          ((u16*)Cv)[(long long)z * sC + (long long)row * ldc + col] = f2b(v);
        } else if (EPI == 1) {
          if (col < Ncap && row < Mcap)
            ((float*)Cv)[(long long)z * sC + (long long)row * ldc + col] = v * scale;
        } else if (EPI == 2) {
          long long idx = (long long)row * ldc + col;
          float bb = bias ? bias[col] : 0.0f;
          ((float*)Cv)[idx] += v + bb;
        } else if (EPI == 3) {
          float hv = v + bias[col];
          float gg = 0.5f * hv * (1.0f + erff(hv * 0.70710678118f));
          ((u16*)Cv)[(long long)row * ldc + col] = f2b(gg);
        } else {  // EPI == 4
          if (col < 64) {
            int b_ = z >> 3, h_ = z & 7;
            ((u16*)Cv)[(long long)(b_ * N_SEQ + row) * 512 + h_ * 64 + col] = f2b(v);
          }
        }
      }
}

// ---------------------------------------------------------------------------
// LayerNorm over D=512, one wave per row.
// ---------------------------------------------------------------------------
template <bool F32OUT>
__global__ void ln_kernel(const float* __restrict__ x, const float* __restrict__ g,
                          const float* __restrict__ b, void* __restrict__ out)
{
  const int row = blockIdx.x;
  const int t = threadIdx.x;  // 64
  const float* xr = x + (long long)row * D_MODEL + t * 8;
  v4f v0 = *(const v4f*)xr;
  v4f v1 = *(const v4f*)(xr + 4);
  float s = v0[0] + v0[1] + v0[2] + v0[3] + v1[0] + v1[1] + v1[2] + v1[3];
  float sq = v0[0]*v0[0] + v0[1]*v0[1] + v0[2]*v0[2] + v0[3]*v0[3]
           + v1[0]*v1[0] + v1[1]*v1[1] + v1[2]*v1[2] + v1[3]*v1[3];
  s = wave_sum(s);
  sq = wave_sum(sq);
  float mu = s * (1.0f / D_MODEL);
  float var = sq * (1.0f / D_MODEL) - mu * mu;
  float rstd = rsqrtf(var + 1e-5f);
  v4f g0 = *(const v4f*)(g + t * 8), g1 = *(const v4f*)(g + t * 8 + 4);
  v4f bb0 = *(const v4f*)(b + t * 8), bb1 = *(const v4f*)(b + t * 8 + 4);
  float y[8];
#pragma unroll
  for (int j = 0; j < 4; j++) y[j] = (v0[j] - mu) * rstd * g0[j] + bb0[j];
#pragma unroll
  for (int j = 0; j < 4; j++) y[4 + j] = (v1[j] - mu) * rstd * g1[j] + bb1[j];
  if (F32OUT) {
    float* op = (float*)out + (long long)row * D_MODEL + t * 8;
    v4f o0 = {y[0], y[1], y[2], y[3]}, o1 = {y[4], y[5], y[6], y[7]};
    *(v4f*)op = o0;
    *(v4f*)(op + 4) = o1;
  } else {
    u16* op = (u16*)out + (long long)row * D_MODEL + t * 8;
    alignas(16) u16 tmp[8];
#pragma unroll
    for (int j = 0; j < 8; j++) tmp[j] = f2b(y[j]);
    *(v8s*)op = *(v8s*)tmp;
  }
}

// x = x_in + fixed_pos_emb(N, D)
__global__ void posadd(const float* __restrict__ xin, float* __restrict__ x)
{
  long long i = (long long)blockIdx.x * 256 + threadIdx.x;  // 4*2048*512
  int d = (int)(i & 511);
  int n = (int)((i >> 9) & 2047);
  int j = d & 255;
  float sarg = (float)n * expf(-0.035977892f * (float)j);  // 10000^(-2j/512)
  float pe = (d < 256) ? sinf(sarg) : cosf(sarg);
  x[i] = xin[i] + pe;
}

// rotary sin/cos tables: per (n, j<32)
__global__ void rotab(float* __restrict__ ts, float* __restrict__ tc)
{
  int i = blockIdx.x * 64 + threadIdx.x;  // 2048*32
  int n = i >> 5, j = i & 31;
  float sarg = (float)n * expf(-0.28782314f * (float)j);  // 10000^(-2j/64)
  float s, c;
  sincosf(sarg, &s, &c);
  ts[i] = s;
  tc[i] = c;
}

// rotary on q,k + diag; reads qkv_pre (B,N,1536) bf16 -> q_rot,k_rot (b,h,n,64)
__global__ void rotary_kernel(const u16* __restrict__ qkv,
                              const float* __restrict__ ts, const float* __restrict__ tc,
                              u16* __restrict__ qr, u16* __restrict__ kr,
                              float* __restrict__ dq, float* __restrict__ dk)
{
  int bid = blockIdx.x;  // ((b*8+h)*2048+n)
  int n = bid & 2047;
  int h = (bid >> 11) & 7;
  int b = bid >> 14;
  int t = threadIdx.x;  // 64
  long long src = ((long long)(b * N_SEQ + n)) * 1536 + h * 64 + t;
  float qv = b2f(qkv[src]);
  float kv = b2f(qkv[src + 512]);
  int j = t >> 1;
  float sn = ts[n * 32 + j], cn = tc[n * 32 + j];
  float qp = __shfl_xor(qv, 1), kp = __shfl_xor(kv, 1);
  float qrv = (t & 1) ? (qv * cn + qp * sn) : (qv * cn - qp * sn);
  float krv = (t & 1) ? (kv * cn + kp * sn) : (kv * cn - kp * sn);
  u16 qb = f2b(qrv), kb = f2b(krv);
  long long dst = ((long long)bid) * 64 + t;
  qr[dst] = qb;
  kr[dst] = kb;
  float q2 = b2f(qb); q2 *= q2;
  float k2 = b2f(kb); k2 *= k2;
  q2 = wave_sum(q2);
  k2 = wave_sum(k2);
  if (t == 0) { dq[bid] = q2 * 0.0625f; dk[bid] = k2 * 0.0625f; }  // 0.5 * 64^-0.5
}

// v transpose: qkv_pre (b,n,h,dh) -> vT (b,h,dh,n) bf16
__global__ void vtrans(const u16* __restrict__ qkv, u16* __restrict__ vT)
{
  int bid = blockIdx.x;  // B*H*32
  int nt = bid & 31;
  int h = (bid >> 5) & 7;
  int b = bid >> 8;
  __shared__ u16 st[64][72];
  int t = threadIdx.x;  // 256
  int r = t >> 2, c = (t & 3) << 4;
  long long src = ((long long)(b * N_SEQ + nt * 64 + r)) * 1536 + 1024 + h * 64 + c;
  *(v8s*)&st[r][c] = *(const v8s*)(qkv + src);
  *(v8s*)&st[r][c + 8] = *(const v8s*)(qkv + src + 8);
  __syncthreads();
  alignas(16) u16 tmp[16];
#pragma unroll
  for (int jj = 0; jj < 16; jj++) tmp[jj] = st[c + jj][r];
  long long dst = ((long long)((b * 8 + h) * 64 + r)) * N_SEQ + nt * 64 + c;
  *(v8s*)(vT + dst) = *(v8s*)&tmp[0];
  *(v8s*)(vT + dst + 8) = *(v8s*)&tmp[8];
}

// weight transpose + bf16: src (l, Ks, Ns) f32 -> dst (l, Ns, Ks) bf16
__global__ void wtrans(const float* __restrict__ src, u16* __restrict__ dst,
                       int Ks, int Ns, long long sSrc, long long sDst)
{
  int l = blockIdx.z;
  src += (long long)l * sSrc;
  dst += (long long)l * sDst;
  int n0 = blockIdx.x << 6, k0 = blockIdx.y << 6;
  __shared__ float st[64][68];
  int t = threadIdx.x;
  int r = t >> 2, c = (t & 3) << 4;
  const float* sp = src + (long long)(k0 + r) * Ns + n0 + c;
#pragma unroll
  for (int jj = 0; jj < 16; jj += 4) *(v4f*)&st[r][c + jj] = *(const v4f*)(sp + jj);
  __syncthreads();
  alignas(16) u16 tmp[16];
#pragma unroll
  for (int jj = 0; jj < 16; jj++) tmp[jj] = f2b(st[c + jj][r]);
  u16* dp = dst + (long long)(n0 + r) * Ks + k0 + c;
  *(v8s*)(dp) = *(v8s*)&tmp[0];
  *(v8s*)(dp + 8) = *(v8s*)&tmp[8];
}

// proj (l, 266, 64) f32 -> (l, 384, 64) bf16, zero-padded rows
__global__ void projconv(const float* __restrict__ proj, u16* __restrict__ out)
{
  int i = blockIdx.x * 256 + threadIdx.x;  // 6*384*64
  int dh = i & 63;
  int m = (i >> 6) % M_ALLOC;
  int l = i / (M_ALLOC * 64);
  float v = (m < M_FEAT) ? proj[((long long)l * M_FEAT + m) * 64 + dh] : 0.0f;
  out[i] = f2b(v);
}

__global__ void kmax1(const float* __restrict__ dd, float* __restrict__ part)
{
  const long long total = (long long)32 * N_SEQ * M_PAD;
  float m = -3e38f;
  for (long long i = (long long)blockIdx.x * 256 + threadIdx.x; i < total;
       i += (long long)gridDim.x * 256)
    m = fmaxf(m, dd[i]);
  m = wave_max(m);
  __shared__ float sm[4];
  if ((threadIdx.x & 63) == 0) sm[threadIdx.x >> 6] = m;
  __syncthreads();
  if (threadIdx.x == 0)
    part[blockIdx.x] = fmaxf(fmaxf(sm[0], sm[1]), fmaxf(sm[2], sm[3]));
}

__global__ void kmax2(const float* __restrict__ part, float* __restrict__ kmax)
{
  float m = -3e38f;
  for (int i = threadIdx.x; i < 2048; i += 256) m = fmaxf(m, part[i]);
  m = wave_max(m);
  __shared__ float sm[4];
  if ((threadIdx.x & 63) == 0) sm[threadIdx.x >> 6] = m;
  __syncthreads();
  if (threadIdx.x == 0) kmax[0] = fmaxf(fmaxf(sm[0], sm[1]), fmaxf(sm[2], sm[3]));
}

// kf transpose-prep: dd_k (bh,n,288) f32 -> kfT (bh,384,2048) bf16 (rows>=288 skipped)
__global__ void kfprep(const float* __restrict__ dd, const float* __restrict__ diag,
                       const float* __restrict__ kmax, u16* __restrict__ kfT)
{
  int bh = blockIdx.z;
  int n0 = blockIdx.x << 6;
  int m0 = blockIdx.y << 6;
  __shared__ u16 st[64][72];
  float km = kmax[0];
  int t = threadIdx.x;
  int r = t >> 2, c = (t & 3) << 4;
  const float* dp = dd + ((long long)bh * N_SEQ + n0 + r) * M_PAD + m0 + c;
  float dg = diag[(long long)bh * N_SEQ + n0 + r];
#pragma unroll
  for (int jj = 0; jj < 16; jj++) {
    int m = m0 + c + jj;
    float kf = 0.0f;
    if (m < M_FEAT) kf = 0.06131389f * (expf(dp[jj] - dg - km) + 1e-4f);
    st[c + jj][r] = f2b(kf);
  }
  __syncthreads();
  int mr = t >> 2, nc = (t & 3) << 4;
  if (m0 + mr < M_PAD) {
    alignas(16) u16 tmp[16];
#pragma unroll
    for (int jj = 0; jj < 16; jj++) tmp[jj] = st[mr][nc + jj];
    u16* op = kfT + ((long long)bh * M_ALLOC + m0 + mr) * N_SEQ + n0 + nc;
    *(v8s*)op = *(v8s*)&tmp[0];
    *(v8s*)(op + 8) = *(v8s*)&tmp[8];
  }
}

// ksum[bh][m] = sum_n kfT[bh][m][n]
__global__ void ksumk(const u16* __restrict__ kfT, float* __restrict__ ksum)
{
  int bid = blockIdx.x;  // 32*288
  int bh = bid / M_PAD, m = bid % M_PAD;
  const u16* p = kfT + ((long long)bh * M_ALLOC + m) * N_SEQ;
  int t = threadIdx.x;  // 64
  float s = 0.0f;
#pragma unroll
  for (int j = 0; j < 4; j++) {
    v8s v = *(const v8s*)(p + j * 512 + t * 8);
#pragma unroll
    for (int e = 0; e < 8; e++) s += b2f((u16)v[e]);
  }
  s = wave_sum(s);
  if (t == 0) ksum[bid] = s;
}

// qf prep: row max, denominator, write qf*dinv as bf16 (bh,n,288)
__global__ void qfprep(const float* __restrict__ dd, const float* __restrict__ diag,
                       const float* __restrict__ ksum, u16* __restrict__ qf)
{
  int bid = blockIdx.x;  // 32*2048
  int bh = bid >> 11;
  int t = threadIdx.x;  // 64
  const float* rowp = dd + (long long)bid * M_PAD;
  float dg = diag[bid];
  const float* ks = ksum + bh * M_PAD;
  float vals[5];
  float mx = -3e38f;
  int cnt = 0;
  for (int m = t; m < M_FEAT; m += 64) {
    float v = rowp[m];
    vals[cnt++] = v;
    mx = fmaxf(mx, v);
  }
  mx = wave_max(mx);
  float ss = 0.0f;
  cnt = 0;
  for (int m = t; m < M_FEAT; m += 64) {
    float e = 0.06131389f * (expf(vals[cnt] - dg - mx) + 1e-4f);
    vals[cnt++] = e;
    ss += e * ks[m];
  }
  ss = wave_sum(ss);
  float dinv = 1.0f / ss;
  u16* op = qf + (long long)bid * M_PAD;
  cnt = 0;
  for (int m = t; m < M_PAD; m += 64) {
    float v = 0.0f;
    if (m < M_FEAT) v = vals[cnt++] * dinv;
    op[m] = f2b(v);
  }
}

// ctx (bh,288,64) f32 -> ctxT (bh,64,288) bf16
__global__ void ctxtrans(const float* __restrict__ ctx, u16* __restrict__ ctxT)
{
  int i = blockIdx.x * 256 + threadIdx.x;  // 32*288*64
  int e = i & 63;
  int m = (i >> 6) % M_PAD;
  int bh = i / (M_PAD * 64);
  ctxT[((long long)bh * 64 + e) * M_PAD + m] = f2b(ctx[i]);
}

// ---------------------------------------------------------------------------
extern "C" void kernel_launch(void* const* d_in, const int* in_sizes, int n_in,
                              void* d_out, int out_size, void* d_ws, size_t ws_size,
                              hipStream_t stream)
{
  const float* x_in = (const float*)d_in[0];
  const float* Wq  = (const float*)d_in[1];
  const float* Wk  = (const float*)d_in[2];
  const float* Wv  = (const float*)d_in[3];
  const float* Wo  = (const float*)d_in[4];
  const float* Pr  = (const float*)d_in[5];
  const float* ln1g = (const float*)d_in[6];
  const float* ln1b = (const float*)d_in[7];
  const float* W1  = (const float*)d_in[8];
  const float* b1  = (const float*)d_in[9];
  const float* W2  = (const float*)d_in[10];
  const float* b2  = (const float*)d_in[11];
  const float* ln2g = (const float*)d_in[12];
  const float* ln2b = (const float*)d_in[13];
  const float* lnfg = (const float*)d_in[14];
  const float* lnfb = (const float*)d_in[15];

  char* ws = (char*)d_ws;
  size_t off = 0;
  auto alloc = [&](size_t bytes) -> void* {
    void* p = ws + off;
    off = (off + bytes + 255) & ~(size_t)255;
    return p;
  };

  float* x      = (float*)alloc((size_t)ROWS * D_MODEL * 4);          // residual stream
  float* tsin   = (float*)alloc((size_t)N_SEQ * 32 * 4);
  float* tcos   = (float*)alloc((size_t)N_SEQ * 32 * 4);
  u16*   wqkvT  = (u16*)alloc((size_t)N_LAYER * 1536 * 512 * 2);
  u16*   woT    = (u16*)alloc((size_t)N_LAYER * 512 * 512 * 2);
  u16*   w1T    = (u16*)alloc((size_t)N_LAYER * 2048 * 512 * 2);
  u16*   w2T    = (u16*)alloc((size_t)N_LAYER * 512 * 2048 * 2);
  u16*   projT  = (u16*)alloc((size_t)N_LAYER * M_ALLOC * 64 * 2);
  u16*   hbuf   = (u16*)alloc((size_t)ROWS * D_MODEL * 2);
  u16*   obuf   = (u16*)alloc((size_t)ROWS * D_MODEL * 2);
  float* big    = (float*)alloc((size_t)32 * N_SEQ * M_PAD * 4);      // qkv_pre / dd / ff union
  u16*   qrbuf  = (u16*)alloc((size_t)BHN * 64 * 2);
  u16*   krbuf  = (u16*)alloc((size_t)BHN * 64 * 2);
  u16*   vTbuf  = (u16*)alloc((size_t)BHN * 64 * 2);
  float* diagq  = (float*)alloc((size_t)BHN * 4);
  float* diagk  = (float*)alloc((size_t)BHN * 4);
  float* kpart  = (float*)alloc(2048 * 4);
  float* kmaxb  = (float*)alloc(256);
  u16*   kfT    = (u16*)alloc((size_t)32 * M_ALLOC * N_SEQ * 2);      // also qf buffer
  float* ctxb   = (float*)alloc((size_t)32 * M_PAD * 64 * 4);
  u16*   ctxT   = (u16*)alloc((size_t)32 * 64 * M_PAD * 2);
  float* ksum   = (float*)alloc((size_t)32 * M_PAD * 4);
  (void)alloc(1 << 20);  // guard region for benign OOB tile reads
  (void)ws_size; (void)in_sizes; (void)n_in; (void)out_size;

  // ---- setup ----
  posadd<<<16384, 256, 0, stream>>>(x_in, x);
  rotab<<<1024, 64, 0, stream>>>(tsin, tcos);
  wtrans<<<dim3(8, 8, 6), 256, 0, stream>>>(Wq, wqkvT, 512, 512, 512LL * 512, 1536LL * 512);
  wtrans<<<dim3(8, 8, 6), 256, 0, stream>>>(Wk, wqkvT + 512LL * 512, 512, 512, 512LL * 512, 1536LL * 512);
  wtrans<<<dim3(8, 8, 6), 256, 0, stream>>>(Wv, wqkvT + 1024LL * 512, 512, 512, 512LL * 512, 1536LL * 512);
  wtrans<<<dim3(8, 8, 6), 256, 0, stream>>>(Wo, woT, 512, 512, 512LL * 512, 512LL * 512);
  wtrans<<<dim3(32, 8, 6), 256, 0, stream>>>(W1, w1T, 512, 2048, 512LL * 2048, 2048LL * 512);
  wtrans<<<dim3(8, 32, 6), 256, 0, stream>>>(W2, w2T, 2048, 512, 2048LL * 512, 512LL * 2048);
  projconv<<<(N_LAYER * M_ALLOC * 64) / 256, 256, 0, stream>>>(Pr, projT);

  for (int l = 0; l < N_LAYER; l++) {
    const u16* wq = wqkvT + (long long)l * 1536 * 512;
    const u16* wo = woT + (long long)l * 512 * 512;
    const u16* w1 = w1T + (long long)l * 2048 * 512;
    const u16* w2 = w2T + (long long)l * 512 * 2048;
    const u16* pj = projT + (long long)l * M_ALLOC * 64;

    // LN1 -> h
    ln_kernel<false><<<ROWS, 64, 0, stream>>>(x, ln1g + l * 512, ln1b + l * 512, hbuf);
    // qkv_pre = h @ Wqkv^T   (8192 x 1536, K=512) -> big (bf16)
    gemm_bt<0><<<dim3(64, 12, 1), 256, 0, stream>>>(hbuf, wq, big, nullptr,
        512, 1536, 0, 0, 0, 1.0f, 1536, ROWS);
    // rotary + diag, v transpose
    rotary_kernel<<<BHN, 64, 0, stream>>>((u16*)big, tsin, tcos, qrbuf, krbuf, diagq, diagk);
    vtrans<<<1024, 256, 0, stream>>>((u16*)big, vTbuf);
    // dd_k = k_rot @ proj^T * 64^-0.25   (batched 32: 2048 x 288, K=64) -> big (f32)
    gemm_bt<1><<<dim3(16, 3, 32), 256, 0, stream>>>(krbuf, pj, big, nullptr,
        64, M_PAD, 2048LL * 64, 0, (long long)N_SEQ * M_PAD, 0.35355339f, M_PAD, N_SEQ);
    // global k max
    kmax1<<<2048, 256, 0, stream>>>(big, kpart);
    kmax2<<<1, 256, 0, stream>>>(kpart, kmaxb);
    // kf^T bf16 tiles
    kfprep<<<dim3(32, 5, 32), 256, 0, stream>>>(big, diagk, kmaxb, kfT);
    ksumk<<<32 * M_PAD, 64, 0, stream>>>(kfT, ksum);
    // ctx = kf^T @ v  (batched 32: 384 x 64(=128 tile), K=2048) -> ctxb f32
    gemm_bt<1><<<dim3(3, 1, 32), 256, 0, stream>>>(kfT, vTbuf, ctxb, nullptr,
        2048, 64, (long long)M_ALLOC * N_SEQ, 64LL * N_SEQ, (long long)M_PAD * 64,
        1.0f, 64, M_PAD);
    ctxtrans<<<(32 * M_PAD * 64) / 256, 256, 0, stream>>>(ctxb, ctxT);
    // dd_q overwrite big
    gemm_bt<1><<<dim3(16, 3, 32), 256, 0, stream>>>(qrbuf, pj, big, nullptr,
        64, M_PAD, 2048LL * 64, 0, (long long)N_SEQ * M_PAD, 0.35355339f, M_PAD, N_SEQ);
    // qf (with d_inv folded) -> kfT buffer reuse
    qfprep<<<BHN, 64, 0, stream>>>(big, diagq, ksum, kfT);
    // o = qf @ ctx  (batched 32: 2048 x 64, K=288) -> obuf scatter (b,n,h*64+e)
    gemm_bt<4><<<dim3(16, 1, 32), 256, 0, stream>>>(kfT, ctxT, obuf, nullptr,
        M_PAD, 0, (long long)N_SEQ * M_PAD, 64LL * M_PAD, 0, 1.0f, 64, N_SEQ);
    // x += o @ Wo^T
    gemm_bt<2><<<dim3(64, 4, 1), 256, 0, stream>>>(obuf, wo, x, nullptr,
        512, 512, 0, 0, 0, 1.0f, 512, ROWS);
    // LN2 -> h
    ln_kernel<false><<<ROWS, 64, 0, stream>>>(x, ln2g + l * 512, ln2b + l * 512, hbuf);
    // ff = gelu(h @ W1^T + b1) -> big (bf16)
    gemm_bt<3><<<dim3(64, 16, 1), 256, 0, stream>>>(hbuf, w1, big, b1 + (long long)l * 2048,
        512, 2048, 0, 0, 0, 1.0f, 2048, ROWS);
    // x += ff @ W2^T + b2
    gemm_bt<2><<<dim3(64, 4, 1), 256, 0, stream>>>((u16*)big, w2, x, b2 + (long long)l * 512,
        2048, 512, 0, 0, 0, 1.0f, 512, ROWS);
  }

  // final LN -> d_out (f32)
  ln_kernel<true><<<ROWS, 64, 0, stream>>>(x, lnfg, lnfb, d_out);
}

// Round 2
// 2197.338 us; speedup vs baseline: 1.0839x; 1.0839x over previous
//
#include <hip/hip_runtime.h>
#include <hip/hip_bf16.h>
#include <cstdint>

typedef float v4f __attribute__((ext_vector_type(4)));
typedef short v8s __attribute__((ext_vector_type(8)));
typedef unsigned short u16;

#define N_SEQ 2048
#define D_MODEL 512
#define N_LAYER 6
#define N_HEAD 8
#define D_HEAD 64
#define M_FEAT 266
#define M_PAD 288
#define M_ALLOC 384
#define FF_DIM 2048
#define BATCH 4
#define ROWS 8192
#define BHN 65536   // B*H*N

__device__ __forceinline__ float b2f(u16 u) {
  return __uint_as_float(((uint32_t)u) << 16);
}
__device__ __forceinline__ u16 f2b(float f) {
  union { __hip_bfloat16 h; u16 u; } c;
  c.h = __float2bfloat16(f);
  return c.u;
}
__device__ __forceinline__ float wave_sum(float v) {
#pragma unroll
  for (int o = 1; o < 64; o <<= 1) v += __shfl_xor(v, o);
  return v;
}
__device__ __forceinline__ float wave_max(float v) {
#pragma unroll
  for (int o = 1; o < 64; o <<= 1) v = fmaxf(v, __shfl_xor(v, o));
  return v;
}

__device__ __forceinline__ void mfma_bf16(v4f& d, v8s a, v8s b) {
  asm volatile("v_mfma_f32_16x16x32_bf16 %0, %1, %2, %0" : "+v"(d) : "v"(a), "v"(b));
}

// async global->LDS, 16B per lane. LDS dest must be wave-linear (base + lane*16).
__device__ __forceinline__ void async16(const u16* g, u16* l) {
  __builtin_amdgcn_global_load_lds(
      (const __attribute__((address_space(1))) uint32_t*)g,
      (__attribute__((address_space(3))) uint32_t*)l, 16, 0, 0);
}

// ---------------------------------------------------------------------------
// GEMM:  C[M x N] = A[M x K] * B^T   (B stored as [N x K], both bf16)
// 128x128 tile (or 128x64 when N64), BK=32, 256 threads (4 waves),
// global_load_lds staging, double-buffered LDS, ONE barrier per K-step.
// EPI: 0 = plain bf16 out; 1 = f32 * scale with col<Ncap,row<Mcap masks;
//      2 = f32 residual += acc + bias; 3 = bf16 gelu(acc+bias);
//      4 = bf16 head-scatter o[(b*N+row)*512 + h*64 + col], col<64.
// ---------------------------------------------------------------------------
template <int EPI, bool N64>
__global__ void __launch_bounds__(256, 3)
gemm2(const u16* __restrict__ A, const u16* __restrict__ B,
      void* __restrict__ Cv, const float* __restrict__ bias,
      int K, int ldc, long long sA, long long sB, long long sC,
      float scale, int Ncap, int Mcap)
{
  __shared__ u16 As[2][128 * 32];
  __shared__ u16 Bs[2][128 * 32];
  const int z = blockIdx.z;
  const u16* Ag = A + (long long)z * sA;
  const u16* Bg = B + (long long)z * sB;
  const int t = threadIdx.x;
  const int lane = t & 63;
  const int w = t >> 6;
  constexpr int NF = N64 ? 2 : 4;
  const int wm = (w >> 1) << 6;
  const int wn = (w & 1) << (N64 ? 5 : 6);
  const int tiM = blockIdx.x << 7, tiN = blockIdx.y << 7;

  // staging: thread t covers (row = t>>2 [+64], col = (t&3)*8); LDS linear at t*8 [+2048]
  const int srow = t >> 2;
  const int scol = (t & 3) << 3;
  const u16* Ap = Ag + (long long)(tiM + srow) * K + scol;
  const u16* Bp = Bg + (long long)(tiN + srow) * K + scol;
  const long long rstride = 64LL * K;

  const int rr = lane & 15;
  const int kc = (lane >> 4) << 3;

  v4f acc[4][NF] = {};

  const int nk = K >> 5;
  auto stage = [&](int buf, int k0) {
    const u16* a = Ap + k0;
    async16(a, &As[buf][t * 8]);
    async16(a + rstride, &As[buf][t * 8 + 2048]);
    const u16* b = Bp + k0;
    async16(b, &Bs[buf][t * 8]);
    if (!N64) async16(b + rstride, &Bs[buf][t * 8 + 2048]);
  };

  stage(0, 0);
  __syncthreads();
  int cur = 0;
  for (int kt = 0; kt < nk; ++kt) {
    if (kt + 1 < nk) stage(cur ^ 1, (kt + 1) << 5);
    v8s af[4], bf[NF];
#pragma unroll
    for (int i = 0; i < 4; i++) af[i] = *(const v8s*)&As[cur][(wm + rr + i * 16) * 32 + kc];
#pragma unroll
    for (int i = 0; i < NF; i++) bf[i] = *(const v8s*)&Bs[cur][(wn + rr + i * 16) * 32 + kc];
#pragma unroll
    for (int fm = 0; fm < 4; fm++)
#pragma unroll
      for (int fn = 0; fn < NF; fn++)
        mfma_bf16(acc[fm][fn], af[fm], bf[fn]);
    __syncthreads();
    cur ^= 1;
  }

  // hazard cushion: MFMA results -> VALU epilogue
  __builtin_amdgcn_sched_barrier(0);
  asm volatile("s_nop 7\ns_nop 7\ns_nop 7");
  __builtin_amdgcn_sched_barrier(0);

  const int r4 = (lane >> 4) << 2;
  const int cc = lane & 15;
#pragma unroll
  for (int fm = 0; fm < 4; fm++)
#pragma unroll
    for (int fn = 0; fn < NF; fn++)
#pragma unroll
      for (int i = 0; i < 4; i++) {
        int row = tiM + wm + fm * 16 + r4 + i;
        int col = tiN + wn + fn * 16 + cc;
        float v = acc[fm][fn][i];
        if (EPI == 0) {
          ((u16*)Cv)[(long long)z * sC + (long long)row * ldc + col] = f2b(v);
        } else if (EPI == 1) {
          if (col < Ncap && row < Mcap)
            ((float*)Cv)[(long long)z * sC + (long long)row * ldc + col] = v * scale;
        } else if (EPI == 2) {
          long long idx = (long long)row * ldc + col;
          float bb = bias ? bias[col] : 0.0f;
          ((float*)Cv)[idx] += v + bb;
        } else if (EPI == 3) {
          float hv = v + bias[col];
          float gg = 0.5f * hv * (1.0f + erff(hv * 0.70710678118f));
          ((u16*)Cv)[(long long)row * ldc + col] = f2b(gg);
        } else {  // EPI == 4
          if (col < 64) {
            int b_ = z >> 3, h_ = z & 7;
            ((u16*)Cv)[(long long)(b_ * N_SEQ + row) * 512 + h_ * 64 + col] = f2b(v);
          }
        }
      }
}

// ---------------------------------------------------------------------------
// LayerNorm over D=512, 256 threads = 4 waves, one row per wave.
// ---------------------------------------------------------------------------
template <bool F32OUT>
__global__ void ln_kernel(const float* __restrict__ x, const float* __restrict__ g,
                          const float* __restrict__ b, void* __restrict__ out)
{
  const int row = blockIdx.x * 4 + (threadIdx.x >> 6);
  const int lane = threadIdx.x & 63;
  const float* xr = x + (long long)row * D_MODEL + lane * 8;
  v4f v0 = *(const v4f*)xr;
  v4f v1 = *(const v4f*)(xr + 4);
  float s = v0[0] + v0[1] + v0[2] + v0[3] + v1[0] + v1[1] + v1[2] + v1[3];
  float sq = v0[0]*v0[0] + v0[1]*v0[1] + v0[2]*v0[2] + v0[3]*v0[3]
           + v1[0]*v1[0] + v1[1]*v1[1] + v1[2]*v1[2] + v1[3]*v1[3];
  s = wave_sum(s);
  sq = wave_sum(sq);
  float mu = s * (1.0f / D_MODEL);
  float var = sq * (1.0f / D_MODEL) - mu * mu;
  float rstd = rsqrtf(var + 1e-5f);
  v4f g0 = *(const v4f*)(g + lane * 8), g1 = *(const v4f*)(g + lane * 8 + 4);
  v4f bb0 = *(const v4f*)(b + lane * 8), bb1 = *(const v4f*)(b + lane * 8 + 4);
  float y[8];
#pragma unroll
  for (int j = 0; j < 4; j++) y[j] = (v0[j] - mu) * rstd * g0[j] + bb0[j];
#pragma unroll
  for (int j = 0; j < 4; j++) y[4 + j] = (v1[j] - mu) * rstd * g1[j] + bb1[j];
  if (F32OUT) {
    float* op = (float*)out + (long long)row * D_MODEL + lane * 8;
    v4f o0 = {y[0], y[1], y[2], y[3]}, o1 = {y[4], y[5], y[6], y[7]};
    *(v4f*)op = o0;
    *(v4f*)(op + 4) = o1;
  } else {
    u16* op = (u16*)out + (long long)row * D_MODEL + lane * 8;
    alignas(16) u16 tmp[8];
#pragma unroll
    for (int j = 0; j < 8; j++) tmp[j] = f2b(y[j]);
    *(v8s*)op = *(v8s*)tmp;
  }
}

// x = x_in + fixed_pos_emb(N, D)
__global__ void posadd(const float* __restrict__ xin, float* __restrict__ x)
{
  long long i = (long long)blockIdx.x * 256 + threadIdx.x;  // 4*2048*512
  int d = (int)(i & 511);
  int n = (int)((i >> 9) & 2047);
  int j = d & 255;
  float sarg = (float)n * expf(-0.035977892f * (float)j);  // 10000^(-2j/512)
  float pe = (d < 256) ? sinf(sarg) : cosf(sarg);
  x[i] = xin[i] + pe;
}

// rotary sin/cos tables: per (n, j<32)
__global__ void rotab(float* __restrict__ ts, float* __restrict__ tc)
{
  int i = blockIdx.x * 64 + threadIdx.x;  // 2048*32
  int n = i >> 5, j = i & 31;
  float sarg = (float)n * expf(-0.28782314f * (float)j);  // 10000^(-2j/64)
  float s, c;
  sincosf(sarg, &s, &c);
  ts[i] = s;
  tc[i] = c;
}

// rotary on q,k + diag; 4 (b,h,n) rows per 256-thread block
__global__ void rotary_kernel(const u16* __restrict__ qkv,
                              const float* __restrict__ ts, const float* __restrict__ tc,
                              u16* __restrict__ qr, u16* __restrict__ kr,
                              float* __restrict__ dq, float* __restrict__ dk)
{
  int bid = blockIdx.x * 4 + (threadIdx.x >> 6);  // ((b*8+h)*2048+n)
  int n = bid & 2047;
  int h = (bid >> 11) & 7;
  int b = bid >> 14;
  int lane = threadIdx.x & 63;
  long long src = ((long long)(b * N_SEQ + n)) * 1536 + h * 64 + lane;
  float qv = b2f(qkv[src]);
  float kv = b2f(qkv[src + 512]);
  int j = lane >> 1;
  float sn = ts[n * 32 + j], cn = tc[n * 32 + j];
  float qp = __shfl_xor(qv, 1), kp = __shfl_xor(kv, 1);
  float qrv = (lane & 1) ? (qv * cn + qp * sn) : (qv * cn - qp * sn);
  float krv = (lane & 1) ? (kv * cn + kp * sn) : (kv * cn - kp * sn);
  u16 qb = f2b(qrv), kb = f2b(krv);
  long long dst = ((long long)bid) * 64 + lane;
  qr[dst] = qb;
  kr[dst] = kb;
  float q2 = b2f(qb); q2 *= q2;
  float k2 = b2f(kb); k2 *= k2;
  q2 = wave_sum(q2);
  k2 = wave_sum(k2);
  if (lane == 0) { dq[bid] = q2 * 0.0625f; dk[bid] = k2 * 0.0625f; }  // 0.5 * 64^-0.5
}

// v transpose: qkv_pre (b,n,h,dh) -> vT (b,h,dh,n) bf16
__global__ void vtrans(const u16* __restrict__ qkv, u16* __restrict__ vT)
{
  int bid = blockIdx.x;  // B*H*32
  int nt = bid & 31;
  int h = (bid >> 5) & 7;
  int b = bid >> 8;
  __shared__ u16 st[64][72];
  int t = threadIdx.x;  // 256
  int r = t >> 2, c = (t & 3) << 4;
  long long src = ((long long)(b * N_SEQ + nt * 64 + r)) * 1536 + 1024 + h * 64 + c;
  *(v8s*)&st[r][c] = *(const v8s*)(qkv + src);
  *(v8s*)&st[r][c + 8] = *(const v8s*)(qkv + src + 8);
  __syncthreads();
  alignas(16) u16 tmp[16];
#pragma unroll
  for (int jj = 0; jj < 16; jj++) tmp[jj] = st[c + jj][r];
  long long dst = ((long long)((b * 8 + h) * 64 + r)) * N_SEQ + nt * 64 + c;
  *(v8s*)(vT + dst) = *(v8s*)&tmp[0];
  *(v8s*)(vT + dst + 8) = *(v8s*)&tmp[8];
}

// weight transpose + bf16: src (l, Ks, Ns) f32 -> dst (l, Ns, Ks) bf16
__global__ void wtrans(const float* __restrict__ src, u16* __restrict__ dst,
                       int Ks, int Ns, long long sSrc, long long sDst)
{
  int l = blockIdx.z;
  src += (long long)l * sSrc;
  dst += (long long)l * sDst;
  int n0 = blockIdx.x << 6, k0 = blockIdx.y << 6;
  __shared__ float st[64][68];
  int t = threadIdx.x;
  int r = t >> 2, c = (t & 3) << 4;
  const float* sp = src + (long long)(k0 + r) * Ns + n0 + c;
#pragma unroll
  for (int jj = 0; jj < 16; jj += 4) *(v4f*)&st[r][c + jj] = *(const v4f*)(sp + jj);
  __syncthreads();
  alignas(16) u16 tmp[16];
#pragma unroll
  for (int jj = 0; jj < 16; jj++) tmp[jj] = f2b(st[c + jj][r]);
  u16* dp = dst + (long long)(n0 + r) * Ks + k0 + c;
  *(v8s*)(dp) = *(v8s*)&tmp[0];
  *(v8s*)(dp + 8) = *(v8s*)&tmp[8];
}

// proj (l, 266, 64) f32 -> (l, 384, 64) bf16, zero-padded rows
__global__ void projconv(const float* __restrict__ proj, u16* __restrict__ out)
{
  int i = blockIdx.x * 256 + threadIdx.x;  // 6*384*64
  int dh = i & 63;
  int m = (i >> 6) % M_ALLOC;
  int l = i / (M_ALLOC * 64);
  float v = (m < M_FEAT) ? proj[((long long)l * M_FEAT + m) * 64 + dh] : 0.0f;
  out[i] = f2b(v);
}

__global__ void kmax1(const float* __restrict__ dd, float* __restrict__ part)
{
  const long long total = (long long)32 * N_SEQ * M_PAD;
  float m = -3e38f;
  for (long long i = (long long)blockIdx.x * 256 + threadIdx.x; i < total;
       i += (long long)gridDim.x * 256)
    m = fmaxf(m, dd[i]);
  m = wave_max(m);
  __shared__ float sm[4];
  if ((threadIdx.x & 63) == 0) sm[threadIdx.x >> 6] = m;
  __syncthreads();
  if (threadIdx.x == 0)
    part[blockIdx.x] = fmaxf(fmaxf(sm[0], sm[1]), fmaxf(sm[2], sm[3]));
}

__global__ void kmax2(const float* __restrict__ part, float* __restrict__ kmax)
{
  float m = -3e38f;
  for (int i = threadIdx.x; i < 2048; i += 256) m = fmaxf(m, part[i]);
  m = wave_max(m);
  __shared__ float sm[4];
  if ((threadIdx.x & 63) == 0) sm[threadIdx.x >> 6] = m;
  __syncthreads();
  if (threadIdx.x == 0) kmax[0] = fmaxf(fmaxf(sm[0], sm[1]), fmaxf(sm[2], sm[3]));
}

// kf transpose-prep: dd_k (bh,n,288) f32 -> kfT (bh,384,2048) bf16 (rows>=288 skipped)
__global__ void kfprep(const float* __restrict__ dd, const float* __restrict__ diag,
                       const float* __restrict__ kmax, u16* __restrict__ kfT)
{
  int bh = blockIdx.z;
  int n0 = blockIdx.x << 6;
  int m0 = blockIdx.y << 6;
  __shared__ u16 st[64][72];
  float km = kmax[0];
  int t = threadIdx.x;
  int r = t >> 2, c = (t & 3) << 4;
  const float* dp = dd + ((long long)bh * N_SEQ + n0 + r) * M_PAD + m0 + c;
  float dg = diag[(long long)bh * N_SEQ + n0 + r];
#pragma unroll
  for (int jj = 0; jj < 16; jj++) {
    int m = m0 + c + jj;
    float kf = 0.0f;
    if (m < M_FEAT) kf = 0.06131389f * (expf(dp[jj] - dg - km) + 1e-4f);
    st[c + jj][r] = f2b(kf);
  }
  __syncthreads();
  int mr = t >> 2, nc = (t & 3) << 4;
  if (m0 + mr < M_PAD) {
    alignas(16) u16 tmp[16];
#pragma unroll
    for (int jj = 0; jj < 16; jj++) tmp[jj] = st[mr][nc + jj];
    u16* op = kfT + ((long long)bh * M_ALLOC + m0 + mr) * N_SEQ + n0 + nc;
    *(v8s*)op = *(v8s*)&tmp[0];
    *(v8s*)(op + 8) = *(v8s*)&tmp[8];
  }
}

// ksum[bh][m] = sum_n kfT[bh][m][n]; 4 rows per 256-thread block
__global__ void ksumk(const u16* __restrict__ kfT, float* __restrict__ ksum)
{
  int bid = blockIdx.x * 4 + (threadIdx.x >> 6);  // 32*288
  int bh = bid / M_PAD, m = bid % M_PAD;
  const u16* p = kfT + ((long long)bh * M_ALLOC + m) * N_SEQ;
  int lane = threadIdx.x & 63;
  float s = 0.0f;
#pragma unroll
  for (int j = 0; j < 4; j++) {
    v8s v = *(const v8s*)(p + j * 512 + lane * 8);
#pragma unroll
    for (int e = 0; e < 8; e++) s += b2f((u16)v[e]);
  }
  s = wave_sum(s);
  if (lane == 0) ksum[bid] = s;
}

// qf prep: row max, denominator, write qf*dinv as bf16 (bh,n,288); 4 rows/block
__global__ void qfprep(const float* __restrict__ dd, const float* __restrict__ diag,
                       const float* __restrict__ ksum, u16* __restrict__ qf)
{
  int bid = blockIdx.x * 4 + (threadIdx.x >> 6);  // 32*2048
  int bh = bid >> 11;
  int lane = threadIdx.x & 63;
  const float* rowp = dd + (long long)bid * M_PAD;
  float dg = diag[bid];
  const float* ks = ksum + bh * M_PAD;
  float vals[5];
  float mx = -3e38f;
  int cnt = 0;
  for (int m = lane; m < M_FEAT; m += 64) {
    float v = rowp[m];
    vals[cnt++] = v;
    mx = fmaxf(mx, v);
  }
  mx = wave_max(mx);
  float ss = 0.0f;
  cnt = 0;
  for (int m = lane; m < M_FEAT; m += 64) {
    float e = 0.06131389f * (expf(vals[cnt] - dg - mx) + 1e-4f);
    vals[cnt++] = e;
    ss += e * ks[m];
  }
  ss = wave_sum(ss);
  float dinv = 1.0f / ss;
  u16* op = qf + (long long)bid * M_PAD;
  cnt = 0;
  for (int m = lane; m < M_PAD; m += 64) {
    float v = 0.0f;
    if (m < M_FEAT) v = vals[cnt++] * dinv;
    op[m] = f2b(v);
  }
}

// ctx (bh,288,64) f32 -> ctxT (bh,64,288) bf16
__global__ void ctxtrans(const float* __restrict__ ctx, u16* __restrict__ ctxT)
{
  int i = blockIdx.x * 256 + threadIdx.x;  // 32*288*64
  int e = i & 63;
  int m = (i >> 6) % M_PAD;
  int bh = i / (M_PAD * 64);
  ctxT[((long long)bh * 64 + e) * M_PAD + m] = f2b(ctx[i]);
}

// ---------------------------------------------------------------------------
extern "C" void kernel_launch(void* const* d_in, const int* in_sizes, int n_in,
                              void* d_out, int out_size, void* d_ws, size_t ws_size,
                              hipStream_t stream)
{
  const float* x_in = (const float*)d_in[0];
  const float* Wq  = (const float*)d_in[1];
  const float* Wk  = (const float*)d_in[2];
  const float* Wv  = (const float*)d_in[3];
  const float* Wo  = (const float*)d_in[4];
  const float* Pr  = (const float*)d_in[5];
  const float* ln1g = (const float*)d_in[6];
  const float* ln1b = (const float*)d_in[7];
  const float* W1  = (const float*)d_in[8];
  const float* b1  = (const float*)d_in[9];
  const float* W2  = (const float*)d_in[10];
  const float* b2  = (const float*)d_in[11];
  const float* ln2g = (const float*)d_in[12];
  const float* ln2b = (const float*)d_in[13];
  const float* lnfg = (const float*)d_in[14];
  const float* lnfb = (const float*)d_in[15];

  char* ws = (char*)d_ws;
  size_t off = 0;
  auto alloc = [&](size_t bytes) -> void* {
    void* p = ws + off;
    off = (off + bytes + 255) & ~(size_t)255;
    return p;
  };

  float* x      = (float*)alloc((size_t)ROWS * D_MODEL * 4);          // residual stream
  float* tsin   = (float*)alloc((size_t)N_SEQ * 32 * 4);
  float* tcos   = (float*)alloc((size_t)N_SEQ * 32 * 4);
  u16*   wqkvT  = (u16*)alloc((size_t)N_LAYER * 1536 * 512 * 2);
  u16*   woT    = (u16*)alloc((size_t)N_LAYER * 512 * 512 * 2);
  u16*   w1T    = (u16*)alloc((size_t)N_LAYER * 2048 * 512 * 2);
  u16*   w2T    = (u16*)alloc((size_t)N_LAYER * 512 * 2048 * 2);
  u16*   projT  = (u16*)alloc((size_t)N_LAYER * M_ALLOC * 64 * 2);
  u16*   hbuf   = (u16*)alloc((size_t)ROWS * D_MODEL * 2);
  u16*   obuf   = (u16*)alloc((size_t)ROWS * D_MODEL * 2);
  float* big    = (float*)alloc((size_t)32 * N_SEQ * M_PAD * 4);      // qkv_pre / dd / ff union
  u16*   qrbuf  = (u16*)alloc((size_t)BHN * 64 * 2);
  u16*   krbuf  = (u16*)alloc((size_t)BHN * 64 * 2);
  u16*   vTbuf  = (u16*)alloc((size_t)BHN * 64 * 2);
  float* diagq  = (float*)alloc((size_t)BHN * 4);
  float* diagk  = (float*)alloc((size_t)BHN * 4);
  float* kpart  = (float*)alloc(2048 * 4);
  float* kmaxb  = (float*)alloc(256);
  u16*   kfT    = (u16*)alloc((size_t)32 * M_ALLOC * N_SEQ * 2);      // also qf buffer
  float* ctxb   = (float*)alloc((size_t)32 * M_PAD * 64 * 4);
  u16*   ctxT   = (u16*)alloc((size_t)32 * 64 * M_PAD * 2);
  float* ksum   = (float*)alloc((size_t)32 * M_PAD * 4);
  (void)alloc(1 << 20);  // guard region for benign OOB tile reads
  (void)ws_size; (void)in_sizes; (void)n_in; (void)out_size;

  // ---- setup ----
  posadd<<<16384, 256, 0, stream>>>(x_in, x);
  rotab<<<1024, 64, 0, stream>>>(tsin, tcos);
  wtrans<<<dim3(8, 8, 6), 256, 0, stream>>>(Wq, wqkvT, 512, 512, 512LL * 512, 1536LL * 512);
  wtrans<<<dim3(8, 8, 6), 256, 0, stream>>>(Wk, wqkvT + 512LL * 512, 512, 512, 512LL * 512, 1536LL * 512);
  wtrans<<<dim3(8, 8, 6), 256, 0, stream>>>(Wv, wqkvT + 1024LL * 512, 512, 512, 512LL * 512, 1536LL * 512);
  wtrans<<<dim3(8, 8, 6), 256, 0, stream>>>(Wo, woT, 512, 512, 512LL * 512, 512LL * 512);
  wtrans<<<dim3(32, 8, 6), 256, 0, stream>>>(W1, w1T, 512, 2048, 512LL * 2048, 2048LL * 512);
  wtrans<<<dim3(8, 32, 6), 256, 0, stream>>>(W2, w2T, 2048, 512, 2048LL * 512, 512LL * 2048);
  projconv<<<(N_LAYER * M_ALLOC * 64) / 256, 256, 0, stream>>>(Pr, projT);

  for (int l = 0; l < N_LAYER; l++) {
    const u16* wq = wqkvT + (long long)l * 1536 * 512;
    const u16* wo = woT + (long long)l * 512 * 512;
    const u16* w1 = w1T + (long long)l * 2048 * 512;
    const u16* w2 = w2T + (long long)l * 512 * 2048;
    const u16* pj = projT + (long long)l * M_ALLOC * 64;

    // LN1 -> h
    ln_kernel<false><<<ROWS / 4, 256, 0, stream>>>(x, ln1g + l * 512, ln1b + l * 512, hbuf);
    // qkv_pre = h @ Wqkv^T   (8192 x 1536, K=512) -> big (bf16)
    gemm2<0, false><<<dim3(64, 12, 1), 256, 0, stream>>>(hbuf, wq, big, nullptr,
        512, 1536, 0, 0, 0, 1.0f, 1536, ROWS);
    // rotary + diag, v transpose
    rotary_kernel<<<BHN / 4, 256, 0, stream>>>((u16*)big, tsin, tcos, qrbuf, krbuf, diagq, diagk);
    vtrans<<<1024, 256, 0, stream>>>((u16*)big, vTbuf);
    // dd_k = k_rot @ proj^T * 64^-0.25   (batched 32: 2048 x 288, K=64) -> big (f32)
    gemm2<1, false><<<dim3(16, 3, 32), 256, 0, stream>>>(krbuf, pj, big, nullptr,
        64, M_PAD, 2048LL * 64, 0, (long long)N_SEQ * M_PAD, 0.35355339f, M_PAD, N_SEQ);
    // global k max
    kmax1<<<2048, 256, 0, stream>>>(big, kpart);
    kmax2<<<1, 256, 0, stream>>>(kpart, kmaxb);
    // kf^T bf16 tiles
    kfprep<<<dim3(32, 5, 32), 256, 0, stream>>>(big, diagk, kmaxb, kfT);
    ksumk<<<32 * M_PAD / 4, 256, 0, stream>>>(kfT, ksum);
    // ctx = kf^T @ v  (batched 32: 384 x 64, K=2048) -> ctxb f32
    gemm2<1, true><<<dim3(3, 1, 32), 256, 0, stream>>>(kfT, vTbuf, ctxb, nullptr,
        2048, 64, (long long)M_ALLOC * N_SEQ, 64LL * N_SEQ, (long long)M_PAD * 64,
        1.0f, 64, M_PAD);
    ctxtrans<<<(32 * M_PAD * 64) / 256, 256, 0, stream>>>(ctxb, ctxT);
    // dd_q overwrite big
    gemm2<1, false><<<dim3(16, 3, 32), 256, 0, stream>>>(qrbuf, pj, big, nullptr,
        64, M_PAD, 2048LL * 64, 0, (long long)N_SEQ * M_PAD, 0.35355339f, M_PAD, N_SEQ);
    // qf (with d_inv folded) -> kfT buffer reuse
    qfprep<<<BHN / 4, 256, 0, stream>>>(big, diagq, ksum, kfT);
    // o = qf @ ctx  (batched 32: 2048 x 64, K=288) -> obuf scatter (b,n,h*64+e)
    gemm2<4, true><<<dim3(16, 1, 32), 256, 0, stream>>>(kfT, ctxT, obuf, nullptr,
        M_PAD, 0, (long long)N_SEQ * M_PAD, 64LL * M_PAD, 0, 1.0f, 64, N_SEQ);
    // x += o @ Wo^T
    gemm2<2, false><<<dim3(64, 4, 1), 256, 0, stream>>>(obuf, wo, x, nullptr,
        512, 512, 0, 0, 0, 1.0f, 512, ROWS);
    // LN2 -> h
    ln_kernel<false><<<ROWS / 4, 256, 0, stream>>>(x, ln2g + l * 512, ln2b + l * 512, hbuf);
    // ff = gelu(h @ W1^T + b1) -> big (bf16)
    gemm2<3, false><<<dim3(64, 16, 1), 256, 0, stream>>>(hbuf, w1, big, b1 + (long long)l * 2048,
        512, 2048, 0, 0, 0, 1.0f, 2048, ROWS);
    // x += ff @ W2^T + b2
    gemm2<2, false><<<dim3(64, 4, 1), 256, 0, stream>>>((u16*)big, w2, x, b2 + (long long)l * 512,
        2048, 512, 0, 0, 0, 1.0f, 512, ROWS);
  }

  // final LN -> d_out (f32)
  ln_kernel<true><<<ROWS / 4, 256, 0, stream>>>(x, lnfg, lnfb, d_out);
}

// Round 3
// 1842.818 us; speedup vs baseline: 1.2925x; 1.1924x over previous
//
#include <hip/hip_runtime.h>
#include <hip/hip_bf16.h>
#include <cstdint>

typedef float v4f __attribute__((ext_vector_type(4)));
typedef short v8s __attribute__((ext_vector_type(8)));
typedef unsigned short u16;

#define N_SEQ 2048
#define D_MODEL 512
#define N_LAYER 6
#define N_HEAD 8
#define D_HEAD 64
#define M_FEAT 266
#define M_PAD 288
#define M_ALLOC 384
#define FF_DIM 2048
#define BATCH 4
#define ROWS 8192
#define BHN 65536   // B*H*N

__device__ __forceinline__ float b2f(u16 u) {
  return __uint_as_float(((uint32_t)u) << 16);
}
__device__ __forceinline__ u16 f2b(float f) {
  union { __hip_bfloat16 h; u16 u; } c;
  c.h = __float2bfloat16(f);
  return c.u;
}
__device__ __forceinline__ float wave_sum(float v) {
#pragma unroll
  for (int o = 1; o < 64; o <<= 1) v += __shfl_xor(v, o);
  return v;
}
__device__ __forceinline__ float wave_max(float v) {
#pragma unroll
  for (int o = 1; o < 64; o <<= 1) v = fmaxf(v, __shfl_xor(v, o));
  return v;
}

__device__ __forceinline__ void mfma_bf16(v4f& d, v8s a, v8s b) {
  asm volatile("v_mfma_f32_16x16x32_bf16 %0, %1, %2, %0" : "+v"(d) : "v"(a), "v"(b));
}

// async global->LDS, 16B per lane. LDS dest must be wave-linear (base + lane*16).
__device__ __forceinline__ void async16(const u16* g, u16* l) {
  __builtin_amdgcn_global_load_lds(
      (const __attribute__((address_space(1))) uint32_t*)g,
      (__attribute__((address_space(3))) uint32_t*)l, 16, 0, 0);
}

// ---------------------------------------------------------------------------
// GEMM:  C[M x N] = A[M x K] * B^T   (B stored as [N x K], both bf16)
// BM=128, BN in {64,128}, BK=32, 256 threads (4 waves, 2x2), double-buffered
// LDS via global_load_lds, one barrier per K-step. Optional split-K.
// EPI: 0 = plain bf16 out
//      2 = f32 residual += acc + bias
//      3 = bf16 gelu(acc+bias)
//      4 = bf16 head-scatter o[(b*N+row)*512 + h*64 + col]
//      5 = f32 split-K partial: part[(zz*M_ALLOC+row)*64+col], row<Mcap
//      6 = f32 dd store * scale (col<Ncap) + global atomicMax over col<266
// ---------------------------------------------------------------------------
template <int EPI, int BN, int KSPLIT>
__global__ void __launch_bounds__(256, 4)
gemm2(const u16* __restrict__ A, const u16* __restrict__ B,
      void* __restrict__ Cv, const float* __restrict__ bias,
      int K, int ldc, long long sA, long long sB, long long sC,
      float scale, int Ncap, int Mcap, unsigned int* __restrict__ gmax)
{
  __shared__ u16 As[2][128 * 32];
  __shared__ u16 Bs[2][BN * 32];
  __shared__ float smax[4];
  const int zz = blockIdx.z;
  const int z = (KSPLIT > 1) ? zz / KSPLIT : zz;
  const int ks = (KSPLIT > 1) ? zz % KSPLIT : 0;
  const int kchunk = K / KSPLIT;
  const u16* Ag = A + (long long)z * sA + ks * kchunk;
  const u16* Bg = B + (long long)z * sB + ks * kchunk;
  const int t = threadIdx.x;
  const int lane = t & 63;
  const int w = t >> 6;
  constexpr int NF = BN / 32;
  const int wm = (w >> 1) << 6;
  const int wn = (w & 1) * (BN / 2);
  const int tiM = blockIdx.x << 7, tiN = blockIdx.y * BN;

  const int srow = t >> 2;
  const int scol = (t & 3) << 3;
  const u16* Ap = Ag + (long long)(tiM + srow) * K + scol;
  const u16* Bp = Bg + (long long)(tiN + srow) * K + scol;
  const long long rstride = 64LL * K;

  const int rr = lane & 15;
  const int kc = (lane >> 4) << 3;

  v4f acc[4][NF] = {};

  const int nk = kchunk >> 5;
  auto stage = [&](int buf, int k0) {
    async16(Ap + k0, &As[buf][t * 8]);
    async16(Ap + k0 + rstride, &As[buf][t * 8 + 2048]);
    async16(Bp + k0, &Bs[buf][t * 8]);
    if (BN == 128) async16(Bp + k0 + rstride, &Bs[buf][t * 8 + 2048]);
  };

  stage(0, 0);
  __syncthreads();
  int cur = 0;
  for (int kt = 0; kt < nk; ++kt) {
    if (kt + 1 < nk) stage(cur ^ 1, (kt + 1) << 5);
    v8s af[4], bf[NF];
#pragma unroll
    for (int i = 0; i < 4; i++) af[i] = *(const v8s*)&As[cur][(wm + rr + i * 16) * 32 + kc];
#pragma unroll
    for (int i = 0; i < NF; i++) bf[i] = *(const v8s*)&Bs[cur][(wn + rr + i * 16) * 32 + kc];
#pragma unroll
    for (int fm = 0; fm < 4; fm++)
#pragma unroll
      for (int fn = 0; fn < NF; fn++)
        mfma_bf16(acc[fm][fn], af[fm], bf[fn]);
    __syncthreads();
    cur ^= 1;
  }

  // hazard cushion: MFMA results -> VALU epilogue
  __builtin_amdgcn_sched_barrier(0);
  asm volatile("s_nop 7\ns_nop 7\ns_nop 7");
  __builtin_amdgcn_sched_barrier(0);

  const int r4 = (lane >> 4) << 2;
  const int cc = lane & 15;
  float lmax = -3e38f;
#pragma unroll
  for (int fm = 0; fm < 4; fm++)
#pragma unroll
    for (int fn = 0; fn < NF; fn++)
#pragma unroll
      for (int i = 0; i < 4; i++) {
        int row = tiM + wm + fm * 16 + r4 + i;
        int col = tiN + wn + fn * 16 + cc;
        float v = acc[fm][fn][i];
        if (EPI == 0) {
          ((u16*)Cv)[(long long)z * sC + (long long)row * ldc + col] = f2b(v);
        } else if (EPI == 2) {
          long long idx = (long long)row * ldc + col;
          float bb = bias ? bias[col] : 0.0f;
          ((float*)Cv)[idx] += v + bb;
        } else if (EPI == 3) {
          float hv = v + bias[col];
          float gg = 0.5f * hv * (1.0f + erff(hv * 0.70710678118f));
          ((u16*)Cv)[(long long)row * ldc + col] = f2b(gg);
        } else if (EPI == 4) {
          if (col < 64) {
            int b_ = z >> 3, h_ = z & 7;
            ((u16*)Cv)[(long long)(b_ * N_SEQ + row) * 512 + h_ * 64 + col] = f2b(v);
          }
        } else if (EPI == 5) {
          if (row < Mcap && col < Ncap)
            ((float*)Cv)[((long long)zz * M_ALLOC + row) * 64 + col] = v;
        } else if (EPI == 6) {
          float sv = v * scale;
          if (col < Ncap) ((float*)Cv)[(long long)row * ldc + col] = sv;
          if (col < M_FEAT) lmax = fmaxf(lmax, sv);
        }
      }

  if (EPI == 6) {
    lmax = wave_max(lmax);
    if (lane == 0) smax[w] = lmax;
    __syncthreads();
    if (t == 0) {
      float m = fmaxf(fmaxf(smax[0], smax[1]), fmaxf(smax[2], smax[3]));
      unsigned int u = __float_as_uint(m);
      unsigned int key = (u & 0x80000000u) ? ~u : (u | 0x80000000u);
      atomicMax(gmax, key);
    }
  }
}

// ---------------------------------------------------------------------------
// Fused dd_q -> row-max -> exp -> denominator -> qf (bf16, d_inv folded).
// Per block: 64 rows x all 384 cols (288 cap), 512 threads = 8 waves (1x8).
// A = q_rot (bh,2048,64), B = projT (384,64). K=64 (2 K-steps).
// ---------------------------------------------------------------------------
__global__ void __launch_bounds__(512, 2)
ddq_qf(const u16* __restrict__ qr, const u16* __restrict__ proj,
       const float* __restrict__ diag, const float* __restrict__ ksum,
       u16* __restrict__ qf)
{
  __shared__ u16 As[2][64 * 32];
  __shared__ u16 Bs[2][384 * 32];
  __shared__ float red[2][8][64];
  const int bh = blockIdx.z;
  const int tiM = blockIdx.x << 6;
  const int t = threadIdx.x;
  const int lane = t & 63;
  const int w = t >> 6;
  const u16* Ag = qr + (long long)bh * (N_SEQ * 64);
  const int srow = t >> 2, scol = (t & 3) << 3;
  const u16* Ap = Ag + (long long)(tiM + srow) * 64 + scol;
  const u16* Bp = proj + (long long)srow * 64 + scol;
  const int rr = lane & 15, kc = (lane >> 4) << 3;
  const int wn = w * 48;

  v4f acc[4][3] = {};
  auto stage = [&](int buf, int k0) {
    if (t < 256) async16(Ap + k0, &As[buf][t * 8]);
#pragma unroll
    for (int i = 0; i < 3; i++)
      async16(Bp + k0 + (long long)i * (128 * 64), &Bs[buf][t * 8 + i * 4096]);
  };

  stage(0, 0);
  __syncthreads();
  for (int kt = 0; kt < 2; ++kt) {
    if (kt == 0) stage(1, 32);
    v8s af[4], bf[3];
#pragma unroll
    for (int i = 0; i < 4; i++) af[i] = *(const v8s*)&As[kt][(rr + i * 16) * 32 + kc];
#pragma unroll
    for (int i = 0; i < 3; i++) bf[i] = *(const v8s*)&Bs[kt][(wn + rr + i * 16) * 32 + kc];
#pragma unroll
    for (int fm = 0; fm < 4; fm++)
#pragma unroll
      for (int fn = 0; fn < 3; fn++)
        mfma_bf16(acc[fm][fn], af[fm], bf[fn]);
    __syncthreads();
  }

  __builtin_amdgcn_sched_barrier(0);
  asm volatile("s_nop 7\ns_nop 7\ns_nop 7");
  __builtin_amdgcn_sched_barrier(0);

  const int r4 = (lane >> 4) << 2;
  const int cc = lane & 15;
  const float sc = 0.35355339f;

  // per-wave row max over its 48 cols
#pragma unroll
  for (int fm = 0; fm < 4; fm++)
#pragma unroll
    for (int i = 0; i < 4; i++) {
      float m = -3e38f;
#pragma unroll
      for (int fn = 0; fn < 3; fn++) {
        int col = wn + fn * 16 + cc;
        float v = acc[fm][fn][i] * sc;
        if (col < M_FEAT) m = fmaxf(m, v);
      }
#pragma unroll
      for (int o = 1; o < 16; o <<= 1) m = fmaxf(m, __shfl_xor(m, o));
      if (cc == 0) red[0][w][fm * 16 + r4 + i] = m;
    }
  __syncthreads();

  float ksv[3];
#pragma unroll
  for (int fn = 0; fn < 3; fn++) {
    int col = wn + fn * 16 + cc;
    ksv[fn] = (col < M_PAD) ? ksum[bh * M_PAD + col] : 0.0f;
  }

  // e = ratio*(exp(dd - diag - rowmax)+eps); row-dot with ksum
#pragma unroll
  for (int fm = 0; fm < 4; fm++)
#pragma unroll
    for (int i = 0; i < 4; i++) {
      int row = fm * 16 + r4 + i;
      float gm = red[0][0][row];
#pragma unroll
      for (int ww = 1; ww < 8; ww++) gm = fmaxf(gm, red[0][ww][row]);
      float dg = diag[(long long)bh * N_SEQ + tiM + row];
      float s = 0.0f;
#pragma unroll
      for (int fn = 0; fn < 3; fn++) {
        int col = wn + fn * 16 + cc;
        float v = acc[fm][fn][i] * sc;
        float e = (col < M_FEAT) ? 0.06131389f * (expf(v - dg - gm) + 1e-4f) : 0.0f;
        acc[fm][fn][i] = e;
        s += e * ksv[fn];
      }
#pragma unroll
      for (int o = 1; o < 16; o <<= 1) s += __shfl_xor(s, o);
      if (cc == 0) red[1][w][row] = s;
    }
  __syncthreads();

#pragma unroll
  for (int fm = 0; fm < 4; fm++)
#pragma unroll
    for (int i = 0; i < 4; i++) {
      int row = fm * 16 + r4 + i;
      float s = 0.0f;
#pragma unroll
      for (int ww = 0; ww < 8; ww++) s += red[1][ww][row];
      float dinv = 1.0f / s;
#pragma unroll
      for (int fn = 0; fn < 3; fn++) {
        int col = wn + fn * 16 + cc;
        if (col < M_PAD)
          qf[((long long)bh * N_SEQ + tiM + row) * M_PAD + col] =
              f2b(acc[fm][fn][i] * dinv);
      }
    }
}

// ---------------------------------------------------------------------------
template <bool F32OUT>
__global__ void ln_kernel(const float* __restrict__ x, const float* __restrict__ g,
                          const float* __restrict__ b, void* __restrict__ out)
{
  const int row = blockIdx.x * 4 + (threadIdx.x >> 6);
  const int lane = threadIdx.x & 63;
  const float* xr = x + (long long)row * D_MODEL + lane * 8;
  v4f v0 = *(const v4f*)xr;
  v4f v1 = *(const v4f*)(xr + 4);
  float s = v0[0] + v0[1] + v0[2] + v0[3] + v1[0] + v1[1] + v1[2] + v1[3];
  float sq = v0[0]*v0[0] + v0[1]*v0[1] + v0[2]*v0[2] + v0[3]*v0[3]
           + v1[0]*v1[0] + v1[1]*v1[1] + v1[2]*v1[2] + v1[3]*v1[3];
  s = wave_sum(s);
  sq = wave_sum(sq);
  float mu = s * (1.0f / D_MODEL);
  float var = sq * (1.0f / D_MODEL) - mu * mu;
  float rstd = rsqrtf(var + 1e-5f);
  v4f g0 = *(const v4f*)(g + lane * 8), g1 = *(const v4f*)(g + lane * 8 + 4);
  v4f bb0 = *(const v4f*)(b + lane * 8), bb1 = *(const v4f*)(b + lane * 8 + 4);
  float y[8];
#pragma unroll
  for (int j = 0; j < 4; j++) y[j] = (v0[j] - mu) * rstd * g0[j] + bb0[j];
#pragma unroll
  for (int j = 0; j < 4; j++) y[4 + j] = (v1[j] - mu) * rstd * g1[j] + bb1[j];
  if (F32OUT) {
    float* op = (float*)out + (long long)row * D_MODEL + lane * 8;
    v4f o0 = {y[0], y[1], y[2], y[3]}, o1 = {y[4], y[5], y[6], y[7]};
    *(v4f*)op = o0;
    *(v4f*)(op + 4) = o1;
  } else {
    u16* op = (u16*)out + (long long)row * D_MODEL + lane * 8;
    alignas(16) u16 tmp[8];
#pragma unroll
    for (int j = 0; j < 8; j++) tmp[j] = f2b(y[j]);
    *(v8s*)op = *(v8s*)tmp;
  }
}

// x = x_in + fixed_pos_emb(N, D)
__global__ void posadd(const float* __restrict__ xin, float* __restrict__ x)
{
  long long i = (long long)blockIdx.x * 256 + threadIdx.x;
  int d = (int)(i & 511);
  int n = (int)((i >> 9) & 2047);
  int j = d & 255;
  float sarg = (float)n * expf(-0.035977892f * (float)j);
  float pe = (d < 256) ? sinf(sarg) : cosf(sarg);
  x[i] = xin[i] + pe;
}

__global__ void rotab(float* __restrict__ ts, float* __restrict__ tc)
{
  int i = blockIdx.x * 64 + threadIdx.x;  // 2048*32
  int n = i >> 5, j = i & 31;
  float sarg = (float)n * expf(-0.28782314f * (float)j);
  float s, c;
  sincosf(sarg, &s, &c);
  ts[i] = s;
  tc[i] = c;
}

__global__ void rotary_kernel(const u16* __restrict__ qkv,
                              const float* __restrict__ ts, const float* __restrict__ tc,
                              u16* __restrict__ qr, u16* __restrict__ kr,
                              float* __restrict__ dq, float* __restrict__ dk)
{
  int bid = blockIdx.x * 4 + (threadIdx.x >> 6);
  int n = bid & 2047;
  int h = (bid >> 11) & 7;
  int b = bid >> 14;
  int lane = threadIdx.x & 63;
  long long src = ((long long)(b * N_SEQ + n)) * 1536 + h * 64 + lane;
  float qv = b2f(qkv[src]);
  float kv = b2f(qkv[src + 512]);
  int j = lane >> 1;
  float sn = ts[n * 32 + j], cn = tc[n * 32 + j];
  float qp = __shfl_xor(qv, 1), kp = __shfl_xor(kv, 1);
  float qrv = (lane & 1) ? (qv * cn + qp * sn) : (qv * cn - qp * sn);
  float krv = (lane & 1) ? (kv * cn + kp * sn) : (kv * cn - kp * sn);
  u16 qb = f2b(qrv), kb = f2b(krv);
  long long dst = ((long long)bid) * 64 + lane;
  qr[dst] = qb;
  kr[dst] = kb;
  float q2 = b2f(qb); q2 *= q2;
  float k2 = b2f(kb); k2 *= k2;
  q2 = wave_sum(q2);
  k2 = wave_sum(k2);
  if (lane == 0) { dq[bid] = q2 * 0.0625f; dk[bid] = k2 * 0.0625f; }
}

__global__ void vtrans(const u16* __restrict__ qkv, u16* __restrict__ vT)
{
  int bid = blockIdx.x;  // B*H*32
  int nt = bid & 31;
  int h = (bid >> 5) & 7;
  int b = bid >> 8;
  __shared__ u16 st[64][72];
  int t = threadIdx.x;
  int r = t >> 2, c = (t & 3) << 4;
  long long src = ((long long)(b * N_SEQ + nt * 64 + r)) * 1536 + 1024 + h * 64 + c;
  *(v8s*)&st[r][c] = *(const v8s*)(qkv + src);
  *(v8s*)&st[r][c + 8] = *(const v8s*)(qkv + src + 8);
  __syncthreads();
  alignas(16) u16 tmp[16];
#pragma unroll
  for (int jj = 0; jj < 16; jj++) tmp[jj] = st[c + jj][r];
  long long dst = ((long long)((b * 8 + h) * 64 + r)) * N_SEQ + nt * 64 + c;
  *(v8s*)(vT + dst) = *(v8s*)&tmp[0];
  *(v8s*)(vT + dst + 8) = *(v8s*)&tmp[8];
}

__global__ void wtrans(const float* __restrict__ src, u16* __restrict__ dst,
                       int Ks, int Ns, long long sSrc, long long sDst)
{
  int l = blockIdx.z;
  src += (long long)l * sSrc;
  dst += (long long)l * sDst;
  int n0 = blockIdx.x << 6, k0 = blockIdx.y << 6;
  __shared__ float st[64][68];
  int t = threadIdx.x;
  int r = t >> 2, c = (t & 3) << 4;
  const float* sp = src + (long long)(k0 + r) * Ns + n0 + c;
#pragma unroll
  for (int jj = 0; jj < 16; jj += 4) *(v4f*)&st[r][c + jj] = *(const v4f*)(sp + jj);
  __syncthreads();
  alignas(16) u16 tmp[16];
#pragma unroll
  for (int jj = 0; jj < 16; jj++) tmp[jj] = f2b(st[c + jj][r]);
  u16* dp = dst + (long long)(n0 + r) * Ks + k0 + c;
  *(v8s*)(dp) = *(v8s*)&tmp[0];
  *(v8s*)(dp + 8) = *(v8s*)&tmp[8];
}

__global__ void projconv(const float* __restrict__ proj, u16* __restrict__ out)
{
  int i = blockIdx.x * 256 + threadIdx.x;  // 6*384*64
  int dh = i & 63;
  int m = (i >> 6) % M_ALLOC;
  int l = i / (M_ALLOC * 64);
  float v = (m < M_FEAT) ? proj[((long long)l * M_FEAT + m) * 64 + dh] : 0.0f;
  out[i] = f2b(v);
}

__global__ void resetmax(unsigned int* p) { *p = 0u; }

// kf transpose-prep: dd_k (bh,n,288) f32 -> kfT (bh,384,2048) bf16
__global__ void kfprep(const float* __restrict__ dd, const float* __restrict__ diag,
                       const unsigned int* __restrict__ kmax, u16* __restrict__ kfT)
{
  int bh = blockIdx.z;
  int n0 = blockIdx.x << 6;
  int m0 = blockIdx.y << 6;
  __shared__ u16 st[64][72];
  unsigned int kk = kmax[0];
  float km = (kk & 0x80000000u) ? __uint_as_float(kk ^ 0x80000000u)
                                : __uint_as_float(~kk);
  int t = threadIdx.x;
  int r = t >> 2, c = (t & 3) << 4;
  const float* dp = dd + ((long long)bh * N_SEQ + n0 + r) * M_PAD + m0 + c;
  float dg = diag[(long long)bh * N_SEQ + n0 + r];
#pragma unroll
  for (int jj = 0; jj < 16; jj++) {
    int m = m0 + c + jj;
    float kf = 0.0f;
    if (m < M_FEAT) kf = 0.06131389f * (expf(dp[jj] - dg - km) + 1e-4f);
    st[c + jj][r] = f2b(kf);
  }
  __syncthreads();
  int mr = t >> 2, nc = (t & 3) << 4;
  if (m0 + mr < M_PAD) {
    alignas(16) u16 tmp[16];
#pragma unroll
    for (int jj = 0; jj < 16; jj++) tmp[jj] = st[mr][nc + jj];
    u16* op = kfT + ((long long)bh * M_ALLOC + m0 + mr) * N_SEQ + n0 + nc;
    *(v8s*)op = *(v8s*)&tmp[0];
    *(v8s*)(op + 8) = *(v8s*)&tmp[8];
  }
}

// ksum[bh][m] = sum_n kfT[bh][m][n]; 4 rows per 256-thread block
__global__ void ksumk(const u16* __restrict__ kfT, float* __restrict__ ksum)
{
  int bid = blockIdx.x * 4 + (threadIdx.x >> 6);  // 32*288
  int bh = bid / M_PAD, m = bid % M_PAD;
  const u16* p = kfT + ((long long)bh * M_ALLOC + m) * N_SEQ;
  int lane = threadIdx.x & 63;
  float s = 0.0f;
#pragma unroll
  for (int j = 0; j < 4; j++) {
    v8s v = *(const v8s*)(p + j * 512 + lane * 8);
#pragma unroll
    for (int e = 0; e < 8; e++) s += b2f((u16)v[e]);
  }
  s = wave_sum(s);
  if (lane == 0) ksum[bid] = s;
}

// reduce split-K ctx partials (8) + transpose -> ctxT (bh,64,288) bf16
__global__ void ctxred(const float* __restrict__ part, u16* __restrict__ ctxT)
{
  int bh = blockIdx.y;
  int m0 = blockIdx.x << 6;   // 5 tiles
  __shared__ float st[64][65];
  int t = threadIdx.x;
  int r = t >> 2, c = (t & 3) << 4;
  int m = m0 + r;
  v4f s[4] = {};
  if (m < M_PAD) {
    for (int ks = 0; ks < 8; ks++) {
      const float* p = part + (((long long)bh * 8 + ks) * M_ALLOC + m) * 64 + c;
#pragma unroll
      for (int j = 0; j < 4; j++) s[j] += *(const v4f*)(p + j * 4);
    }
  }
#pragma unroll
  for (int j = 0; j < 4; j++) *(v4f*)&st[r][c + j * 4] = s[j];
  __syncthreads();
  int e = t >> 2, mc = (t & 3) << 4;
  if (m0 + mc < M_PAD) {
    alignas(16) u16 tmp[16];
#pragma unroll
    for (int j = 0; j < 16; j++) tmp[j] = f2b(st[mc + j][e]);
    u16* op = ctxT + ((long long)bh * 64 + e) * M_PAD + m0 + mc;
    *(v8s*)op = *(v8s*)&tmp[0];
    *(v8s*)(op + 8) = *(v8s*)&tmp[8];
  }
}

// ---------------------------------------------------------------------------
extern "C" void kernel_launch(void* const* d_in, const int* in_sizes, int n_in,
                              void* d_out, int out_size, void* d_ws, size_t ws_size,
                              hipStream_t stream)
{
  const float* x_in = (const float*)d_in[0];
  const float* Wq  = (const float*)d_in[1];
  const float* Wk  = (const float*)d_in[2];
  const float* Wv  = (const float*)d_in[3];
  const float* Wo  = (const float*)d_in[4];
  const float* Pr  = (const float*)d_in[5];
  const float* ln1g = (const float*)d_in[6];
  const float* ln1b = (const float*)d_in[7];
  const float* W1  = (const float*)d_in[8];
  const float* b1  = (const float*)d_in[9];
  const float* W2  = (const float*)d_in[10];
  const float* b2  = (const float*)d_in[11];
  const float* ln2g = (const float*)d_in[12];
  const float* ln2b = (const float*)d_in[13];
  const float* lnfg = (const float*)d_in[14];
  const float* lnfb = (const float*)d_in[15];

  char* ws = (char*)d_ws;
  size_t off = 0;
  auto alloc = [&](size_t bytes) -> void* {
    void* p = ws + off;
    off = (off + bytes + 255) & ~(size_t)255;
    return p;
  };

  float* x      = (float*)alloc((size_t)ROWS * D_MODEL * 4);
  float* tsin   = (float*)alloc((size_t)N_SEQ * 32 * 4);
  float* tcos   = (float*)alloc((size_t)N_SEQ * 32 * 4);
  u16*   wqkvT  = (u16*)alloc((size_t)N_LAYER * 1536 * 512 * 2);
  u16*   woT    = (u16*)alloc((size_t)N_LAYER * 512 * 512 * 2);
  u16*   w1T    = (u16*)alloc((size_t)N_LAYER * 2048 * 512 * 2);
  u16*   w2T    = (u16*)alloc((size_t)N_LAYER * 512 * 2048 * 2);
  u16*   projT  = (u16*)alloc((size_t)N_LAYER * M_ALLOC * 64 * 2);
  u16*   hbuf   = (u16*)alloc((size_t)ROWS * D_MODEL * 2);
  u16*   obuf   = (u16*)alloc((size_t)ROWS * D_MODEL * 2);
  float* big    = (float*)alloc((size_t)32 * N_SEQ * M_PAD * 4);   // qkv_pre bf16 / dd f32
  u16*   qrbuf  = (u16*)alloc((size_t)BHN * 64 * 2);
  u16*   krbuf  = (u16*)alloc((size_t)BHN * 64 * 2);
  u16*   vTbuf  = (u16*)alloc((size_t)BHN * 64 * 2);
  float* diagq  = (float*)alloc((size_t)BHN * 4);
  float* diagk  = (float*)alloc((size_t)BHN * 4);
  unsigned int* kmaxu = (unsigned int*)alloc(256);
  u16*   kfT    = (u16*)alloc((size_t)32 * M_ALLOC * N_SEQ * 2);   // also qf buffer
  float* part   = (float*)alloc((size_t)32 * 8 * M_ALLOC * 64 * 4);
  u16*   ctxT   = (u16*)alloc((size_t)32 * 64 * M_PAD * 2);
  float* ksum   = (float*)alloc((size_t)32 * M_PAD * 4);
  (void)alloc(1 << 20);  // guard region for benign OOB tile reads
  (void)ws_size; (void)in_sizes; (void)n_in; (void)out_size;

  // ---- setup ----
  posadd<<<16384, 256, 0, stream>>>(x_in, x);
  rotab<<<1024, 64, 0, stream>>>(tsin, tcos);
  wtrans<<<dim3(8, 8, 6), 256, 0, stream>>>(Wq, wqkvT, 512, 512, 512LL * 512, 1536LL * 512);
  wtrans<<<dim3(8, 8, 6), 256, 0, stream>>>(Wk, wqkvT + 512LL * 512, 512, 512, 512LL * 512, 1536LL * 512);
  wtrans<<<dim3(8, 8, 6), 256, 0, stream>>>(Wv, wqkvT + 1024LL * 512, 512, 512, 512LL * 512, 1536LL * 512);
  wtrans<<<dim3(8, 8, 6), 256, 0, stream>>>(Wo, woT, 512, 512, 512LL * 512, 512LL * 512);
  wtrans<<<dim3(32, 8, 6), 256, 0, stream>>>(W1, w1T, 512, 2048, 512LL * 2048, 2048LL * 512);
  wtrans<<<dim3(8, 32, 6), 256, 0, stream>>>(W2, w2T, 2048, 512, 2048LL * 512, 512LL * 2048);
  projconv<<<(N_LAYER * M_ALLOC * 64) / 256, 256, 0, stream>>>(Pr, projT);

  for (int l = 0; l < N_LAYER; l++) {
    const u16* wq = wqkvT + (long long)l * 1536 * 512;
    const u16* wo = woT + (long long)l * 512 * 512;
    const u16* w1 = w1T + (long long)l * 2048 * 512;
    const u16* w2 = w2T + (long long)l * 512 * 2048;
    const u16* pj = projT + (long long)l * M_ALLOC * 64;

    resetmax<<<1, 1, 0, stream>>>(kmaxu);
    // LN1 -> h
    ln_kernel<false><<<ROWS / 4, 256, 0, stream>>>(x, ln1g + l * 512, ln1b + l * 512, hbuf);
    // qkv_pre = h @ Wqkv^T  (8192 x 1536, K=512)
    gemm2<0, 128, 1><<<dim3(64, 12, 1), 256, 0, stream>>>(hbuf, wq, big, nullptr,
        512, 1536, 0, 0, 0, 1.0f, 1536, ROWS, nullptr);
    rotary_kernel<<<BHN / 4, 256, 0, stream>>>((u16*)big, tsin, tcos, qrbuf, krbuf, diagq, diagk);
    vtrans<<<1024, 256, 0, stream>>>((u16*)big, vTbuf);
    // dd_k (one 65536 x 288 GEMM, K=64) + fused global max
    gemm2<6, 128, 1><<<dim3(512, 3, 1), 256, 0, stream>>>(krbuf, pj, big, nullptr,
        64, M_PAD, 0, 0, 0, 0.35355339f, M_PAD, BHN, kmaxu);
    kfprep<<<dim3(32, 5, 32), 256, 0, stream>>>(big, diagk, kmaxu, kfT);
    ksumk<<<32 * M_PAD / 4, 256, 0, stream>>>(kfT, ksum);
    // ctx = kf^T @ v  split-K=8: (384x64 per bh, K=2048)
    gemm2<5, 64, 8><<<dim3(3, 1, 256), 256, 0, stream>>>(kfT, vTbuf, part, nullptr,
        2048, 64, (long long)M_ALLOC * N_SEQ, 64LL * N_SEQ, 0, 1.0f, 64, M_PAD, nullptr);
    ctxred<<<dim3(5, 32), 256, 0, stream>>>(part, ctxT);
    // fused dd_q -> qf (writes qf into kfT buffer, stride M_PAD)
    ddq_qf<<<dim3(32, 1, 32), 512, 0, stream>>>(qrbuf, pj, diagq, ksum, kfT);
    // o = qf @ ctx^T  (2048 x 64 per bh, K=288) -> head scatter
    gemm2<4, 64, 1><<<dim3(16, 1, 32), 256, 0, stream>>>(kfT, ctxT, obuf, nullptr,
        M_PAD, 0, (long long)N_SEQ * M_PAD, 64LL * M_PAD, 0, 1.0f, 64, N_SEQ, nullptr);
    // x += o @ Wo^T
    gemm2<2, 64, 1><<<dim3(64, 8, 1), 256, 0, stream>>>(obuf, wo, x, nullptr,
        512, 512, 0, 0, 0, 1.0f, 512, ROWS, nullptr);
    // LN2 -> h
    ln_kernel<false><<<ROWS / 4, 256, 0, stream>>>(x, ln2g + l * 512, ln2b + l * 512, hbuf);
    // ff = gelu(h @ W1^T + b1)
    gemm2<3, 128, 1><<<dim3(64, 16, 1), 256, 0, stream>>>(hbuf, w1, big, b1 + (long long)l * 2048,
        512, 2048, 0, 0, 0, 1.0f, 2048, ROWS, nullptr);
    // x += ff @ W2^T + b2
    gemm2<2, 64, 1><<<dim3(64, 8, 1), 256, 0, stream>>>((u16*)big, w2, x, b2 + (long long)l * 512,
        2048, 512, 0, 0, 0, 1.0f, 512, ROWS, nullptr);
  }

  ln_kernel<true><<<ROWS / 4, 256, 0, stream>>>(x, lnfg, lnfb, d_out);
}

// Round 4
// 1679.057 us; speedup vs baseline: 1.4185x; 1.0975x over previous
//
#include <hip/hip_runtime.h>
#include <hip/hip_bf16.h>
#include <cstdint>

typedef float v4f __attribute__((ext_vector_type(4)));
typedef short v8s __attribute__((ext_vector_type(8)));
typedef unsigned short u16;

#define N_SEQ 2048
#define D_MODEL 512
#define N_LAYER 6
#define N_HEAD 8
#define D_HEAD 64
#define M_FEAT 266
#define M_PAD 288
#define M_ALLOC 384
#define FF_DIM 2048
#define BATCH 4
#define ROWS 8192
#define BHN 65536   // B*H*N

__device__ __forceinline__ float b2f(u16 u) {
  return __uint_as_float(((uint32_t)u) << 16);
}
__device__ __forceinline__ u16 f2b(float f) {
  union { __hip_bfloat16 h; u16 u; } c;
  c.h = __float2bfloat16(f);
  return c.u;
}
__device__ __forceinline__ float wave_sum(float v) {
#pragma unroll
  for (int o = 1; o < 64; o <<= 1) v += __shfl_xor(v, o);
  return v;
}
__device__ __forceinline__ float wave_max(float v) {
#pragma unroll
  for (int o = 1; o < 64; o <<= 1) v = fmaxf(v, __shfl_xor(v, o));
  return v;
}

__device__ __forceinline__ void mfma_bf16(v4f& d, v8s a, v8s b) {
  asm volatile("v_mfma_f32_16x16x32_bf16 %0, %1, %2, %0" : "+v"(d) : "v"(a), "v"(b));
}

// async global->LDS, 16B per lane. LDS dest must be wave-linear (base + lane*16).
__device__ __forceinline__ void async16(const u16* g, u16* l) {
  __builtin_amdgcn_global_load_lds(
      (const __attribute__((address_space(1))) uint32_t*)g,
      (__attribute__((address_space(3))) uint32_t*)l, 16, 0, 0);
}

// ---------------------------------------------------------------------------
// gemm2: C[M x N] = A[M x K] * B^T, BM=128 fixed, BN in {64,128}.
// 256 threads (4 waves, 2x2), double-buffered LDS via global_load_lds.
// EPI: 5 = f32 split-K partial; 6 = f32 dd*scale store + fused global atomicMax
// ---------------------------------------------------------------------------
template <int EPI, int BN, int KSPLIT>
__global__ void __launch_bounds__(256, 4)
gemm2(const u16* __restrict__ A, const u16* __restrict__ B,
      void* __restrict__ Cv, const float* __restrict__ bias,
      int K, int ldc, long long sA, long long sB, long long sC,
      float scale, int Ncap, int Mcap, unsigned int* __restrict__ gmax)
{
  __shared__ u16 As[2][128 * 32];
  __shared__ u16 Bs[2][BN * 32];
  __shared__ float smax[4];
  const int zz = blockIdx.z;
  const int z = (KSPLIT > 1) ? zz / KSPLIT : zz;
  const int ks = (KSPLIT > 1) ? zz % KSPLIT : 0;
  const int kchunk = K / KSPLIT;
  const u16* Ag = A + (long long)z * sA + ks * kchunk;
  const u16* Bg = B + (long long)z * sB + ks * kchunk;
  const int t = threadIdx.x;
  const int lane = t & 63;
  const int w = t >> 6;
  constexpr int NF = BN / 32;
  const int wm = (w >> 1) << 6;
  const int wn = (w & 1) * (BN / 2);
  const int tiM = blockIdx.x << 7, tiN = blockIdx.y * BN;

  const int srow = t >> 2;
  const int scol = (t & 3) << 3;
  const u16* Ap = Ag + (long long)(tiM + srow) * K + scol;
  const u16* Bp = Bg + (long long)(tiN + srow) * K + scol;
  const long long rstride = 64LL * K;

  const int rr = lane & 15;
  const int kc = (lane >> 4) << 3;

  v4f acc[4][NF] = {};

  const int nk = kchunk >> 5;
  auto stage = [&](int buf, int k0) {
    async16(Ap + k0, &As[buf][t * 8]);
    async16(Ap + k0 + rstride, &As[buf][t * 8 + 2048]);
    async16(Bp + k0, &Bs[buf][t * 8]);
    if (BN == 128) async16(Bp + k0 + rstride, &Bs[buf][t * 8 + 2048]);
  };

  stage(0, 0);
  __syncthreads();
  int cur = 0;
  for (int kt = 0; kt < nk; ++kt) {
    if (kt + 1 < nk) stage(cur ^ 1, (kt + 1) << 5);
    v8s af[4], bf[NF];
#pragma unroll
    for (int i = 0; i < 4; i++) af[i] = *(const v8s*)&As[cur][(wm + rr + i * 16) * 32 + kc];
#pragma unroll
    for (int i = 0; i < NF; i++) bf[i] = *(const v8s*)&Bs[cur][(wn + rr + i * 16) * 32 + kc];
#pragma unroll
    for (int fm = 0; fm < 4; fm++)
#pragma unroll
      for (int fn = 0; fn < NF; fn++)
        mfma_bf16(acc[fm][fn], af[fm], bf[fn]);
    __syncthreads();
    cur ^= 1;
  }

  __builtin_amdgcn_sched_barrier(0);
  asm volatile("s_nop 7\ns_nop 7\ns_nop 7");
  __builtin_amdgcn_sched_barrier(0);

  const int r4 = (lane >> 4) << 2;
  const int cc = lane & 15;
  float lmax = -3e38f;
#pragma unroll
  for (int fm = 0; fm < 4; fm++)
#pragma unroll
    for (int fn = 0; fn < NF; fn++)
#pragma unroll
      for (int i = 0; i < 4; i++) {
        int row = tiM + wm + fm * 16 + r4 + i;
        int col = tiN + wn + fn * 16 + cc;
        float v = acc[fm][fn][i];
        if (EPI == 5) {
          if (row < Mcap && col < Ncap)
            ((float*)Cv)[((long long)zz * M_ALLOC + row) * 64 + col] = v;
        } else if (EPI == 6) {
          float sv = v * scale;
          if (col < Ncap) ((float*)Cv)[(long long)row * ldc + col] = sv;
          if (col < M_FEAT) lmax = fmaxf(lmax, sv);
        }
      }

  if (EPI == 6) {
    lmax = wave_max(lmax);
    if (lane == 0) smax[w] = lmax;
    __syncthreads();
    if (t == 0) {
      float m = fmaxf(fmaxf(smax[0], smax[1]), fmaxf(smax[2], smax[3]));
      unsigned int u = __float_as_uint(m);
      unsigned int key = (u & 0x80000000u) ? ~u : (u | 0x80000000u);
      atomicMax(gmax, key);
    }
  }
}

// ---------------------------------------------------------------------------
// gemm_small: BM=64, BN=64, BK=32, 4 waves (2x2 of 32x32), 16KB LDS,
// high-occupancy variant for the dense GEMMs.
// EPI: 0 = bf16 out; 2 = f32 residual += acc + bias; 3 = bf16 gelu(acc+bias);
//      4 = bf16 head-scatter.
// ---------------------------------------------------------------------------
template <int EPI>
__global__ void __launch_bounds__(256, 6)
gemm_small(const u16* __restrict__ A, const u16* __restrict__ B,
           void* __restrict__ Cv, const float* __restrict__ bias,
           int K, int ldc, long long sA, long long sB)
{
  __shared__ u16 As[2][64 * 32];
  __shared__ u16 Bs[2][64 * 32];
  const int z = blockIdx.z;
  const u16* Ag = A + (long long)z * sA;
  const u16* Bg = B + (long long)z * sB;
  const int t = threadIdx.x;
  const int lane = t & 63;
  const int w = t >> 6;
  const int wm = (w >> 1) << 5;
  const int wn = (w & 1) << 5;
  const int tiM = blockIdx.x << 6, tiN = blockIdx.y << 6;

  const int srow = t >> 2;
  const int scol = (t & 3) << 3;
  const u16* Ap = Ag + (long long)(tiM + srow) * K + scol;
  const u16* Bp = Bg + (long long)(tiN + srow) * K + scol;

  const int rr = lane & 15;
  const int kc = (lane >> 4) << 3;

  v4f acc[2][2] = {};

  const int nk = K >> 5;
  auto stage = [&](int buf, int k0) {
    async16(Ap + k0, &As[buf][t * 8]);
    async16(Bp + k0, &Bs[buf][t * 8]);
  };

  stage(0, 0);
  __syncthreads();
  int cur = 0;
  for (int kt = 0; kt < nk; ++kt) {
    if (kt + 1 < nk) stage(cur ^ 1, (kt + 1) << 5);
    v8s af[2], bf[2];
#pragma unroll
    for (int i = 0; i < 2; i++) af[i] = *(const v8s*)&As[cur][(wm + rr + i * 16) * 32 + kc];
#pragma unroll
    for (int i = 0; i < 2; i++) bf[i] = *(const v8s*)&Bs[cur][(wn + rr + i * 16) * 32 + kc];
#pragma unroll
    for (int fm = 0; fm < 2; fm++)
#pragma unroll
      for (int fn = 0; fn < 2; fn++)
        mfma_bf16(acc[fm][fn], af[fm], bf[fn]);
    __syncthreads();
    cur ^= 1;
  }

  __builtin_amdgcn_sched_barrier(0);
  asm volatile("s_nop 7\ns_nop 7\ns_nop 7");
  __builtin_amdgcn_sched_barrier(0);

  const int r4 = (lane >> 4) << 2;
  const int cc = lane & 15;
#pragma unroll
  for (int fm = 0; fm < 2; fm++)
#pragma unroll
    for (int fn = 0; fn < 2; fn++)
#pragma unroll
      for (int i = 0; i < 4; i++) {
        int row = tiM + wm + fm * 16 + r4 + i;
        int col = tiN + wn + fn * 16 + cc;
        float v = acc[fm][fn][i];
        if (EPI == 0) {
          ((u16*)Cv)[(long long)row * ldc + col] = f2b(v);
        } else if (EPI == 2) {
          long long idx = (long long)row * ldc + col;
          float bb = bias ? bias[col] : 0.0f;
          ((float*)Cv)[idx] += v + bb;
        } else if (EPI == 3) {
          float hv = v + bias[col];
          float gg = 0.5f * hv * (1.0f + erff(hv * 0.70710678118f));
          ((u16*)Cv)[(long long)row * ldc + col] = f2b(gg);
        } else {  // EPI == 4: head scatter (N=64 per z)
          int b_ = z >> 3, h_ = z & 7;
          ((u16*)Cv)[(long long)(b_ * N_SEQ + row) * 512 + h_ * 64 + col] = f2b(v);
        }
      }
}

// ---------------------------------------------------------------------------
// Fused dd_q -> row-max -> exp -> denominator -> qf (bf16, d_inv folded).
// ---------------------------------------------------------------------------
__global__ void __launch_bounds__(512, 2)
ddq_qf(const u16* __restrict__ qr, const u16* __restrict__ proj,
       const float* __restrict__ diag, const float* __restrict__ ksum,
       u16* __restrict__ qf)
{
  __shared__ u16 As[2][64 * 32];
  __shared__ u16 Bs[2][384 * 32];
  __shared__ float red[2][8][64];
  const int bh = blockIdx.z;
  const int tiM = blockIdx.x << 6;
  const int t = threadIdx.x;
  const int lane = t & 63;
  const int w = t >> 6;
  const u16* Ag = qr + (long long)bh * (N_SEQ * 64);
  const int srow = t >> 2, scol = (t & 3) << 3;
  const u16* Ap = Ag + (long long)(tiM + srow) * 64 + scol;
  const u16* Bp = proj + (long long)srow * 64 + scol;
  const int rr = lane & 15, kc = (lane >> 4) << 3;
  const int wn = w * 48;

  v4f acc[4][3] = {};
  auto stage = [&](int buf, int k0) {
    if (t < 256) async16(Ap + k0, &As[buf][t * 8]);
#pragma unroll
    for (int i = 0; i < 3; i++)
      async16(Bp + k0 + (long long)i * (128 * 64), &Bs[buf][t * 8 + i * 4096]);
  };

  stage(0, 0);
  __syncthreads();
  for (int kt = 0; kt < 2; ++kt) {
    if (kt == 0) stage(1, 32);
    v8s af[4], bf[3];
#pragma unroll
    for (int i = 0; i < 4; i++) af[i] = *(const v8s*)&As[kt][(rr + i * 16) * 32 + kc];
#pragma unroll
    for (int i = 0; i < 3; i++) bf[i] = *(const v8s*)&Bs[kt][(wn + rr + i * 16) * 32 + kc];
#pragma unroll
    for (int fm = 0; fm < 4; fm++)
#pragma unroll
      for (int fn = 0; fn < 3; fn++)
        mfma_bf16(acc[fm][fn], af[fm], bf[fn]);
    __syncthreads();
  }

  __builtin_amdgcn_sched_barrier(0);
  asm volatile("s_nop 7\ns_nop 7\ns_nop 7");
  __builtin_amdgcn_sched_barrier(0);

  const int r4 = (lane >> 4) << 2;
  const int cc = lane & 15;
  const float sc = 0.35355339f;

#pragma unroll
  for (int fm = 0; fm < 4; fm++)
#pragma unroll
    for (int i = 0; i < 4; i++) {
      float m = -3e38f;
#pragma unroll
      for (int fn = 0; fn < 3; fn++) {
        int col = wn + fn * 16 + cc;
        float v = acc[fm][fn][i] * sc;
        if (col < M_FEAT) m = fmaxf(m, v);
      }
#pragma unroll
      for (int o = 1; o < 16; o <<= 1) m = fmaxf(m, __shfl_xor(m, o));
      if (cc == 0) red[0][w][fm * 16 + r4 + i] = m;
    }
  __syncthreads();

  float ksv[3];
#pragma unroll
  for (int fn = 0; fn < 3; fn++) {
    int col = wn + fn * 16 + cc;
    ksv[fn] = (col < M_PAD) ? ksum[bh * M_PAD + col] : 0.0f;
  }

#pragma unroll
  for (int fm = 0; fm < 4; fm++)
#pragma unroll
    for (int i = 0; i < 4; i++) {
      int row = fm * 16 + r4 + i;
      float gm = red[0][0][row];
#pragma unroll
      for (int ww = 1; ww < 8; ww++) gm = fmaxf(gm, red[0][ww][row]);
      float dg = diag[(long long)bh * N_SEQ + tiM + row];
      float s = 0.0f;
#pragma unroll
      for (int fn = 0; fn < 3; fn++) {
        int col = wn + fn * 16 + cc;
        float v = acc[fm][fn][i] * sc;
        float e = (col < M_FEAT) ? 0.06131389f * (expf(v - dg - gm) + 1e-4f) : 0.0f;
        acc[fm][fn][i] = e;
        s += e * ksv[fn];
      }
#pragma unroll
      for (int o = 1; o < 16; o <<= 1) s += __shfl_xor(s, o);
      if (cc == 0) red[1][w][row] = s;
    }
  __syncthreads();

#pragma unroll
  for (int fm = 0; fm < 4; fm++)
#pragma unroll
    for (int i = 0; i < 4; i++) {
      int row = fm * 16 + r4 + i;
      float s = 0.0f;
#pragma unroll
      for (int ww = 0; ww < 8; ww++) s += red[1][ww][row];
      float dinv = 1.0f / s;
#pragma unroll
      for (int fn = 0; fn < 3; fn++) {
        int col = wn + fn * 16 + cc;
        if (col < M_PAD)
          qf[((long long)bh * N_SEQ + tiM + row) * M_PAD + col] =
              f2b(acc[fm][fn][i] * dinv);
      }
    }
}

// ---------------------------------------------------------------------------
template <bool F32OUT>
__global__ void ln_kernel(const float* __restrict__ x, const float* __restrict__ g,
                          const float* __restrict__ b, void* __restrict__ out)
{
  const int row = blockIdx.x * 4 + (threadIdx.x >> 6);
  const int lane = threadIdx.x & 63;
  const float* xr = x + (long long)row * D_MODEL + lane * 8;
  v4f v0 = *(const v4f*)xr;
  v4f v1 = *(const v4f*)(xr + 4);
  float s = v0[0] + v0[1] + v0[2] + v0[3] + v1[0] + v1[1] + v1[2] + v1[3];
  float sq = v0[0]*v0[0] + v0[1]*v0[1] + v0[2]*v0[2] + v0[3]*v0[3]
           + v1[0]*v1[0] + v1[1]*v1[1] + v1[2]*v1[2] + v1[3]*v1[3];
  s = wave_sum(s);
  sq = wave_sum(sq);
  float mu = s * (1.0f / D_MODEL);
  float var = sq * (1.0f / D_MODEL) - mu * mu;
  float rstd = rsqrtf(var + 1e-5f);
  v4f g0 = *(const v4f*)(g + lane * 8), g1 = *(const v4f*)(g + lane * 8 + 4);
  v4f bb0 = *(const v4f*)(b + lane * 8), bb1 = *(const v4f*)(b + lane * 8 + 4);
  float y[8];
#pragma unroll
  for (int j = 0; j < 4; j++) y[j] = (v0[j] - mu) * rstd * g0[j] + bb0[j];
#pragma unroll
  for (int j = 0; j < 4; j++) y[4 + j] = (v1[j] - mu) * rstd * g1[j] + bb1[j];
  if (F32OUT) {
    float* op = (float*)out + (long long)row * D_MODEL + lane * 8;
    v4f o0 = {y[0], y[1], y[2], y[3]}, o1 = {y[4], y[5], y[6], y[7]};
    *(v4f*)op = o0;
    *(v4f*)(op + 4) = o1;
  } else {
    u16* op = (u16*)out + (long long)row * D_MODEL + lane * 8;
    alignas(16) u16 tmp[8];
#pragma unroll
    for (int j = 0; j < 8; j++) tmp[j] = f2b(y[j]);
    *(v8s*)op = *(v8s*)tmp;
  }
}

__global__ void posadd(const float* __restrict__ xin, float* __restrict__ x)
{
  long long i = (long long)blockIdx.x * 256 + threadIdx.x;
  int d = (int)(i & 511);
  int n = (int)((i >> 9) & 2047);
  int j = d & 255;
  float sarg = (float)n * expf(-0.035977892f * (float)j);
  float pe = (d < 256) ? sinf(sarg) : cosf(sarg);
  x[i] = xin[i] + pe;
}

__global__ void rotab(float* __restrict__ ts, float* __restrict__ tc)
{
  int i = blockIdx.x * 64 + threadIdx.x;  // 2048*32
  int n = i >> 5, j = i & 31;
  float sarg = (float)n * expf(-0.28782314f * (float)j);
  float s, c;
  sincosf(sarg, &s, &c);
  ts[i] = s;
  tc[i] = c;
}

__global__ void rotary_kernel(const u16* __restrict__ qkv,
                              const float* __restrict__ ts, const float* __restrict__ tc,
                              u16* __restrict__ qr, u16* __restrict__ kr,
                              float* __restrict__ dq, float* __restrict__ dk)
{
  int bid = blockIdx.x * 4 + (threadIdx.x >> 6);
  int n = bid & 2047;
  int h = (bid >> 11) & 7;
  int b = bid >> 14;
  int lane = threadIdx.x & 63;
  long long src = ((long long)(b * N_SEQ + n)) * 1536 + h * 64 + lane;
  float qv = b2f(qkv[src]);
  float kv = b2f(qkv[src + 512]);
  int j = lane >> 1;
  float sn = ts[n * 32 + j], cn = tc[n * 32 + j];
  float qp = __shfl_xor(qv, 1), kp = __shfl_xor(kv, 1);
  float qrv = (lane & 1) ? (qv * cn + qp * sn) : (qv * cn - qp * sn);
  float krv = (lane & 1) ? (kv * cn + kp * sn) : (kv * cn - kp * sn);
  u16 qb = f2b(qrv), kb = f2b(krv);
  long long dst = ((long long)bid) * 64 + lane;
  qr[dst] = qb;
  kr[dst] = kb;
  float q2 = b2f(qb); q2 *= q2;
  float k2 = b2f(kb); k2 *= k2;
  q2 = wave_sum(q2);
  k2 = wave_sum(k2);
  if (lane == 0) { dq[bid] = q2 * 0.0625f; dk[bid] = k2 * 0.0625f; }
}

__global__ void vtrans(const u16* __restrict__ qkv, u16* __restrict__ vT)
{
  int bid = blockIdx.x;  // B*H*32
  int nt = bid & 31;
  int h = (bid >> 5) & 7;
  int b = bid >> 8;
  __shared__ u16 st[64][72];
  int t = threadIdx.x;
  int r = t >> 2, c = (t & 3) << 4;
  long long src = ((long long)(b * N_SEQ + nt * 64 + r)) * 1536 + 1024 + h * 64 + c;
  *(v8s*)&st[r][c] = *(const v8s*)(qkv + src);
  *(v8s*)&st[r][c + 8] = *(const v8s*)(qkv + src + 8);
  __syncthreads();
  alignas(16) u16 tmp[16];
#pragma unroll
  for (int jj = 0; jj < 16; jj++) tmp[jj] = st[c + jj][r];
  long long dst = ((long long)((b * 8 + h) * 64 + r)) * N_SEQ + nt * 64 + c;
  *(v8s*)(vT + dst) = *(v8s*)&tmp[0];
  *(v8s*)(vT + dst + 8) = *(v8s*)&tmp[8];
}

__global__ void wtrans(const float* __restrict__ src, u16* __restrict__ dst,
                       int Ks, int Ns, long long sSrc, long long sDst)
{
  int l = blockIdx.z;
  src += (long long)l * sSrc;
  dst += (long long)l * sDst;
  int n0 = blockIdx.x << 6, k0 = blockIdx.y << 6;
  __shared__ float st[64][68];
  int t = threadIdx.x;
  int r = t >> 2, c = (t & 3) << 4;
  const float* sp = src + (long long)(k0 + r) * Ns + n0 + c;
#pragma unroll
  for (int jj = 0; jj < 16; jj += 4) *(v4f*)&st[r][c + jj] = *(const v4f*)(sp + jj);
  __syncthreads();
  alignas(16) u16 tmp[16];
#pragma unroll
  for (int jj = 0; jj < 16; jj++) tmp[jj] = f2b(st[c + jj][r]);
  u16* dp = dst + (long long)(n0 + r) * Ks + k0 + c;
  *(v8s*)(dp) = *(v8s*)&tmp[0];
  *(v8s*)(dp + 8) = *(v8s*)&tmp[8];
}

__global__ void projconv(const float* __restrict__ proj, u16* __restrict__ out)
{
  int i = blockIdx.x * 256 + threadIdx.x;  // 6*384*64
  int dh = i & 63;
  int m = (i >> 6) % M_ALLOC;
  int l = i / (M_ALLOC * 64);
  float v = (m < M_FEAT) ? proj[((long long)l * M_FEAT + m) * 64 + dh] : 0.0f;
  out[i] = f2b(v);
}

__global__ void resetmax(unsigned int* p) { *p = 0u; }

// ---------------------------------------------------------------------------
// kfprep: dd_k (bh,n,288) f32 -> kfT (bh,384,2048) bf16 + per-tile ksum partials.
// Conflict-free f32 LDS [64][65]; vectorized loads/stores.
// ---------------------------------------------------------------------------
__global__ void kfprep(const float* __restrict__ dd, const float* __restrict__ diag,
                       const unsigned int* __restrict__ kmax,
                       u16* __restrict__ kfT, float* __restrict__ part)
{
  int ntile = blockIdx.x;          // 32
  int m0 = blockIdx.y << 6;        // 5 tiles (0..319, cap 288)
  int bh = blockIdx.z;             // 32
  int n0 = ntile << 6;
  __shared__ float st[64][65];
  unsigned int kk = kmax[0];
  float km = (kk & 0x80000000u) ? __uint_as_float(kk ^ 0x80000000u)
                                : __uint_as_float(~kk);
  int t = threadIdx.x;
  int r = t >> 2, c = (t & 3) << 4;
  const float* dp = dd + ((long long)bh * N_SEQ + n0 + r) * M_PAD + m0 + c;
  float dg = diag[(long long)bh * N_SEQ + n0 + r];
  float vals[16];
  if (m0 + c + 16 <= M_PAD) {
#pragma unroll
    for (int j = 0; j < 16; j += 4) *(v4f*)&vals[j] = *(const v4f*)(dp + j);
  } else {
#pragma unroll
    for (int j = 0; j < 16; j++) vals[j] = (m0 + c + j < M_PAD) ? dp[j] : 0.0f;
  }
#pragma unroll
  for (int j = 0; j < 16; j++) {
    int m = m0 + c + j;
    float e = (m < M_FEAT) ? 0.06131389f * (expf(vals[j] - dg - km) + 1e-4f) : 0.0f;
    st[r][c + j] = e;
  }
  __syncthreads();
  int mr = t >> 2, nc = (t & 3) << 4;
  float s = 0.0f;
  alignas(16) u16 tmp[16];
#pragma unroll
  for (int j = 0; j < 16; j++) {
    float e = st[nc + j][mr];
    s += e;
    tmp[j] = f2b(e);
  }
  s += __shfl_xor(s, 1);
  s += __shfl_xor(s, 2);
  int m = m0 + mr;
  if (m < M_PAD) {
    u16* op = kfT + ((long long)bh * M_ALLOC + m) * N_SEQ + n0 + nc;
    *(v8s*)op = *(v8s*)&tmp[0];
    *(v8s*)(op + 8) = *(v8s*)&tmp[8];
    if ((t & 3) == 0)
      part[((long long)bh * M_PAD + m) * 32 + ntile] = s;
  }
}

// ksum[bh][m] = sum of 32 partials
__global__ void ksumred(const float* __restrict__ part, float* __restrict__ ksum)
{
  int i = blockIdx.x * 256 + threadIdx.x;  // 32*288
  if (i >= 32 * M_PAD) return;
  const float* p = part + (long long)i * 32;
  float s = 0.0f;
#pragma unroll
  for (int j = 0; j < 32; j += 4) {
    v4f v = *(const v4f*)(p + j);
    s += v[0] + v[1] + v[2] + v[3];
  }
  ksum[i] = s;
}

// reduce split-K ctx partials (8) + transpose -> ctxT (bh,64,288) bf16
__global__ void ctxred(const float* __restrict__ part, u16* __restrict__ ctxT)
{
  int bh = blockIdx.y;
  int m0 = blockIdx.x << 6;   // 5 tiles
  __shared__ float st[64][65];
  int t = threadIdx.x;
  int r = t >> 2, c = (t & 3) << 4;
  int m = m0 + r;
  v4f s[4] = {};
  if (m < M_PAD) {
    for (int ks = 0; ks < 8; ks++) {
      const float* p = part + (((long long)bh * 8 + ks) * M_ALLOC + m) * 64 + c;
#pragma unroll
      for (int j = 0; j < 4; j++) s[j] += *(const v4f*)(p + j * 4);
    }
  }
#pragma unroll
  for (int j = 0; j < 4; j++)
#pragma unroll
    for (int e = 0; e < 4; e++) st[r][c + j * 4 + e] = s[j][e];
  __syncthreads();
  int e = t >> 2, mc = (t & 3) << 4;
  if (m0 + mc < M_PAD) {
    alignas(16) u16 tmp[16];
#pragma unroll
    for (int j = 0; j < 16; j++) tmp[j] = f2b(st[mc + j][e]);
    u16* op = ctxT + ((long long)bh * 64 + e) * M_PAD + m0 + mc;
    *(v8s*)op = *(v8s*)&tmp[0];
    *(v8s*)(op + 8) = *(v8s*)&tmp[8];
  }
}

// ---------------------------------------------------------------------------
extern "C" void kernel_launch(void* const* d_in, const int* in_sizes, int n_in,
                              void* d_out, int out_size, void* d_ws, size_t ws_size,
                              hipStream_t stream)
{
  const float* x_in = (const float*)d_in[0];
  const float* Wq  = (const float*)d_in[1];
  const float* Wk  = (const float*)d_in[2];
  const float* Wv  = (const float*)d_in[3];
  const float* Wo  = (const float*)d_in[4];
  const float* Pr  = (const float*)d_in[5];
  const float* ln1g = (const float*)d_in[6];
  const float* ln1b = (const float*)d_in[7];
  const float* W1  = (const float*)d_in[8];
  const float* b1  = (const float*)d_in[9];
  const float* W2  = (const float*)d_in[10];
  const float* b2  = (const float*)d_in[11];
  const float* ln2g = (const float*)d_in[12];
  const float* ln2b = (const float*)d_in[13];
  const float* lnfg = (const float*)d_in[14];
  const float* lnfb = (const float*)d_in[15];

  char* ws = (char*)d_ws;
  size_t off = 0;
  auto alloc = [&](size_t bytes) -> void* {
    void* p = ws + off;
    off = (off + bytes + 255) & ~(size_t)255;
    return p;
  };

  float* x      = (float*)alloc((size_t)ROWS * D_MODEL * 4);
  float* tsin   = (float*)alloc((size_t)N_SEQ * 32 * 4);
  float* tcos   = (float*)alloc((size_t)N_SEQ * 32 * 4);
  u16*   wqkvT  = (u16*)alloc((size_t)N_LAYER * 1536 * 512 * 2);
  u16*   woT    = (u16*)alloc((size_t)N_LAYER * 512 * 512 * 2);
  u16*   w1T    = (u16*)alloc((size_t)N_LAYER * 2048 * 512 * 2);
  u16*   w2T    = (u16*)alloc((size_t)N_LAYER * 512 * 2048 * 2);
  u16*   projT  = (u16*)alloc((size_t)N_LAYER * M_ALLOC * 64 * 2);
  u16*   hbuf   = (u16*)alloc((size_t)ROWS * D_MODEL * 2);
  u16*   obuf   = (u16*)alloc((size_t)ROWS * D_MODEL * 2);
  float* big    = (float*)alloc((size_t)32 * N_SEQ * M_PAD * 4);   // qkv_pre bf16 / dd f32
  u16*   qrbuf  = (u16*)alloc((size_t)BHN * 64 * 2);
  u16*   krbuf  = (u16*)alloc((size_t)BHN * 64 * 2);
  u16*   vTbuf  = (u16*)alloc((size_t)BHN * 64 * 2);
  float* diagq  = (float*)alloc((size_t)BHN * 4);
  float* diagk  = (float*)alloc((size_t)BHN * 4);
  unsigned int* kmaxu = (unsigned int*)alloc(256);
  u16*   kfT    = (u16*)alloc((size_t)32 * M_ALLOC * N_SEQ * 2);   // also qf buffer
  float* part   = (float*)alloc((size_t)32 * 8 * M_ALLOC * 64 * 4);
  float* kspart = (float*)alloc((size_t)32 * M_PAD * 32 * 4);
  u16*   ctxT   = (u16*)alloc((size_t)32 * 64 * M_PAD * 2);
  float* ksum   = (float*)alloc((size_t)32 * M_PAD * 4);
  (void)alloc(1 << 20);  // guard region for benign OOB tile reads
  (void)ws_size; (void)in_sizes; (void)n_in; (void)out_size;

  // ---- setup ----
  posadd<<<16384, 256, 0, stream>>>(x_in, x);
  rotab<<<1024, 64, 0, stream>>>(tsin, tcos);
  wtrans<<<dim3(8, 8, 6), 256, 0, stream>>>(Wq, wqkvT, 512, 512, 512LL * 512, 1536LL * 512);
  wtrans<<<dim3(8, 8, 6), 256, 0, stream>>>(Wk, wqkvT + 512LL * 512, 512, 512, 512LL * 512, 1536LL * 512);
  wtrans<<<dim3(8, 8, 6), 256, 0, stream>>>(Wv, wqkvT + 1024LL * 512, 512, 512, 512LL * 512, 1536LL * 512);
  wtrans<<<dim3(8, 8, 6), 256, 0, stream>>>(Wo, woT, 512, 512, 512LL * 512, 512LL * 512);
  wtrans<<<dim3(32, 8, 6), 256, 0, stream>>>(W1, w1T, 512, 2048, 512LL * 2048, 2048LL * 512);
  wtrans<<<dim3(8, 32, 6), 256, 0, stream>>>(W2, w2T, 2048, 512, 2048LL * 512, 512LL * 2048);
  projconv<<<(N_LAYER * M_ALLOC * 64) / 256, 256, 0, stream>>>(Pr, projT);

  for (int l = 0; l < N_LAYER; l++) {
    const u16* wq = wqkvT + (long long)l * 1536 * 512;
    const u16* wo = woT + (long long)l * 512 * 512;
    const u16* w1 = w1T + (long long)l * 2048 * 512;
    const u16* w2 = w2T + (long long)l * 512 * 2048;
    const u16* pj = projT + (long long)l * M_ALLOC * 64;

    resetmax<<<1, 1, 0, stream>>>(kmaxu);
    // LN1 -> h
    ln_kernel<false><<<ROWS / 4, 256, 0, stream>>>(x, ln1g + l * 512, ln1b + l * 512, hbuf);
    // qkv_pre = h @ Wqkv^T  (8192 x 1536, K=512)
    gemm_small<0><<<dim3(128, 24, 1), 256, 0, stream>>>(hbuf, wq, big, nullptr,
        512, 1536, 0, 0);
    rotary_kernel<<<BHN / 4, 256, 0, stream>>>((u16*)big, tsin, tcos, qrbuf, krbuf, diagq, diagk);
    vtrans<<<1024, 256, 0, stream>>>((u16*)big, vTbuf);
    // dd_k (65536 x 288, K=64) + fused global max
    gemm2<6, 128, 1><<<dim3(512, 3, 1), 256, 0, stream>>>(krbuf, pj, big, nullptr,
        64, M_PAD, 0, 0, 0, 0.35355339f, M_PAD, BHN, kmaxu);
    // kf^T + ksum partials
    kfprep<<<dim3(32, 5, 32), 256, 0, stream>>>(big, diagk, kmaxu, kfT, kspart);
    ksumred<<<(32 * M_PAD + 255) / 256, 256, 0, stream>>>(kspart, ksum);
    // ctx = kf^T @ v  split-K=8
    gemm2<5, 64, 8><<<dim3(3, 1, 256), 256, 0, stream>>>(kfT, vTbuf, part, nullptr,
        2048, 64, (long long)M_ALLOC * N_SEQ, 64LL * N_SEQ, 0, 1.0f, 64, M_PAD, nullptr);
    ctxred<<<dim3(5, 32), 256, 0, stream>>>(part, ctxT);
    // fused dd_q -> qf
    ddq_qf<<<dim3(32, 1, 32), 512, 0, stream>>>(qrbuf, pj, diagq, ksum, kfT);
    // o = qf @ ctx^T -> head scatter
    gemm_small<4><<<dim3(32, 1, 32), 256, 0, stream>>>(kfT, ctxT, obuf, nullptr,
        M_PAD, 0, (long long)N_SEQ * M_PAD, 64LL * M_PAD);
    // x += o @ Wo^T
    gemm_small<2><<<dim3(128, 8, 1), 256, 0, stream>>>(obuf, wo, x, nullptr,
        512, 512, 0, 0);
    // LN2 -> h
    ln_kernel<false><<<ROWS / 4, 256, 0, stream>>>(x, ln2g + l * 512, ln2b + l * 512, hbuf);
    // ff = gelu(h @ W1^T + b1)
    gemm_small<3><<<dim3(128, 32, 1), 256, 0, stream>>>(hbuf, w1, big, b1 + (long long)l * 2048,
        512, 2048, 0, 0);
    // x += ff @ W2^T + b2
    gemm_small<2><<<dim3(128, 8, 1), 256, 0, stream>>>((u16*)big, w2, x, b2 + (long long)l * 512,
        2048, 512, 0, 0);
  }

  ln_kernel<true><<<ROWS / 4, 256, 0, stream>>>(x, lnfg, lnfb, d_out);
}

// Round 5
// 1626.432 us; speedup vs baseline: 1.4644x; 1.0324x over previous
//
#include <hip/hip_runtime.h>
#include <hip/hip_bf16.h>
#include <cstdint>

typedef float v4f __attribute__((ext_vector_type(4)));
typedef short v8s __attribute__((ext_vector_type(8)));
typedef unsigned short u16;

#define N_SEQ 2048
#define D_MODEL 512
#define N_LAYER 6
#define N_HEAD 8
#define D_HEAD 64
#define M_FEAT 266
#define M_PAD 288
#define M_ALLOC 384
#define FF_DIM 2048
#define BATCH 4
#define ROWS 8192
#define BHN 65536   // B*H*N

__device__ __forceinline__ float b2f(u16 u) {
  return __uint_as_float(((uint32_t)u) << 16);
}
__device__ __forceinline__ u16 f2b(float f) {
  union { __hip_bfloat16 h; u16 u; } c;
  c.h = __float2bfloat16(f);
  return c.u;
}
__device__ __forceinline__ float wave_sum(float v) {
#pragma unroll
  for (int o = 1; o < 64; o <<= 1) v += __shfl_xor(v, o);
  return v;
}
__device__ __forceinline__ float wave_max(float v) {
#pragma unroll
  for (int o = 1; o < 64; o <<= 1) v = fmaxf(v, __shfl_xor(v, o));
  return v;
}

__device__ __forceinline__ void mfma_bf16(v4f& d, v8s a, v8s b) {
  asm volatile("v_mfma_f32_16x16x32_bf16 %0, %1, %2, %0" : "+v"(d) : "v"(a), "v"(b));
}

// async global->LDS, 16B per lane. LDS dest must be wave-linear (base + lane*16).
__device__ __forceinline__ void async16(const u16* g, u16* l) {
  __builtin_amdgcn_global_load_lds(
      (const __attribute__((address_space(1))) uint32_t*)g,
      (__attribute__((address_space(3))) uint32_t*)l, 16, 0, 0);
}

// ---------------------------------------------------------------------------
// gemm8p: 256x256 tile, BK=64, 512 threads (8 waves 2Mx4N), 8-phase schedule
// with counted staging, raw s_barrier, setprio around MFMA clusters, and
// st-swizzled LDS (inverse-swizzled global source + swizzled ds_read).
// C = A[M x K] * B^T (B stored [N x K]).  Dynamic LDS = 128 KiB.
// EPI: 0 = bf16 out; 3 = bf16 gelu(acc + bias).
// ---------------------------------------------------------------------------
template <int EPI>
__global__ void __launch_bounds__(512, 2)
gemm8p(const u16* __restrict__ A, const u16* __restrict__ B,
       void* __restrict__ Cv, const float* __restrict__ bias,
       int K, int ldc)
{
  extern __shared__ u16 lds[];   // [0..32767] A halves, [32768..65535] B halves
  const int t = threadIdx.x;
  const int lane = t & 63;
  const int w = t >> 6;
  const int wm = w >> 2;          // 0..1  (M half)
  const int wn = w & 3;           // 0..3  (N quarter)
  const int tiM = blockIdx.x << 8, tiN = blockIdx.y << 8;

  const int rr = lane & 15;
  const int kq = (lane >> 4) << 3;          // 0,8,16,24
  const int swz = (rr & 7) << 3;            // read-side XOR (row&7)*8
  const int c0 = kq ^ swz;                  // ksub 0 col
  const int c1 = (32 + kq) ^ swz;           // ksub 1 col

  // staging: thread t, load j covers LDS el (t*8 + j*4096) of a half-buffer.
  // prow = t>>3 (+64 for j=1), linear pcol = (t&7)*8; source col inverse-swizzled.
  const int prow = t >> 3;
  const int scol = ((t & 7) << 3) ^ ((prow & 7) << 3);
  const u16* Abase = A + (long long)(tiM + prow) * K + scol;
  const u16* Bbase = B + (long long)(tiN + prow) * K + scol;
  const long long r64 = 64LL * K;

  const int ab0 = (0 * 2 + wm) * 8192;           // A half base (dbuf 0)
  const int bb0 = 32768 + (0 * 2 + (wn >> 1)) * 8192;
  const int brow = (wn & 1) * 64;

  v4f acc[8][4] = {};
  const int NT = K >> 6;

  // prologue: stage tile 0 into dbuf 0 (A + B, 8 loads/thread)
#pragma unroll
  for (int hj = 0; hj < 4; hj++) {
    async16(Abase + (long long)hj * r64,
            &lds[(hj >> 1) * 8192 + (hj & 1) * 4096 + t * 8]);
    async16(Bbase + (long long)hj * r64,
            &lds[32768 + (hj >> 1) * 8192 + (hj & 1) * 4096 + t * 8]);
  }
  asm volatile("s_waitcnt vmcnt(0)" ::: "memory");
  __builtin_amdgcn_s_barrier();

  int d = 0;
  for (int kt = 0; kt < NT; ++kt) {
    const bool pf = (kt + 1 < NT);
    const int ab = ab0 + d * 16384;
    const int bb = bb0 + d * 16384;
    v8s af[4], ag[4], bf[4];

    // ---- phase 0: ksub0, mf 0-3 ----
#pragma unroll
    for (int i = 0; i < 4; i++) af[i] = *(const v8s*)&lds[ab + (i * 16 + rr) * 64 + c0];
#pragma unroll
    for (int i = 0; i < 4; i++) bf[i] = *(const v8s*)&lds[bb + (brow + i * 16 + rr) * 64 + c0];
    if (pf) {
      const u16* src = Abase + (long long)(kt + 1) * 64;
#pragma unroll
      for (int hj = 0; hj < 4; hj++)
        async16(src + (long long)hj * r64,
                &lds[((d ^ 1) * 2 + (hj >> 1)) * 8192 + (hj & 1) * 4096 + t * 8]);
    }
    __builtin_amdgcn_s_barrier();
    __builtin_amdgcn_s_setprio(1);
#pragma unroll
    for (int m = 0; m < 4; m++)
#pragma unroll
      for (int n = 0; n < 4; n++) mfma_bf16(acc[m][n], af[m], bf[n]);
    __builtin_amdgcn_s_setprio(0);
    __builtin_amdgcn_s_barrier();

    // ---- phase 1: ksub0, mf 4-7 ----
#pragma unroll
    for (int i = 0; i < 4; i++) ag[i] = *(const v8s*)&lds[ab + ((i + 4) * 16 + rr) * 64 + c0];
    if (pf) {
      const u16* src = Bbase + (long long)(kt + 1) * 64;
#pragma unroll
      for (int hj = 0; hj < 4; hj++)
        async16(src + (long long)hj * r64,
                &lds[32768 + ((d ^ 1) * 2 + (hj >> 1)) * 8192 + (hj & 1) * 4096 + t * 8]);
    }
    __builtin_amdgcn_s_barrier();
    __builtin_amdgcn_s_setprio(1);
#pragma unroll
    for (int m = 0; m < 4; m++)
#pragma unroll
      for (int n = 0; n < 4; n++) mfma_bf16(acc[4 + m][n], ag[m], bf[n]);
    __builtin_amdgcn_s_setprio(0);
    __builtin_amdgcn_s_barrier();

    // ---- phase 2: ksub1, mf 0-3 ----
#pragma unroll
    for (int i = 0; i < 4; i++) af[i] = *(const v8s*)&lds[ab + (i * 16 + rr) * 64 + c1];
#pragma unroll
    for (int i = 0; i < 4; i++) bf[i] = *(const v8s*)&lds[bb + (brow + i * 16 + rr) * 64 + c1];
    __builtin_amdgcn_s_barrier();
    __builtin_amdgcn_s_setprio(1);
#pragma unroll
    for (int m = 0; m < 4; m++)
#pragma unroll
      for (int n = 0; n < 4; n++) mfma_bf16(acc[m][n], af[m], bf[n]);
    __builtin_amdgcn_s_setprio(0);
    __builtin_amdgcn_s_barrier();

    // ---- phase 3: ksub1, mf 4-7 ----
#pragma unroll
    for (int i = 0; i < 4; i++) ag[i] = *(const v8s*)&lds[ab + ((i + 4) * 16 + rr) * 64 + c1];
    __builtin_amdgcn_s_barrier();
    __builtin_amdgcn_s_setprio(1);
#pragma unroll
    for (int m = 0; m < 4; m++)
#pragma unroll
      for (int n = 0; n < 4; n++) mfma_bf16(acc[4 + m][n], ag[m], bf[n]);
    __builtin_amdgcn_s_setprio(0);
    if (pf) asm volatile("s_waitcnt vmcnt(0)" ::: "memory");
    __builtin_amdgcn_s_barrier();
    d ^= 1;
  }

  __builtin_amdgcn_sched_barrier(0);
  asm volatile("s_nop 7\ns_nop 7\ns_nop 7");
  __builtin_amdgcn_sched_barrier(0);

  const int r4 = (lane >> 4) << 2;
  const int cc = lane & 15;
#pragma unroll
  for (int mf = 0; mf < 8; mf++)
#pragma unroll
    for (int nf = 0; nf < 4; nf++)
#pragma unroll
      for (int i = 0; i < 4; i++) {
        int row = tiM + wm * 128 + mf * 16 + r4 + i;
        int col = tiN + wn * 64 + nf * 16 + cc;
        float v = acc[mf][nf][i];
        if (EPI == 0) {
          ((u16*)Cv)[(long long)row * ldc + col] = f2b(v);
        } else {  // EPI == 3
          float hv = v + bias[col];
          float gg = 0.5f * hv * (1.0f + erff(hv * 0.70710678118f));
          ((u16*)Cv)[(long long)row * ldc + col] = f2b(gg);
        }
      }
}

// ---------------------------------------------------------------------------
// gemm2: BM=128, BN in {64,128}.  (attn-path GEMMs)
// EPI: 5 = f32 split-K partial; 6 = f32 dd*scale store + fused global atomicMax
// ---------------------------------------------------------------------------
template <int EPI, int BN, int KSPLIT>
__global__ void __launch_bounds__(256, 4)
gemm2(const u16* __restrict__ A, const u16* __restrict__ B,
      void* __restrict__ Cv, const float* __restrict__ bias,
      int K, int ldc, long long sA, long long sB, long long sC,
      float scale, int Ncap, int Mcap, unsigned int* __restrict__ gmax)
{
  __shared__ u16 As[2][128 * 32];
  __shared__ u16 Bs[2][BN * 32];
  __shared__ float smax[4];
  const int zz = blockIdx.z;
  const int z = (KSPLIT > 1) ? zz / KSPLIT : zz;
  const int ks = (KSPLIT > 1) ? zz % KSPLIT : 0;
  const int kchunk = K / KSPLIT;
  const u16* Ag = A + (long long)z * sA + ks * kchunk;
  const u16* Bg = B + (long long)z * sB + ks * kchunk;
  const int t = threadIdx.x;
  const int lane = t & 63;
  const int w = t >> 6;
  constexpr int NF = BN / 32;
  const int wm = (w >> 1) << 6;
  const int wn = (w & 1) * (BN / 2);
  const int tiM = blockIdx.x << 7, tiN = blockIdx.y * BN;

  const int srow = t >> 2;
  const int scol = (t & 3) << 3;
  const u16* Ap = Ag + (long long)(tiM + srow) * K + scol;
  const u16* Bp = Bg + (long long)(tiN + srow) * K + scol;
  const long long rstride = 64LL * K;

  const int rr = lane & 15;
  const int kc = (lane >> 4) << 3;

  v4f acc[4][NF] = {};

  const int nk = kchunk >> 5;
  auto stage = [&](int buf, int k0) {
    async16(Ap + k0, &As[buf][t * 8]);
    async16(Ap + k0 + rstride, &As[buf][t * 8 + 2048]);
    async16(Bp + k0, &Bs[buf][t * 8]);
    if (BN == 128) async16(Bp + k0 + rstride, &Bs[buf][t * 8 + 2048]);
  };

  stage(0, 0);
  __syncthreads();
  int cur = 0;
  for (int kt = 0; kt < nk; ++kt) {
    if (kt + 1 < nk) stage(cur ^ 1, (kt + 1) << 5);
    v8s af[4], bf[NF];
#pragma unroll
    for (int i = 0; i < 4; i++) af[i] = *(const v8s*)&As[cur][(wm + rr + i * 16) * 32 + kc];
#pragma unroll
    for (int i = 0; i < NF; i++) bf[i] = *(const v8s*)&Bs[cur][(wn + rr + i * 16) * 32 + kc];
#pragma unroll
    for (int fm = 0; fm < 4; fm++)
#pragma unroll
      for (int fn = 0; fn < NF; fn++)
        mfma_bf16(acc[fm][fn], af[fm], bf[fn]);
    __syncthreads();
    cur ^= 1;
  }

  __builtin_amdgcn_sched_barrier(0);
  asm volatile("s_nop 7\ns_nop 7\ns_nop 7");
  __builtin_amdgcn_sched_barrier(0);

  const int r4 = (lane >> 4) << 2;
  const int cc = lane & 15;
  float lmax = -3e38f;
#pragma unroll
  for (int fm = 0; fm < 4; fm++)
#pragma unroll
    for (int fn = 0; fn < NF; fn++)
#pragma unroll
      for (int i = 0; i < 4; i++) {
        int row = tiM + wm + fm * 16 + r4 + i;
        int col = tiN + wn + fn * 16 + cc;
        float v = acc[fm][fn][i];
        if (EPI == 5) {
          if (row < Mcap && col < Ncap)
            ((float*)Cv)[((long long)zz * M_ALLOC + row) * 64 + col] = v;
        } else if (EPI == 6) {
          float sv = v * scale;
          if (col < Ncap) ((float*)Cv)[(long long)row * ldc + col] = sv;
          if (col < M_FEAT) lmax = fmaxf(lmax, sv);
        }
      }

  if (EPI == 6) {
    lmax = wave_max(lmax);
    if (lane == 0) smax[w] = lmax;
    __syncthreads();
    if (t == 0) {
      float m = fmaxf(fmaxf(smax[0], smax[1]), fmaxf(smax[2], smax[3]));
      unsigned int u = __float_as_uint(m);
      unsigned int key = (u & 0x80000000u) ? ~u : (u | 0x80000000u);
      atomicMax(gmax, key);
    }
  }
}

// ---------------------------------------------------------------------------
// gemm_small: BM=64, BN=64, BK=32, high-occupancy variant.
// EPI: 0 bf16; 2 f32 residual += acc + bias; 3 bf16 gelu; 4 head-scatter.
// ---------------------------------------------------------------------------
template <int EPI>
__global__ void __launch_bounds__(256, 6)
gemm_small(const u16* __restrict__ A, const u16* __restrict__ B,
           void* __restrict__ Cv, const float* __restrict__ bias,
           int K, int ldc, long long sA, long long sB)
{
  __shared__ u16 As[2][64 * 32];
  __shared__ u16 Bs[2][64 * 32];
  const int z = blockIdx.z;
  const u16* Ag = A + (long long)z * sA;
  const u16* Bg = B + (long long)z * sB;
  const int t = threadIdx.x;
  const int lane = t & 63;
  const int w = t >> 6;
  const int wm = (w >> 1) << 5;
  const int wn = (w & 1) << 5;
  const int tiM = blockIdx.x << 6, tiN = blockIdx.y << 6;

  const int srow = t >> 2;
  const int scol = (t & 3) << 3;
  const u16* Ap = Ag + (long long)(tiM + srow) * K + scol;
  const u16* Bp = Bg + (long long)(tiN + srow) * K + scol;

  const int rr = lane & 15;
  const int kc = (lane >> 4) << 3;

  v4f acc[2][2] = {};

  const int nk = K >> 5;
  auto stage = [&](int buf, int k0) {
    async16(Ap + k0, &As[buf][t * 8]);
    async16(Bp + k0, &Bs[buf][t * 8]);
  };

  stage(0, 0);
  __syncthreads();
  int cur = 0;
  for (int kt = 0; kt < nk; ++kt) {
    if (kt + 1 < nk) stage(cur ^ 1, (kt + 1) << 5);
    v8s af[2], bf[2];
#pragma unroll
    for (int i = 0; i < 2; i++) af[i] = *(const v8s*)&As[cur][(wm + rr + i * 16) * 32 + kc];
#pragma unroll
    for (int i = 0; i < 2; i++) bf[i] = *(const v8s*)&Bs[cur][(wn + rr + i * 16) * 32 + kc];
#pragma unroll
    for (int fm = 0; fm < 2; fm++)
#pragma unroll
      for (int fn = 0; fn < 2; fn++)
        mfma_bf16(acc[fm][fn], af[fm], bf[fn]);
    __syncthreads();
    cur ^= 1;
  }

  __builtin_amdgcn_sched_barrier(0);
  asm volatile("s_nop 7\ns_nop 7\ns_nop 7");
  __builtin_amdgcn_sched_barrier(0);

  const int r4 = (lane >> 4) << 2;
  const int cc = lane & 15;
#pragma unroll
  for (int fm = 0; fm < 2; fm++)
#pragma unroll
    for (int fn = 0; fn < 2; fn++)
#pragma unroll
      for (int i = 0; i < 4; i++) {
        int row = tiM + wm + fm * 16 + r4 + i;
        int col = tiN + wn + fn * 16 + cc;
        float v = acc[fm][fn][i];
        if (EPI == 0) {
          ((u16*)Cv)[(long long)row * ldc + col] = f2b(v);
        } else if (EPI == 2) {
          long long idx = (long long)row * ldc + col;
          float bb = bias ? bias[col] : 0.0f;
          ((float*)Cv)[idx] += v + bb;
        } else if (EPI == 3) {
          float hv = v + bias[col];
          float gg = 0.5f * hv * (1.0f + erff(hv * 0.70710678118f));
          ((u16*)Cv)[(long long)row * ldc + col] = f2b(gg);
        } else {  // EPI == 4: head scatter (N=64 per z)
          int b_ = z >> 3, h_ = z & 7;
          ((u16*)Cv)[(long long)(b_ * N_SEQ + row) * 512 + h_ * 64 + col] = f2b(v);
        }
      }
}

// ---------------------------------------------------------------------------
// Fused dd_q -> row-max -> exp -> denominator -> qf (bf16, d_inv folded).
// ---------------------------------------------------------------------------
__global__ void __launch_bounds__(512, 2)
ddq_qf(const u16* __restrict__ qr, const u16* __restrict__ proj,
       const float* __restrict__ diag, const float* __restrict__ ksum,
       u16* __restrict__ qf)
{
  __shared__ u16 As[2][64 * 32];
  __shared__ u16 Bs[2][384 * 32];
  __shared__ float red[2][8][64];
  const int bh = blockIdx.z;
  const int tiM = blockIdx.x << 6;
  const int t = threadIdx.x;
  const int lane = t & 63;
  const int w = t >> 6;
  const u16* Ag = qr + (long long)bh * (N_SEQ * 64);
  const int srow = t >> 2, scol = (t & 3) << 3;
  const u16* Ap = Ag + (long long)(tiM + srow) * 64 + scol;
  const u16* Bp = proj + (long long)srow * 64 + scol;
  const int rr = lane & 15, kc = (lane >> 4) << 3;
  const int wn = w * 48;

  v4f acc[4][3] = {};
  auto stage = [&](int buf, int k0) {
    if (t < 256) async16(Ap + k0, &As[buf][t * 8]);
#pragma unroll
    for (int i = 0; i < 3; i++)
      async16(Bp + k0 + (long long)i * (128 * 64), &Bs[buf][t * 8 + i * 4096]);
  };

  stage(0, 0);
  __syncthreads();
  for (int kt = 0; kt < 2; ++kt) {
    if (kt == 0) stage(1, 32);
    v8s af[4], bf[3];
#pragma unroll
    for (int i = 0; i < 4; i++) af[i] = *(const v8s*)&As[kt][(rr + i * 16) * 32 + kc];
#pragma unroll
    for (int i = 0; i < 3; i++) bf[i] = *(const v8s*)&Bs[kt][(wn + rr + i * 16) * 32 + kc];
#pragma unroll
    for (int fm = 0; fm < 4; fm++)
#pragma unroll
      for (int fn = 0; fn < 3; fn++)
        mfma_bf16(acc[fm][fn], af[fm], bf[fn]);
    __syncthreads();
  }

  __builtin_amdgcn_sched_barrier(0);
  asm volatile("s_nop 7\ns_nop 7\ns_nop 7");
  __builtin_amdgcn_sched_barrier(0);

  const int r4 = (lane >> 4) << 2;
  const int cc = lane & 15;
  const float sc = 0.35355339f;

#pragma unroll
  for (int fm = 0; fm < 4; fm++)
#pragma unroll
    for (int i = 0; i < 4; i++) {
      float m = -3e38f;
#pragma unroll
      for (int fn = 0; fn < 3; fn++) {
        int col = wn + fn * 16 + cc;
        float v = acc[fm][fn][i] * sc;
        if (col < M_FEAT) m = fmaxf(m, v);
      }
#pragma unroll
      for (int o = 1; o < 16; o <<= 1) m = fmaxf(m, __shfl_xor(m, o));
      if (cc == 0) red[0][w][fm * 16 + r4 + i] = m;
    }
  __syncthreads();

  float ksv[3];
#pragma unroll
  for (int fn = 0; fn < 3; fn++) {
    int col = wn + fn * 16 + cc;
    ksv[fn] = (col < M_PAD) ? ksum[bh * M_PAD + col] : 0.0f;
  }

#pragma unroll
  for (int fm = 0; fm < 4; fm++)
#pragma unroll
    for (int i = 0; i < 4; i++) {
      int row = fm * 16 + r4 + i;
      float gm = red[0][0][row];
#pragma unroll
      for (int ww = 1; ww < 8; ww++) gm = fmaxf(gm, red[0][ww][row]);
      float dg = diag[(long long)bh * N_SEQ + tiM + row];
      float s = 0.0f;
#pragma unroll
      for (int fn = 0; fn < 3; fn++) {
        int col = wn + fn * 16 + cc;
        float v = acc[fm][fn][i] * sc;
        float e = (col < M_FEAT) ? 0.06131389f * (expf(v - dg - gm) + 1e-4f) : 0.0f;
        acc[fm][fn][i] = e;
        s += e * ksv[fn];
      }
#pragma unroll
      for (int o = 1; o < 16; o <<= 1) s += __shfl_xor(s, o);
      if (cc == 0) red[1][w][row] = s;
    }
  __syncthreads();

#pragma unroll
  for (int fm = 0; fm < 4; fm++)
#pragma unroll
    for (int i = 0; i < 4; i++) {
      int row = fm * 16 + r4 + i;
      float s = 0.0f;
#pragma unroll
      for (int ww = 0; ww < 8; ww++) s += red[1][ww][row];
      float dinv = 1.0f / s;
#pragma unroll
      for (int fn = 0; fn < 3; fn++) {
        int col = wn + fn * 16 + cc;
        if (col < M_PAD)
          qf[((long long)bh * N_SEQ + tiM + row) * M_PAD + col] =
              f2b(acc[fm][fn][i] * dinv);
      }
    }
}

// ---------------------------------------------------------------------------
template <bool F32OUT>
__global__ void ln_kernel(const float* __restrict__ x, const float* __restrict__ g,
                          const float* __restrict__ b, void* __restrict__ out)
{
  const int row = blockIdx.x * 4 + (threadIdx.x >> 6);
  const int lane = threadIdx.x & 63;
  const float* xr = x + (long long)row * D_MODEL + lane * 8;
  v4f v0 = *(const v4f*)xr;
  v4f v1 = *(const v4f*)(xr + 4);
  float s = v0[0] + v0[1] + v0[2] + v0[3] + v1[0] + v1[1] + v1[2] + v1[3];
  float sq = v0[0]*v0[0] + v0[1]*v0[1] + v0[2]*v0[2] + v0[3]*v0[3]
           + v1[0]*v1[0] + v1[1]*v1[1] + v1[2]*v1[2] + v1[3]*v1[3];
  s = wave_sum(s);
  sq = wave_sum(sq);
  float mu = s * (1.0f / D_MODEL);
  float var = sq * (1.0f / D_MODEL) - mu * mu;
  float rstd = rsqrtf(var + 1e-5f);
  v4f g0 = *(const v4f*)(g + lane * 8), g1 = *(const v4f*)(g + lane * 8 + 4);
  v4f bb0 = *(const v4f*)(b + lane * 8), bb1 = *(const v4f*)(b + lane * 8 + 4);
  float y[8];
#pragma unroll
  for (int j = 0; j < 4; j++) y[j] = (v0[j] - mu) * rstd * g0[j] + bb0[j];
#pragma unroll
  for (int j = 0; j < 4; j++) y[4 + j] = (v1[j] - mu) * rstd * g1[j] + bb1[j];
  if (F32OUT) {
    float* op = (float*)out + (long long)row * D_MODEL + lane * 8;
    v4f o0 = {y[0], y[1], y[2], y[3]}, o1 = {y[4], y[5], y[6], y[7]};
    *(v4f*)op = o0;
    *(v4f*)(op + 4) = o1;
  } else {
    u16* op = (u16*)out + (long long)row * D_MODEL + lane * 8;
    alignas(16) u16 tmp[8];
#pragma unroll
    for (int j = 0; j < 8; j++) tmp[j] = f2b(y[j]);
    *(v8s*)op = *(v8s*)tmp;
  }
}

__global__ void posadd(const float* __restrict__ xin, float* __restrict__ x)
{
  long long i = (long long)blockIdx.x * 256 + threadIdx.x;
  int d = (int)(i & 511);
  int n = (int)((i >> 9) & 2047);
  int j = d & 255;
  float sarg = (float)n * expf(-0.035977892f * (float)j);
  float pe = (d < 256) ? sinf(sarg) : cosf(sarg);
  x[i] = xin[i] + pe;
}

__global__ void rotab(float* __restrict__ ts, float* __restrict__ tc)
{
  int i = blockIdx.x * 64 + threadIdx.x;  // 2048*32
  int n = i >> 5, j = i & 31;
  float sarg = (float)n * expf(-0.28782314f * (float)j);
  float s, c;
  sincosf(sarg, &s, &c);
  ts[i] = s;
  tc[i] = c;
}

__global__ void rotary_kernel(const u16* __restrict__ qkv,
                              const float* __restrict__ ts, const float* __restrict__ tc,
                              u16* __restrict__ qr, u16* __restrict__ kr,
                              float* __restrict__ dq, float* __restrict__ dk)
{
  int bid = blockIdx.x * 4 + (threadIdx.x >> 6);
  int n = bid & 2047;
  int h = (bid >> 11) & 7;
  int b = bid >> 14;
  int lane = threadIdx.x & 63;
  long long src = ((long long)(b * N_SEQ + n)) * 1536 + h * 64 + lane;
  float qv = b2f(qkv[src]);
  float kv = b2f(qkv[src + 512]);
  int j = lane >> 1;
  float sn = ts[n * 32 + j], cn = tc[n * 32 + j];
  float qp = __shfl_xor(qv, 1), kp = __shfl_xor(kv, 1);
  float qrv = (lane & 1) ? (qv * cn + qp * sn) : (qv * cn - qp * sn);
  float krv = (lane & 1) ? (kv * cn + kp * sn) : (kv * cn - kp * sn);
  u16 qb = f2b(qrv), kb = f2b(krv);
  long long dst = ((long long)bid) * 64 + lane;
  qr[dst] = qb;
  kr[dst] = kb;
  float q2 = b2f(qb); q2 *= q2;
  float k2 = b2f(kb); k2 *= k2;
  q2 = wave_sum(q2);
  k2 = wave_sum(k2);
  if (lane == 0) { dq[bid] = q2 * 0.0625f; dk[bid] = k2 * 0.0625f; }
}

__global__ void vtrans(const u16* __restrict__ qkv, u16* __restrict__ vT)
{
  int bid = blockIdx.x;  // B*H*32
  int nt = bid & 31;
  int h = (bid >> 5) & 7;
  int b = bid >> 8;
  __shared__ u16 st[64][72];
  int t = threadIdx.x;
  int r = t >> 2, c = (t & 3) << 4;
  long long src = ((long long)(b * N_SEQ + nt * 64 + r)) * 1536 + 1024 + h * 64 + c;
  *(v8s*)&st[r][c] = *(const v8s*)(qkv + src);
  *(v8s*)&st[r][c + 8] = *(const v8s*)(qkv + src + 8);
  __syncthreads();
  alignas(16) u16 tmp[16];
#pragma unroll
  for (int jj = 0; jj < 16; jj++) tmp[jj] = st[c + jj][r];
  long long dst = ((long long)((b * 8 + h) * 64 + r)) * N_SEQ + nt * 64 + c;
  *(v8s*)(vT + dst) = *(v8s*)&tmp[0];
  *(v8s*)(vT + dst + 8) = *(v8s*)&tmp[8];
}

__global__ void wtrans(const float* __restrict__ src, u16* __restrict__ dst,
                       int Ks, int Ns, long long sSrc, long long sDst)
{
  int l = blockIdx.z;
  src += (long long)l * sSrc;
  dst += (long long)l * sDst;
  int n0 = blockIdx.x << 6, k0 = blockIdx.y << 6;
  __shared__ float st[64][68];
  int t = threadIdx.x;
  int r = t >> 2, c = (t & 3) << 4;
  const float* sp = src + (long long)(k0 + r) * Ns + n0 + c;
#pragma unroll
  for (int jj = 0; jj < 16; jj += 4) *(v4f*)&st[r][c + jj] = *(const v4f*)(sp + jj);
  __syncthreads();
  alignas(16) u16 tmp[16];
#pragma unroll
  for (int jj = 0; jj < 16; jj++) tmp[jj] = f2b(st[c + jj][r]);
  u16* dp = dst + (long long)(n0 + r) * Ks + k0 + c;
  *(v8s*)(dp) = *(v8s*)&tmp[0];
  *(v8s*)(dp + 8) = *(v8s*)&tmp[8];
}

__global__ void projconv(const float* __restrict__ proj, u16* __restrict__ out)
{
  int i = blockIdx.x * 256 + threadIdx.x;  // 6*384*64
  int dh = i & 63;
  int m = (i >> 6) % M_ALLOC;
  int l = i / (M_ALLOC * 64);
  float v = (m < M_FEAT) ? proj[((long long)l * M_FEAT + m) * 64 + dh] : 0.0f;
  out[i] = f2b(v);
}

__global__ void resetmax(unsigned int* p) { *p = 0u; }

// ---------------------------------------------------------------------------
// kfprep: dd_k (bh,n,288) f32 -> kfT (bh,384,2048) bf16 + per-tile ksum partials.
// ---------------------------------------------------------------------------
__global__ void kfprep(const float* __restrict__ dd, const float* __restrict__ diag,
                       const unsigned int* __restrict__ kmax,
                       u16* __restrict__ kfT, float* __restrict__ part)
{
  int ntile = blockIdx.x;          // 32
  int m0 = blockIdx.y << 6;        // 5 tiles (0..319, cap 288)
  int bh = blockIdx.z;             // 32
  int n0 = ntile << 6;
  __shared__ float st[64][65];
  unsigned int kk = kmax[0];
  float km = (kk & 0x80000000u) ? __uint_as_float(kk ^ 0x80000000u)
                                : __uint_as_float(~kk);
  int t = threadIdx.x;
  int r = t >> 2, c = (t & 3) << 4;
  const float* dp = dd + ((long long)bh * N_SEQ + n0 + r) * M_PAD + m0 + c;
  float dg = diag[(long long)bh * N_SEQ + n0 + r];
  float vals[16];
  if (m0 + c + 16 <= M_PAD) {
#pragma unroll
    for (int j = 0; j < 16; j += 4) *(v4f*)&vals[j] = *(const v4f*)(dp + j);
  } else {
#pragma unroll
    for (int j = 0; j < 16; j++) vals[j] = (m0 + c + j < M_PAD) ? dp[j] : 0.0f;
  }
#pragma unroll
  for (int j = 0; j < 16; j++) {
    int m = m0 + c + j;
    float e = (m < M_FEAT) ? 0.06131389f * (expf(vals[j] - dg - km) + 1e-4f) : 0.0f;
    st[r][c + j] = e;
  }
  __syncthreads();
  int mr = t >> 2, nc = (t & 3) << 4;
  float s = 0.0f;
  alignas(16) u16 tmp[16];
#pragma unroll
  for (int j = 0; j < 16; j++) {
    float e = st[nc + j][mr];
    s += e;
    tmp[j] = f2b(e);
  }
  s += __shfl_xor(s, 1);
  s += __shfl_xor(s, 2);
  int m = m0 + mr;
  if (m < M_PAD) {
    u16* op = kfT + ((long long)bh * M_ALLOC + m) * N_SEQ + n0 + nc;
    *(v8s*)op = *(v8s*)&tmp[0];
    *(v8s*)(op + 8) = *(v8s*)&tmp[8];
    if ((t & 3) == 0)
      part[((long long)bh * M_PAD + m) * 32 + ntile] = s;
  }
}

__global__ void ksumred(const float* __restrict__ part, float* __restrict__ ksum)
{
  int i = blockIdx.x * 256 + threadIdx.x;  // 32*288
  if (i >= 32 * M_PAD) return;
  const float* p = part + (long long)i * 32;
  float s = 0.0f;
#pragma unroll
  for (int j = 0; j < 32; j += 4) {
    v4f v = *(const v4f*)(p + j);
    s += v[0] + v[1] + v[2] + v[3];
  }
  ksum[i] = s;
}

// reduce split-K ctx partials (8) + transpose -> ctxT (bh,64,288) bf16
__global__ void ctxred(const float* __restrict__ part, u16* __restrict__ ctxT)
{
  int bh = blockIdx.y;
  int m0 = blockIdx.x << 6;   // 5 tiles
  __shared__ float st[64][65];
  int t = threadIdx.x;
  int r = t >> 2, c = (t & 3) << 4;
  int m = m0 + r;
  v4f s[4] = {};
  if (m < M_PAD) {
    for (int ks = 0; ks < 8; ks++) {
      const float* p = part + (((long long)bh * 8 + ks) * M_ALLOC + m) * 64 + c;
#pragma unroll
      for (int j = 0; j < 4; j++) s[j] += *(const v4f*)(p + j * 4);
    }
  }
#pragma unroll
  for (int j = 0; j < 4; j++)
#pragma unroll
    for (int e = 0; e < 4; e++) st[r][c + j * 4 + e] = s[j][e];
  __syncthreads();
  int e = t >> 2, mc = (t & 3) << 4;
  if (m0 + mc < M_PAD) {
    alignas(16) u16 tmp[16];
#pragma unroll
    for (int j = 0; j < 16; j++) tmp[j] = f2b(st[mc + j][e]);
    u16* op = ctxT + ((long long)bh * 64 + e) * M_PAD + m0 + mc;
    *(v8s*)op = *(v8s*)&tmp[0];
    *(v8s*)(op + 8) = *(v8s*)&tmp[8];
  }
}

// ---------------------------------------------------------------------------
extern "C" void kernel_launch(void* const* d_in, const int* in_sizes, int n_in,
                              void* d_out, int out_size, void* d_ws, size_t ws_size,
                              hipStream_t stream)
{
  const float* x_in = (const float*)d_in[0];
  const float* Wq  = (const float*)d_in[1];
  const float* Wk  = (const float*)d_in[2];
  const float* Wv  = (const float*)d_in[3];
  const float* Wo  = (const float*)d_in[4];
  const float* Pr  = (const float*)d_in[5];
  const float* ln1g = (const float*)d_in[6];
  const float* ln1b = (const float*)d_in[7];
  const float* W1  = (const float*)d_in[8];
  const float* b1  = (const float*)d_in[9];
  const float* W2  = (const float*)d_in[10];
  const float* b2  = (const float*)d_in[11];
  const float* ln2g = (const float*)d_in[12];
  const float* ln2b = (const float*)d_in[13];
  const float* lnfg = (const float*)d_in[14];
  const float* lnfb = (const float*)d_in[15];

  // allow 128 KiB dynamic LDS for the 8-phase GEMM
  hipFuncSetAttribute(reinterpret_cast<const void*>(&gemm8p<0>),
                      hipFuncAttributeMaxDynamicSharedMemorySize, 131072);
  hipFuncSetAttribute(reinterpret_cast<const void*>(&gemm8p<3>),
                      hipFuncAttributeMaxDynamicSharedMemorySize, 131072);

  char* ws = (char*)d_ws;
  size_t off = 0;
  auto alloc = [&](size_t bytes) -> void* {
    void* p = ws + off;
    off = (off + bytes + 255) & ~(size_t)255;
    return p;
  };

  float* x      = (float*)alloc((size_t)ROWS * D_MODEL * 4);
  float* tsin   = (float*)alloc((size_t)N_SEQ * 32 * 4);
  float* tcos   = (float*)alloc((size_t)N_SEQ * 32 * 4);
  u16*   wqkvT  = (u16*)alloc((size_t)N_LAYER * 1536 * 512 * 2);
  u16*   woT    = (u16*)alloc((size_t)N_LAYER * 512 * 512 * 2);
  u16*   w1T    = (u16*)alloc((size_t)N_LAYER * 2048 * 512 * 2);
  u16*   w2T    = (u16*)alloc((size_t)N_LAYER * 512 * 2048 * 2);
  u16*   projT  = (u16*)alloc((size_t)N_LAYER * M_ALLOC * 64 * 2);
  u16*   hbuf   = (u16*)alloc((size_t)ROWS * D_MODEL * 2);
  u16*   obuf   = (u16*)alloc((size_t)ROWS * D_MODEL * 2);
  float* big    = (float*)alloc((size_t)32 * N_SEQ * M_PAD * 4);   // qkv_pre bf16 / dd f32
  u16*   qrbuf  = (u16*)alloc((size_t)BHN * 64 * 2);
  u16*   krbuf  = (u16*)alloc((size_t)BHN * 64 * 2);
  u16*   vTbuf  = (u16*)alloc((size_t)BHN * 64 * 2);
  float* diagq  = (float*)alloc((size_t)BHN * 4);
  float* diagk  = (float*)alloc((size_t)BHN * 4);
  unsigned int* kmaxu = (unsigned int*)alloc(256);
  u16*   kfT    = (u16*)alloc((size_t)32 * M_ALLOC * N_SEQ * 2);   // also qf buffer
  float* part   = (float*)alloc((size_t)32 * 8 * M_ALLOC * 64 * 4);
  float* kspart = (float*)alloc((size_t)32 * M_PAD * 32 * 4);
  u16*   ctxT   = (u16*)alloc((size_t)32 * 64 * M_PAD * 2);
  float* ksum   = (float*)alloc((size_t)32 * M_PAD * 4);
  (void)alloc(1 << 20);  // guard region for benign OOB tile reads
  (void)ws_size; (void)in_sizes; (void)n_in; (void)out_size;

  // ---- setup ----
  posadd<<<16384, 256, 0, stream>>>(x_in, x);
  rotab<<<1024, 64, 0, stream>>>(tsin, tcos);
  wtrans<<<dim3(8, 8, 6), 256, 0, stream>>>(Wq, wqkvT, 512, 512, 512LL * 512, 1536LL * 512);
  wtrans<<<dim3(8, 8, 6), 256, 0, stream>>>(Wk, wqkvT + 512LL * 512, 512, 512, 512LL * 512, 1536LL * 512);
  wtrans<<<dim3(8, 8, 6), 256, 0, stream>>>(Wv, wqkvT + 1024LL * 512, 512, 512, 512LL * 512, 1536LL * 512);
  wtrans<<<dim3(8, 8, 6), 256, 0, stream>>>(Wo, woT, 512, 512, 512LL * 512, 512LL * 512);
  wtrans<<<dim3(32, 8, 6), 256, 0, stream>>>(W1, w1T, 512, 2048, 512LL * 2048, 2048LL * 512);
  wtrans<<<dim3(8, 32, 6), 256, 0, stream>>>(W2, w2T, 2048, 512, 2048LL * 512, 512LL * 2048);
  projconv<<<(N_LAYER * M_ALLOC * 64) / 256, 256, 0, stream>>>(Pr, projT);

  for (int l = 0; l < N_LAYER; l++) {
    const u16* wq = wqkvT + (long long)l * 1536 * 512;
    const u16* wo = woT + (long long)l * 512 * 512;
    const u16* w1 = w1T + (long long)l * 2048 * 512;
    const u16* w2 = w2T + (long long)l * 512 * 2048;
    const u16* pj = projT + (long long)l * M_ALLOC * 64;

    resetmax<<<1, 1, 0, stream>>>(kmaxu);
    // LN1 -> h
    ln_kernel<false><<<ROWS / 4, 256, 0, stream>>>(x, ln1g + l * 512, ln1b + l * 512, hbuf);
    // qkv_pre = h @ Wqkv^T  (8192 x 1536, K=512)  [8-phase 256²]
    gemm8p<0><<<dim3(32, 6), 512, 131072, stream>>>(hbuf, wq, big, nullptr, 512, 1536);
    rotary_kernel<<<BHN / 4, 256, 0, stream>>>((u16*)big, tsin, tcos, qrbuf, krbuf, diagq, diagk);
    vtrans<<<1024, 256, 0, stream>>>((u16*)big, vTbuf);
    // dd_k (65536 x 288, K=64) + fused global max
    gemm2<6, 128, 1><<<dim3(512, 3, 1), 256, 0, stream>>>(krbuf, pj, big, nullptr,
        64, M_PAD, 0, 0, 0, 0.35355339f, M_PAD, BHN, kmaxu);
    // kf^T + ksum partials
    kfprep<<<dim3(32, 5, 32), 256, 0, stream>>>(big, diagk, kmaxu, kfT, kspart);
    ksumred<<<(32 * M_PAD + 255) / 256, 256, 0, stream>>>(kspart, ksum);
    // ctx = kf^T @ v  split-K=8
    gemm2<5, 64, 8><<<dim3(3, 1, 256), 256, 0, stream>>>(kfT, vTbuf, part, nullptr,
        2048, 64, (long long)M_ALLOC * N_SEQ, 64LL * N_SEQ, 0, 1.0f, 64, M_PAD, nullptr);
    ctxred<<<dim3(5, 32), 256, 0, stream>>>(part, ctxT);
    // fused dd_q -> qf
    ddq_qf<<<dim3(32, 1, 32), 512, 0, stream>>>(qrbuf, pj, diagq, ksum, kfT);
    // o = qf @ ctx^T -> head scatter
    gemm_small<4><<<dim3(32, 1, 32), 256, 0, stream>>>(kfT, ctxT, obuf, nullptr,
        M_PAD, 0, (long long)N_SEQ * M_PAD, 64LL * M_PAD);
    // x += o @ Wo^T
    gemm_small<2><<<dim3(128, 8, 1), 256, 0, stream>>>(obuf, wo, x, nullptr,
        512, 512, 0, 0);
    // LN2 -> h
    ln_kernel<false><<<ROWS / 4, 256, 0, stream>>>(x, ln2g + l * 512, ln2b + l * 512, hbuf);
    // ff = gelu(h @ W1^T + b1)  [8-phase 256²]
    gemm8p<3><<<dim3(32, 8), 512, 131072, stream>>>(hbuf, w1, big, b1 + (long long)l * 2048,
        512, 2048);
    // x += ff @ W2^T + b2
    gemm_small<2><<<dim3(128, 8, 1), 256, 0, stream>>>((u16*)big, w2, x, b2 + (long long)l * 512,
        2048, 512, 0, 0);
  }

  ln_kernel<true><<<ROWS / 4, 256, 0, stream>>>(x, lnfg, lnfb, d_out);
}

// Round 6
// 1613.930 us; speedup vs baseline: 1.4758x; 1.0077x over previous
//
#include <hip/hip_runtime.h>
#include <hip/hip_bf16.h>
#include <cstdint>

typedef float v4f __attribute__((ext_vector_type(4)));
typedef short v8s __attribute__((ext_vector_type(8)));
typedef unsigned short u16;

#define N_SEQ 2048
#define D_MODEL 512
#define N_LAYER 6
#define N_HEAD 8
#define D_HEAD 64
#define M_FEAT 266
#define M_PAD 288
#define M_ALLOC 384
#define FF_DIM 2048
#define BATCH 4
#define ROWS 8192
#define BHN 65536   // B*H*N

__device__ __forceinline__ float b2f(u16 u) {
  return __uint_as_float(((uint32_t)u) << 16);
}
__device__ __forceinline__ u16 f2b(float f) {
  union { __hip_bfloat16 h; u16 u; } c;
  c.h = __float2bfloat16(f);
  return c.u;
}
__device__ __forceinline__ float wave_sum(float v) {
#pragma unroll
  for (int o = 1; o < 64; o <<= 1) v += __shfl_xor(v, o);
  return v;
}
__device__ __forceinline__ float wave_max(float v) {
#pragma unroll
  for (int o = 1; o < 64; o <<= 1) v = fmaxf(v, __shfl_xor(v, o));
  return v;
}

__device__ __forceinline__ void mfma_bf16(v4f& d, v8s a, v8s b) {
  asm volatile("v_mfma_f32_16x16x32_bf16 %0, %1, %2, %0" : "+v"(d) : "v"(a), "v"(b));
}

// async global->LDS, 16B per lane. LDS dest must be wave-linear (base + lane*16).
__device__ __forceinline__ void async16(const u16* g, u16* l) {
  __builtin_amdgcn_global_load_lds(
      (const __attribute__((address_space(1))) uint32_t*)g,
      (__attribute__((address_space(3))) uint32_t*)l, 16, 0, 0);
}

// ---------------------------------------------------------------------------
// gemm8p: 256x256 tile, BK=64, 512 threads (8 waves 2Mx4N), 8-phase schedule,
// raw s_barrier, setprio, st-swizzled LDS. Optional split-K (grid.z = split).
// EPI: 0 = bf16 out; 3 = bf16 gelu(acc + bias); 5 = f32 split partial.
// ---------------------------------------------------------------------------
template <int EPI, int KSPLIT>
__global__ void __launch_bounds__(512, 2)
gemm8p(const u16* __restrict__ A, const u16* __restrict__ B,
       void* __restrict__ Cv, const float* __restrict__ bias,
       int K, int ldc)
{
  extern __shared__ u16 lds[];   // [0..32767] A halves, [32768..65535] B halves
  const int t = threadIdx.x;
  const int lane = t & 63;
  const int w = t >> 6;
  const int wm = w >> 2;          // 0..1  (M half)
  const int wn = w & 3;           // 0..3  (N quarter)
  const int tiM = blockIdx.x << 8, tiN = blockIdx.y << 8;
  const int ks = (KSPLIT > 1) ? blockIdx.z : 0;
  const int kchunk = K / KSPLIT;

  const int rr = lane & 15;
  const int kq = (lane >> 4) << 3;          // 0,8,16,24
  const int swz = (rr & 7) << 3;            // read-side XOR (row&7)*8
  const int c0 = kq ^ swz;                  // ksub 0 col
  const int c1 = (32 + kq) ^ swz;           // ksub 1 col

  const int prow = t >> 3;
  const int scol = ((t & 7) << 3) ^ ((prow & 7) << 3);
  const u16* Abase = A + (long long)(tiM + prow) * K + scol + (long long)ks * kchunk;
  const u16* Bbase = B + (long long)(tiN + prow) * K + scol + (long long)ks * kchunk;
  const long long r64 = 64LL * K;

  const int ab0 = wm * 8192;
  const int bb0 = 32768 + (wn >> 1) * 8192;
  const int brow = (wn & 1) * 64;

  v4f acc[8][4] = {};
  const int NT = kchunk >> 6;

#pragma unroll
  for (int hj = 0; hj < 4; hj++) {
    async16(Abase + (long long)hj * r64,
            &lds[(hj >> 1) * 8192 + (hj & 1) * 4096 + t * 8]);
    async16(Bbase + (long long)hj * r64,
            &lds[32768 + (hj >> 1) * 8192 + (hj & 1) * 4096 + t * 8]);
  }
  asm volatile("s_waitcnt vmcnt(0)" ::: "memory");
  __builtin_amdgcn_s_barrier();

  int d = 0;
  for (int kt = 0; kt < NT; ++kt) {
    const bool pf = (kt + 1 < NT);
    const int ab = ab0 + d * 16384;
    const int bb = bb0 + d * 16384;
    v8s af[4], ag[4], bf[4];

    // ---- phase 0: ksub0, mf 0-3 ----
#pragma unroll
    for (int i = 0; i < 4; i++) af[i] = *(const v8s*)&lds[ab + (i * 16 + rr) * 64 + c0];
#pragma unroll
    for (int i = 0; i < 4; i++) bf[i] = *(const v8s*)&lds[bb + (brow + i * 16 + rr) * 64 + c0];
    if (pf) {
      const u16* src = Abase + (long long)(kt + 1) * 64;
#pragma unroll
      for (int hj = 0; hj < 4; hj++)
        async16(src + (long long)hj * r64,
                &lds[((d ^ 1) * 2 + (hj >> 1)) * 8192 + (hj & 1) * 4096 + t * 8]);
    }
    __builtin_amdgcn_s_barrier();
    __builtin_amdgcn_s_setprio(1);
#pragma unroll
    for (int m = 0; m < 4; m++)
#pragma unroll
      for (int n = 0; n < 4; n++) mfma_bf16(acc[m][n], af[m], bf[n]);
    __builtin_amdgcn_s_setprio(0);
    __builtin_amdgcn_s_barrier();

    // ---- phase 1: ksub0, mf 4-7 ----
#pragma unroll
    for (int i = 0; i < 4; i++) ag[i] = *(const v8s*)&lds[ab + ((i + 4) * 16 + rr) * 64 + c0];
    if (pf) {
      const u16* src = Bbase + (long long)(kt + 1) * 64;
#pragma unroll
      for (int hj = 0; hj < 4; hj++)
        async16(src + (long long)hj * r64,
                &lds[32768 + ((d ^ 1) * 2 + (hj >> 1)) * 8192 + (hj & 1) * 4096 + t * 8]);
    }
    __builtin_amdgcn_s_barrier();
    __builtin_amdgcn_s_setprio(1);
#pragma unroll
    for (int m = 0; m < 4; m++)
#pragma unroll
      for (int n = 0; n < 4; n++) mfma_bf16(acc[4 + m][n], ag[m], bf[n]);
    __builtin_amdgcn_s_setprio(0);
    __builtin_amdgcn_s_barrier();

    // ---- phase 2: ksub1, mf 0-3 ----
#pragma unroll
    for (int i = 0; i < 4; i++) af[i] = *(const v8s*)&lds[ab + (i * 16 + rr) * 64 + c1];
#pragma unroll
    for (int i = 0; i < 4; i++) bf[i] = *(const v8s*)&lds[bb + (brow + i * 16 + rr) * 64 + c1];
    __builtin_amdgcn_s_barrier();
    __builtin_amdgcn_s_setprio(1);
#pragma unroll
    for (int m = 0; m < 4; m++)
#pragma unroll
      for (int n = 0; n < 4; n++) mfma_bf16(acc[m][n], af[m], bf[n]);
    __builtin_amdgcn_s_setprio(0);
    __builtin_amdgcn_s_barrier();

    // ---- phase 3: ksub1, mf 4-7 ----
#pragma unroll
    for (int i = 0; i < 4; i++) ag[i] = *(const v8s*)&lds[ab + ((i + 4) * 16 + rr) * 64 + c1];
    __builtin_amdgcn_s_barrier();
    __builtin_amdgcn_s_setprio(1);
#pragma unroll
    for (int m = 0; m < 4; m++)
#pragma unroll
      for (int n = 0; n < 4; n++) mfma_bf16(acc[4 + m][n], ag[m], bf[n]);
    __builtin_amdgcn_s_setprio(0);
    if (pf) asm volatile("s_waitcnt vmcnt(0)" ::: "memory");
    __builtin_amdgcn_s_barrier();
    d ^= 1;
  }

  __builtin_amdgcn_sched_barrier(0);
  asm volatile("s_nop 7\ns_nop 7\ns_nop 7");
  __builtin_amdgcn_sched_barrier(0);

  const int r4 = (lane >> 4) << 2;
  const int cc = lane & 15;
#pragma unroll
  for (int mf = 0; mf < 8; mf++)
#pragma unroll
    for (int nf = 0; nf < 4; nf++)
#pragma unroll
      for (int i = 0; i < 4; i++) {
        int row = tiM + wm * 128 + mf * 16 + r4 + i;
        int col = tiN + wn * 64 + nf * 16 + cc;
        float v = acc[mf][nf][i];
        if (EPI == 0) {
          ((u16*)Cv)[(long long)row * ldc + col] = f2b(v);
        } else if (EPI == 3) {
          float hv = v + bias[col];
          float gg = 0.5f * hv * (1.0f + erff(hv * 0.70710678118f));
          ((u16*)Cv)[(long long)row * ldc + col] = f2b(gg);
        } else {  // EPI == 5: f32 split partial
          ((float*)Cv)[((long long)ks * ROWS + row) * ldc + col] = v;
        }
      }
}

// FF2 reduce: x += sum of 4 split partials + bias
__global__ void ff2red(const float* __restrict__ part, const float* __restrict__ bias,
                       float* __restrict__ x)
{
  long long i = ((long long)blockIdx.x * 256 + threadIdx.x) * 8;  // 8192*512 floats
  int col = (int)(i & 511);
  v4f s0 = {}, s1 = {};
#pragma unroll
  for (int ks = 0; ks < 4; ks++) {
    const float* p = part + (long long)ks * (ROWS * 512LL) + i;
    s0 += *(const v4f*)p;
    s1 += *(const v4f*)(p + 4);
  }
  v4f b0 = *(const v4f*)(bias + col);
  v4f b1 = *(const v4f*)(bias + col + 4);
  v4f x0 = *(const v4f*)(x + i), x1 = *(const v4f*)(x + i + 4);
  x0 += s0 + b0;
  x1 += s1 + b1;
  *(v4f*)(x + i) = x0;
  *(v4f*)(x + i + 4) = x1;
}

// ---------------------------------------------------------------------------
// gemm2: BM=128, BN in {64,128}.  (attn-path GEMMs)
// EPI: 5 = f32 split-K partial; 6 = f32 dd*scale store + fused global atomicMax
// ---------------------------------------------------------------------------
template <int EPI, int BN, int KSPLIT>
__global__ void __launch_bounds__(256, 4)
gemm2(const u16* __restrict__ A, const u16* __restrict__ B,
      void* __restrict__ Cv, const float* __restrict__ bias,
      int K, int ldc, long long sA, long long sB, long long sC,
      float scale, int Ncap, int Mcap, unsigned int* __restrict__ gmax)
{
  __shared__ u16 As[2][128 * 32];
  __shared__ u16 Bs[2][BN * 32];
  __shared__ float smax[4];
  const int zz = blockIdx.z;
  const int z = (KSPLIT > 1) ? zz / KSPLIT : zz;
  const int ks = (KSPLIT > 1) ? zz % KSPLIT : 0;
  const int kchunk = K / KSPLIT;
  const u16* Ag = A + (long long)z * sA + ks * kchunk;
  const u16* Bg = B + (long long)z * sB + ks * kchunk;
  const int t = threadIdx.x;
  const int lane = t & 63;
  const int w = t >> 6;
  constexpr int NF = BN / 32;
  const int wm = (w >> 1) << 6;
  const int wn = (w & 1) * (BN / 2);
  const int tiM = blockIdx.x << 7, tiN = blockIdx.y * BN;

  const int srow = t >> 2;
  const int scol = (t & 3) << 3;
  const u16* Ap = Ag + (long long)(tiM + srow) * K + scol;
  const u16* Bp = Bg + (long long)(tiN + srow) * K + scol;
  const long long rstride = 64LL * K;

  const int rr = lane & 15;
  const int kc = (lane >> 4) << 3;

  v4f acc[4][NF] = {};

  const int nk = kchunk >> 5;
  auto stage = [&](int buf, int k0) {
    async16(Ap + k0, &As[buf][t * 8]);
    async16(Ap + k0 + rstride, &As[buf][t * 8 + 2048]);
    async16(Bp + k0, &Bs[buf][t * 8]);
    if (BN == 128) async16(Bp + k0 + rstride, &Bs[buf][t * 8 + 2048]);
  };

  stage(0, 0);
  __syncthreads();
  int cur = 0;
  for (int kt = 0; kt < nk; ++kt) {
    if (kt + 1 < nk) stage(cur ^ 1, (kt + 1) << 5);
    v8s af[4], bf[NF];
#pragma unroll
    for (int i = 0; i < 4; i++) af[i] = *(const v8s*)&As[cur][(wm + rr + i * 16) * 32 + kc];
#pragma unroll
    for (int i = 0; i < NF; i++) bf[i] = *(const v8s*)&Bs[cur][(wn + rr + i * 16) * 32 + kc];
#pragma unroll
    for (int fm = 0; fm < 4; fm++)
#pragma unroll
      for (int fn = 0; fn < NF; fn++)
        mfma_bf16(acc[fm][fn], af[fm], bf[fn]);
    __syncthreads();
    cur ^= 1;
  }

  __builtin_amdgcn_sched_barrier(0);
  asm volatile("s_nop 7\ns_nop 7\ns_nop 7");
  __builtin_amdgcn_sched_barrier(0);

  const int r4 = (lane >> 4) << 2;
  const int cc = lane & 15;
  float lmax = -3e38f;
#pragma unroll
  for (int fm = 0; fm < 4; fm++)
#pragma unroll
    for (int fn = 0; fn < NF; fn++)
#pragma unroll
      for (int i = 0; i < 4; i++) {
        int row = tiM + wm + fm * 16 + r4 + i;
        int col = tiN + wn + fn * 16 + cc;
        float v = acc[fm][fn][i];
        if (EPI == 5) {
          if (row < Mcap && col < Ncap)
            ((float*)Cv)[((long long)zz * M_ALLOC + row) * 64 + col] = v;
        } else if (EPI == 6) {
          float sv = v * scale;
          if (col < Ncap) ((float*)Cv)[(long long)row * ldc + col] = sv;
          if (col < M_FEAT) lmax = fmaxf(lmax, sv);
        }
      }

  if (EPI == 6) {
    lmax = wave_max(lmax);
    if (lane == 0) smax[w] = lmax;
    __syncthreads();
    if (t == 0) {
      float m = fmaxf(fmaxf(smax[0], smax[1]), fmaxf(smax[2], smax[3]));
      unsigned int u = __float_as_uint(m);
      unsigned int key = (u & 0x80000000u) ? ~u : (u | 0x80000000u);
      atomicMax(gmax, key);
    }
  }
}

// ---------------------------------------------------------------------------
// gemm_small: BM=64, BN=64, BK=32, high-occupancy variant.
// EPI: 0 bf16; 2 f32 residual += acc + bias; 3 bf16 gelu; 4 head-scatter.
// ---------------------------------------------------------------------------
template <int EPI>
__global__ void __launch_bounds__(256, 6)
gemm_small(const u16* __restrict__ A, const u16* __restrict__ B,
           void* __restrict__ Cv, const float* __restrict__ bias,
           int K, int ldc, long long sA, long long sB)
{
  __shared__ u16 As[2][64 * 32];
  __shared__ u16 Bs[2][64 * 32];
  const int z = blockIdx.z;
  const u16* Ag = A + (long long)z * sA;
  const u16* Bg = B + (long long)z * sB;
  const int t = threadIdx.x;
  const int lane = t & 63;
  const int w = t >> 6;
  const int wm = (w >> 1) << 5;
  const int wn = (w & 1) << 5;
  const int tiM = blockIdx.x << 6, tiN = blockIdx.y << 6;

  const int srow = t >> 2;
  const int scol = (t & 3) << 3;
  const u16* Ap = Ag + (long long)(tiM + srow) * K + scol;
  const u16* Bp = Bg + (long long)(tiN + srow) * K + scol;

  const int rr = lane & 15;
  const int kc = (lane >> 4) << 3;

  v4f acc[2][2] = {};

  const int nk = K >> 5;
  auto stage = [&](int buf, int k0) {
    async16(Ap + k0, &As[buf][t * 8]);
    async16(Bp + k0, &Bs[buf][t * 8]);
  };

  stage(0, 0);
  __syncthreads();
  int cur = 0;
  for (int kt = 0; kt < nk; ++kt) {
    if (kt + 1 < nk) stage(cur ^ 1, (kt + 1) << 5);
    v8s af[2], bf[2];
#pragma unroll
    for (int i = 0; i < 2; i++) af[i] = *(const v8s*)&As[cur][(wm + rr + i * 16) * 32 + kc];
#pragma unroll
    for (int i = 0; i < 2; i++) bf[i] = *(const v8s*)&Bs[cur][(wn + rr + i * 16) * 32 + kc];
#pragma unroll
    for (int fm = 0; fm < 2; fm++)
#pragma unroll
      for (int fn = 0; fn < 2; fn++)
        mfma_bf16(acc[fm][fn], af[fm], bf[fn]);
    __syncthreads();
    cur ^= 1;
  }

  __builtin_amdgcn_sched_barrier(0);
  asm volatile("s_nop 7\ns_nop 7\ns_nop 7");
  __builtin_amdgcn_sched_barrier(0);

  const int r4 = (lane >> 4) << 2;
  const int cc = lane & 15;
#pragma unroll
  for (int fm = 0; fm < 2; fm++)
#pragma unroll
    for (int fn = 0; fn < 2; fn++)
#pragma unroll
      for (int i = 0; i < 4; i++) {
        int row = tiM + wm + fm * 16 + r4 + i;
        int col = tiN + wn + fn * 16 + cc;
        float v = acc[fm][fn][i];
        if (EPI == 0) {
          ((u16*)Cv)[(long long)row * ldc + col] = f2b(v);
        } else if (EPI == 2) {
          long long idx = (long long)row * ldc + col;
          float bb = bias ? bias[col] : 0.0f;
          ((float*)Cv)[idx] += v + bb;
        } else if (EPI == 3) {
          float hv = v + bias[col];
          float gg = 0.5f * hv * (1.0f + erff(hv * 0.70710678118f));
          ((u16*)Cv)[(long long)row * ldc + col] = f2b(gg);
        } else {  // EPI == 4: head scatter (N=64 per z)
          int b_ = z >> 3, h_ = z & 7;
          ((u16*)Cv)[(long long)(b_ * N_SEQ + row) * 512 + h_ * 64 + col] = f2b(v);
        }
      }
}

// ---------------------------------------------------------------------------
// Fused dd_q -> row-max -> exp -> denominator -> qf (bf16, d_inv folded).
// 384 threads = 6 waves x 48 cols = 288; cooperative cross-wave reduces.
// ---------------------------------------------------------------------------
__global__ void __launch_bounds__(384, 3)
ddq_qf(const u16* __restrict__ qr, const u16* __restrict__ proj,
       const float* __restrict__ diag, const float* __restrict__ ksum,
       u16* __restrict__ qf)
{
  __shared__ u16 As[2][64 * 32];
  __shared__ u16 Bs[2][288 * 32];
  __shared__ float redw[6][64];
  __shared__ float rowv[64];
  __shared__ float sdg[64];
  const int bh = blockIdx.z;
  const int tiM = blockIdx.x << 6;
  const int t = threadIdx.x;
  const int lane = t & 63;
  const int w = t >> 6;          // 0..5
  const u16* Ag = qr + (long long)bh * (N_SEQ * 64);
  const int srow = t >> 2, scol = (t & 3) << 3;
  const u16* Ap = Ag + (long long)(tiM + srow) * 64 + scol;
  const int rr = lane & 15, kc = (lane >> 4) << 3;
  const int wn = w * 48;

  if (t < 64) sdg[t] = diag[(long long)bh * N_SEQ + tiM + t];

  v4f acc[4][3] = {};
  auto stage = [&](int buf, int k0) {
    if (t < 256) async16(Ap + k0, &As[buf][t * 8]);
#pragma unroll
    for (int j = 0; j < 3; j++) {
      int idx = j * 384 + t;
      async16(proj + (long long)(idx >> 2) * 64 + ((idx & 3) << 3) + k0,
              &Bs[buf][j * 3072 + t * 8]);
    }
  };

  stage(0, 0);
  __syncthreads();
  for (int kt = 0; kt < 2; ++kt) {
    if (kt == 0) stage(1, 32);
    v8s af[4], bf[3];
#pragma unroll
    for (int i = 0; i < 4; i++) af[i] = *(const v8s*)&As[kt][(rr + i * 16) * 32 + kc];
#pragma unroll
    for (int i = 0; i < 3; i++) bf[i] = *(const v8s*)&Bs[kt][(wn + i * 16 + rr) * 32 + kc];
#pragma unroll
    for (int fm = 0; fm < 4; fm++)
#pragma unroll
      for (int fn = 0; fn < 3; fn++)
        mfma_bf16(acc[fm][fn], af[fm], bf[fn]);
    __syncthreads();
  }

  __builtin_amdgcn_sched_barrier(0);
  asm volatile("s_nop 7\ns_nop 7\ns_nop 7");
  __builtin_amdgcn_sched_barrier(0);

  const int r4 = (lane >> 4) << 2;
  const int cc = lane & 15;
  const float sc = 0.35355339f;

  // phase A: per-wave row max over its 48 cols (valid cols only)
#pragma unroll
  for (int fm = 0; fm < 4; fm++)
#pragma unroll
    for (int i = 0; i < 4; i++) {
      float m = -3e38f;
#pragma unroll
      for (int fn = 0; fn < 3; fn++) {
        int col = wn + fn * 16 + cc;
        float v = acc[fm][fn][i] * sc;
        if (col < M_FEAT) m = fmaxf(m, v);
      }
#pragma unroll
      for (int o = 1; o < 16; o <<= 1) m = fmaxf(m, __shfl_xor(m, o));
      if (cc == 0) redw[w][fm * 16 + r4 + i] = m;
    }
  __syncthreads();
  if (t < 64) {
    float g = redw[0][t];
#pragma unroll
    for (int ww = 1; ww < 6; ww++) g = fmaxf(g, redw[ww][t]);
    rowv[t] = g;
  }
  __syncthreads();

  // phase B: e = ratio*(exp(dd-diag-gm)+eps); per-wave dot with ksum
  float ksv[3];
#pragma unroll
  for (int fn = 0; fn < 3; fn++) ksv[fn] = ksum[bh * M_PAD + wn + fn * 16 + cc];

#pragma unroll
  for (int fm = 0; fm < 4; fm++)
#pragma unroll
    for (int i = 0; i < 4; i++) {
      int row = fm * 16 + r4 + i;
      float gm = rowv[row];
      float dg = sdg[row];
      float s = 0.0f;
#pragma unroll
      for (int fn = 0; fn < 3; fn++) {
        float e = 0.06131389f * (expf(acc[fm][fn][i] * sc - dg - gm) + 1e-4f);
        acc[fm][fn][i] = e;
        s += e * ksv[fn];
      }
#pragma unroll
      for (int o = 1; o < 16; o <<= 1) s += __shfl_xor(s, o);
      if (cc == 0) redw[w][row] = s;
    }
  __syncthreads();
  if (t < 64) {
    float s = redw[0][t];
#pragma unroll
    for (int ww = 1; ww < 6; ww++) s += redw[ww][t];
    rowv[t] = 1.0f / s;
  }
  __syncthreads();

  // phase C: write qf * dinv (cols 266..287 garbage x ctx=0 — inert)
#pragma unroll
  for (int fm = 0; fm < 4; fm++)
#pragma unroll
    for (int i = 0; i < 4; i++) {
      int row = fm * 16 + r4 + i;
      float dinv = rowv[row];
#pragma unroll
      for (int fn = 0; fn < 3; fn++) {
        int col = wn + fn * 16 + cc;
        qf[((long long)bh * N_SEQ + tiM + row) * M_PAD + col] =
            f2b(acc[fm][fn][i] * dinv);
      }
    }
}

// ---------------------------------------------------------------------------
template <bool F32OUT>
__global__ void ln_kernel(const float* __restrict__ x, const float* __restrict__ g,
                          const float* __restrict__ b, void* __restrict__ out)
{
  const int row = blockIdx.x * 4 + (threadIdx.x >> 6);
  const int lane = threadIdx.x & 63;
  const float* xr = x + (long long)row * D_MODEL + lane * 8;
  v4f v0 = *(const v4f*)xr;
  v4f v1 = *(const v4f*)(xr + 4);
  float s = v0[0] + v0[1] + v0[2] + v0[3] + v1[0] + v1[1] + v1[2] + v1[3];
  float sq = v0[0]*v0[0] + v0[1]*v0[1] + v0[2]*v0[2] + v0[3]*v0[3]
           + v1[0]*v1[0] + v1[1]*v1[1] + v1[2]*v1[2] + v1[3]*v1[3];
  s = wave_sum(s);
  sq = wave_sum(sq);
  float mu = s * (1.0f / D_MODEL);
  float var = sq * (1.0f / D_MODEL) - mu * mu;
  float rstd = rsqrtf(var + 1e-5f);
  v4f g0 = *(const v4f*)(g + lane * 8), g1 = *(const v4f*)(g + lane * 8 + 4);
  v4f bb0 = *(const v4f*)(b + lane * 8), bb1 = *(const v4f*)(b + lane * 8 + 4);
  float y[8];
#pragma unroll
  for (int j = 0; j < 4; j++) y[j] = (v0[j] - mu) * rstd * g0[j] + bb0[j];
#pragma unroll
  for (int j = 0; j < 4; j++) y[4 + j] = (v1[j] - mu) * rstd * g1[j] + bb1[j];
  if (F32OUT) {
    float* op = (float*)out + (long long)row * D_MODEL + lane * 8;
    v4f o0 = {y[0], y[1], y[2], y[3]}, o1 = {y[4], y[5], y[6], y[7]};
    *(v4f*)op = o0;
    *(v4f*)(op + 4) = o1;
  } else {
    u16* op = (u16*)out + (long long)row * D_MODEL + lane * 8;
    alignas(16) u16 tmp[8];
#pragma unroll
    for (int j = 0; j < 8; j++) tmp[j] = f2b(y[j]);
    *(v8s*)op = *(v8s*)tmp;
  }
}

__global__ void posadd(const float* __restrict__ xin, float* __restrict__ x)
{
  long long i = (long long)blockIdx.x * 256 + threadIdx.x;
  int d = (int)(i & 511);
  int n = (int)((i >> 9) & 2047);
  int j = d & 255;
  float sarg = (float)n * expf(-0.035977892f * (float)j);
  float pe = (d < 256) ? sinf(sarg) : cosf(sarg);
  x[i] = xin[i] + pe;
}

__global__ void rotab(float* __restrict__ ts, float* __restrict__ tc)
{
  int i = blockIdx.x * 64 + threadIdx.x;  // 2048*32
  int n = i >> 5, j = i & 31;
  float sarg = (float)n * expf(-0.28782314f * (float)j);
  float s, c;
  sincosf(sarg, &s, &c);
  ts[i] = s;
  tc[i] = c;
}

__global__ void rotary_kernel(const u16* __restrict__ qkv,
                              const float* __restrict__ ts, const float* __restrict__ tc,
                              u16* __restrict__ qr, u16* __restrict__ kr,
                              float* __restrict__ dq, float* __restrict__ dk)
{
  int bid = blockIdx.x * 4 + (threadIdx.x >> 6);
  int n = bid & 2047;
  int h = (bid >> 11) & 7;
  int b = bid >> 14;
  int lane = threadIdx.x & 63;
  long long src = ((long long)(b * N_SEQ + n)) * 1536 + h * 64 + lane;
  float qv = b2f(qkv[src]);
  float kv = b2f(qkv[src + 512]);
  int j = lane >> 1;
  float sn = ts[n * 32 + j], cn = tc[n * 32 + j];
  float qp = __shfl_xor(qv, 1), kp = __shfl_xor(kv, 1);
  float qrv = (lane & 1) ? (qv * cn + qp * sn) : (qv * cn - qp * sn);
  float krv = (lane & 1) ? (kv * cn + kp * sn) : (kv * cn - kp * sn);
  u16 qb = f2b(qrv), kb = f2b(krv);
  long long dst = ((long long)bid) * 64 + lane;
  qr[dst] = qb;
  kr[dst] = kb;
  float q2 = b2f(qb); q2 *= q2;
  float k2 = b2f(kb); k2 *= k2;
  q2 = wave_sum(q2);
  k2 = wave_sum(k2);
  if (lane == 0) { dq[bid] = q2 * 0.0625f; dk[bid] = k2 * 0.0625f; }
}

__global__ void vtrans(const u16* __restrict__ qkv, u16* __restrict__ vT)
{
  int bid = blockIdx.x;  // B*H*32
  int nt = bid & 31;
  int h = (bid >> 5) & 7;
  int b = bid >> 8;
  __shared__ u16 st[64][72];
  int t = threadIdx.x;
  int r = t >> 2, c = (t & 3) << 4;
  long long src = ((long long)(b * N_SEQ + nt * 64 + r)) * 1536 + 1024 + h * 64 + c;
  *(v8s*)&st[r][c] = *(const v8s*)(qkv + src);
  *(v8s*)&st[r][c + 8] = *(const v8s*)(qkv + src + 8);
  __syncthreads();
  alignas(16) u16 tmp[16];
#pragma unroll
  for (int jj = 0; jj < 16; jj++) tmp[jj] = st[c + jj][r];
  long long dst = ((long long)((b * 8 + h) * 64 + r)) * N_SEQ + nt * 64 + c;
  *(v8s*)(vT + dst) = *(v8s*)&tmp[0];
  *(v8s*)(vT + dst + 8) = *(v8s*)&tmp[8];
}

__global__ void wtrans(const float* __restrict__ src, u16* __restrict__ dst,
                       int Ks, int Ns, long long sSrc, long long sDst)
{
  int l = blockIdx.z;
  src += (long long)l * sSrc;
  dst += (long long)l * sDst;
  int n0 = blockIdx.x << 6, k0 = blockIdx.y << 6;
  __shared__ float st[64][68];
  int t = threadIdx.x;
  int r = t >> 2, c = (t & 3) << 4;
  const float* sp = src + (long long)(k0 + r) * Ns + n0 + c;
#pragma unroll
  for (int jj = 0; jj < 16; jj += 4) *(v4f*)&st[r][c + jj] = *(const v4f*)(sp + jj);
  __syncthreads();
  alignas(16) u16 tmp[16];
#pragma unroll
  for (int jj = 0; jj < 16; jj++) tmp[jj] = f2b(st[c + jj][r]);
  u16* dp = dst + (long long)(n0 + r) * Ks + k0 + c;
  *(v8s*)(dp) = *(v8s*)&tmp[0];
  *(v8s*)(dp + 8) = *(v8s*)&tmp[8];
}

__global__ void projconv(const float* __restrict__ proj, u16* __restrict__ out)
{
  int i = blockIdx.x * 256 + threadIdx.x;  // 6*384*64
  int dh = i & 63;
  int m = (i >> 6) % M_ALLOC;
  int l = i / (M_ALLOC * 64);
  float v = (m < M_FEAT) ? proj[((long long)l * M_FEAT + m) * 64 + dh] : 0.0f;
  out[i] = f2b(v);
}

__global__ void resetmax(unsigned int* p) { *p = 0u; }

// ---------------------------------------------------------------------------
// kfprep: dd_k (bh,n,288) f32 -> kfT (bh,384,2048) bf16 + per-tile ksum partials.
// ---------------------------------------------------------------------------
__global__ void kfprep(const float* __restrict__ dd, const float* __restrict__ diag,
                       const unsigned int* __restrict__ kmax,
                       u16* __restrict__ kfT, float* __restrict__ part)
{
  int ntile = blockIdx.x;          // 32
  int m0 = blockIdx.y << 6;        // 5 tiles (0..319, cap 288)
  int bh = blockIdx.z;             // 32
  int n0 = ntile << 6;
  __shared__ float st[64][65];
  unsigned int kk = kmax[0];
  float km = (kk & 0x80000000u) ? __uint_as_float(kk ^ 0x80000000u)
                                : __uint_as_float(~kk);
  int t = threadIdx.x;
  int r = t >> 2, c = (t & 3) << 4;
  const float* dp = dd + ((long long)bh * N_SEQ + n0 + r) * M_PAD + m0 + c;
  float dg = diag[(long long)bh * N_SEQ + n0 + r];
  float vals[16];
  if (m0 + c + 16 <= M_PAD) {
#pragma unroll
    for (int j = 0; j < 16; j += 4) *(v4f*)&vals[j] = *(const v4f*)(dp + j);
  } else {
#pragma unroll
    for (int j = 0; j < 16; j++) vals[j] = (m0 + c + j < M_PAD) ? dp[j] : 0.0f;
  }
#pragma unroll
  for (int j = 0; j < 16; j++) {
    int m = m0 + c + j;
    float e = (m < M_FEAT) ? 0.06131389f * (expf(vals[j] - dg - km) + 1e-4f) : 0.0f;
    st[r][c + j] = e;
  }
  __syncthreads();
  int mr = t >> 2, nc = (t & 3) << 4;
  float s = 0.0f;
  alignas(16) u16 tmp[16];
#pragma unroll
  for (int j = 0; j < 16; j++) {
    float e = st[nc + j][mr];
    s += e;
    tmp[j] = f2b(e);
  }
  s += __shfl_xor(s, 1);
  s += __shfl_xor(s, 2);
  int m = m0 + mr;
  if (m < M_PAD) {
    u16* op = kfT + ((long long)bh * M_ALLOC + m) * N_SEQ + n0 + nc;
    *(v8s*)op = *(v8s*)&tmp[0];
    *(v8s*)(op + 8) = *(v8s*)&tmp[8];
    if ((t & 3) == 0)
      part[((long long)bh * M_PAD + m) * 32 + ntile] = s;
  }
}

__global__ void ksumred(const float* __restrict__ part, float* __restrict__ ksum)
{
  int i = blockIdx.x * 256 + threadIdx.x;  // 32*288
  if (i >= 32 * M_PAD) return;
  const float* p = part + (long long)i * 32;
  float s = 0.0f;
#pragma unroll
  for (int j = 0; j < 32; j += 4) {
    v4f v = *(const v4f*)(p + j);
    s += v[0] + v[1] + v[2] + v[3];
  }
  ksum[i] = s;
}

// reduce split-K ctx partials (8) + transpose -> ctxT (bh,64,288) bf16
__global__ void ctxred(const float* __restrict__ part, u16* __restrict__ ctxT)
{
  int bh = blockIdx.y;
  int m0 = blockIdx.x << 6;   // 5 tiles
  __shared__ float st[64][65];
  int t = threadIdx.x;
  int r = t >> 2, c = (t & 3) << 4;
  int m = m0 + r;
  v4f s[4] = {};
  if (m < M_PAD) {
    for (int ks = 0; ks < 8; ks++) {
      const float* p = part + (((long long)bh * 8 + ks) * M_ALLOC + m) * 64 + c;
#pragma unroll
      for (int j = 0; j < 4; j++) s[j] += *(const v4f*)(p + j * 4);
    }
  }
#pragma unroll
  for (int j = 0; j < 4; j++)
#pragma unroll
    for (int e = 0; e < 4; e++) st[r][c + j * 4 + e] = s[j][e];
  __syncthreads();
  int e = t >> 2, mc = (t & 3) << 4;
  if (m0 + mc < M_PAD) {
    alignas(16) u16 tmp[16];
#pragma unroll
    for (int j = 0; j < 16; j++) tmp[j] = f2b(st[mc + j][e]);
    u16* op = ctxT + ((long long)bh * 64 + e) * M_PAD + m0 + mc;
    *(v8s*)op = *(v8s*)&tmp[0];
    *(v8s*)(op + 8) = *(v8s*)&tmp[8];
  }
}

// ---------------------------------------------------------------------------
extern "C" void kernel_launch(void* const* d_in, const int* in_sizes, int n_in,
                              void* d_out, int out_size, void* d_ws, size_t ws_size,
                              hipStream_t stream)
{
  const float* x_in = (const float*)d_in[0];
  const float* Wq  = (const float*)d_in[1];
  const float* Wk  = (const float*)d_in[2];
  const float* Wv  = (const float*)d_in[3];
  const float* Wo  = (const float*)d_in[4];
  const float* Pr  = (const float*)d_in[5];
  const float* ln1g = (const float*)d_in[6];
  const float* ln1b = (const float*)d_in[7];
  const float* W1  = (const float*)d_in[8];
  const float* b1  = (const float*)d_in[9];
  const float* W2  = (const float*)d_in[10];
  const float* b2  = (const float*)d_in[11];
  const float* ln2g = (const float*)d_in[12];
  const float* ln2b = (const float*)d_in[13];
  const float* lnfg = (const float*)d_in[14];
  const float* lnfb = (const float*)d_in[15];

  // allow 128 KiB dynamic LDS for the 8-phase GEMMs
  hipFuncSetAttribute(reinterpret_cast<const void*>(&gemm8p<0, 1>),
                      hipFuncAttributeMaxDynamicSharedMemorySize, 131072);
  hipFuncSetAttribute(reinterpret_cast<const void*>(&gemm8p<3, 1>),
                      hipFuncAttributeMaxDynamicSharedMemorySize, 131072);
  hipFuncSetAttribute(reinterpret_cast<const void*>(&gemm8p<5, 4>),
                      hipFuncAttributeMaxDynamicSharedMemorySize, 131072);

  char* ws = (char*)d_ws;
  size_t off = 0;
  auto alloc = [&](size_t bytes) -> void* {
    void* p = ws + off;
    off = (off + bytes + 255) & ~(size_t)255;
    return p;
  };

  float* x      = (float*)alloc((size_t)ROWS * D_MODEL * 4);
  float* tsin   = (float*)alloc((size_t)N_SEQ * 32 * 4);
  float* tcos   = (float*)alloc((size_t)N_SEQ * 32 * 4);
  u16*   wqkvT  = (u16*)alloc((size_t)N_LAYER * 1536 * 512 * 2);
  u16*   woT    = (u16*)alloc((size_t)N_LAYER * 512 * 512 * 2);
  u16*   w1T    = (u16*)alloc((size_t)N_LAYER * 2048 * 512 * 2);
  u16*   w2T    = (u16*)alloc((size_t)N_LAYER * 512 * 2048 * 2);
  u16*   projT  = (u16*)alloc((size_t)N_LAYER * M_ALLOC * 64 * 2);
  u16*   hbuf   = (u16*)alloc((size_t)ROWS * D_MODEL * 2);
  u16*   obuf   = (u16*)alloc((size_t)ROWS * D_MODEL * 2);
  float* big    = (float*)alloc((size_t)32 * N_SEQ * M_PAD * 4);   // qkv_pre bf16 / dd f32
  u16*   qrbuf  = (u16*)alloc((size_t)BHN * 64 * 2);
  u16*   krbuf  = (u16*)alloc((size_t)BHN * 64 * 2);
  u16*   vTbuf  = (u16*)alloc((size_t)BHN * 64 * 2);
  float* diagq  = (float*)alloc((size_t)BHN * 4);
  float* diagk  = (float*)alloc((size_t)BHN * 4);
  unsigned int* kmaxu = (unsigned int*)alloc(256);
  u16*   kfT    = (u16*)alloc((size_t)32 * M_ALLOC * N_SEQ * 2);   // also qf buffer
  float* part   = (float*)alloc((size_t)32 * 8 * M_ALLOC * 64 * 4);
  float* kspart = (float*)alloc((size_t)32 * M_PAD * 32 * 4);
  u16*   ctxT   = (u16*)alloc((size_t)32 * 64 * M_PAD * 2);
  float* ksum   = (float*)alloc((size_t)32 * M_PAD * 4);
  (void)alloc(1 << 20);  // guard region for benign OOB tile reads
  (void)ws_size; (void)in_sizes; (void)n_in; (void)out_size;
  // FF2 split-K partials (67 MB) alias kfT+part (75 MB): qf/ctx partials are
  // dead by FF2 time each layer, and both regions are rewritten next layer.
  float* ff2part = (float*)kfT;

  // ---- setup ----
  posadd<<<16384, 256, 0, stream>>>(x_in, x);
  rotab<<<1024, 64, 0, stream>>>(tsin, tcos);
  wtrans<<<dim3(8, 8, 6), 256, 0, stream>>>(Wq, wqkvT, 512, 512, 512LL * 512, 1536LL * 512);
  wtrans<<<dim3(8, 8, 6), 256, 0, stream>>>(Wk, wqkvT + 512LL * 512, 512, 512, 512LL * 512, 1536LL * 512);
  wtrans<<<dim3(8, 8, 6), 256, 0, stream>>>(Wv, wqkvT + 1024LL * 512, 512, 512, 512LL * 512, 1536LL * 512);
  wtrans<<<dim3(8, 8, 6), 256, 0, stream>>>(Wo, woT, 512, 512, 512LL * 512, 512LL * 512);
  wtrans<<<dim3(32, 8, 6), 256, 0, stream>>>(W1, w1T, 512, 2048, 512LL * 2048, 2048LL * 512);
  wtrans<<<dim3(8, 32, 6), 256, 0, stream>>>(W2, w2T, 2048, 512, 2048LL * 512, 512LL * 2048);
  projconv<<<(N_LAYER * M_ALLOC * 64) / 256, 256, 0, stream>>>(Pr, projT);

  for (int l = 0; l < N_LAYER; l++) {
    const u16* wq = wqkvT + (long long)l * 1536 * 512;
    const u16* wo = woT + (long long)l * 512 * 512;
    const u16* w1 = w1T + (long long)l * 2048 * 512;
    const u16* w2 = w2T + (long long)l * 512 * 2048;
    const u16* pj = projT + (long long)l * M_ALLOC * 64;

    resetmax<<<1, 1, 0, stream>>>(kmaxu);
    // LN1 -> h
    ln_kernel<false><<<ROWS / 4, 256, 0, stream>>>(x, ln1g + l * 512, ln1b + l * 512, hbuf);
    // qkv_pre = h @ Wqkv^T  (8192 x 1536, K=512)  [8-phase 256²]
    gemm8p<0, 1><<<dim3(32, 6), 512, 131072, stream>>>(hbuf, wq, big, nullptr, 512, 1536);
    rotary_kernel<<<BHN / 4, 256, 0, stream>>>((u16*)big, tsin, tcos, qrbuf, krbuf, diagq, diagk);
    vtrans<<<1024, 256, 0, stream>>>((u16*)big, vTbuf);
    // dd_k (65536 x 288, K=64) + fused global max
    gemm2<6, 128, 1><<<dim3(512, 3, 1), 256, 0, stream>>>(krbuf, pj, big, nullptr,
        64, M_PAD, 0, 0, 0, 0.35355339f, M_PAD, BHN, kmaxu);
    // kf^T + ksum partials
    kfprep<<<dim3(32, 5, 32), 256, 0, stream>>>(big, diagk, kmaxu, kfT, kspart);
    ksumred<<<(32 * M_PAD + 255) / 256, 256, 0, stream>>>(kspart, ksum);
    // ctx = kf^T @ v  split-K=8
    gemm2<5, 64, 8><<<dim3(3, 1, 256), 256, 0, stream>>>(kfT, vTbuf, part, nullptr,
        2048, 64, (long long)M_ALLOC * N_SEQ, 64LL * N_SEQ, 0, 1.0f, 64, M_PAD, nullptr);
    ctxred<<<dim3(5, 32), 256, 0, stream>>>(part, ctxT);
    // fused dd_q -> qf
    ddq_qf<<<dim3(32, 1, 32), 384, 0, stream>>>(qrbuf, pj, diagq, ksum, kfT);
    // o = qf @ ctx^T -> head scatter
    gemm_small<4><<<dim3(32, 1, 32), 256, 0, stream>>>(kfT, ctxT, obuf, nullptr,
        M_PAD, 0, (long long)N_SEQ * M_PAD, 64LL * M_PAD);
    // x += o @ Wo^T
    gemm_small<2><<<dim3(128, 8, 1), 256, 0, stream>>>(obuf, wo, x, nullptr,
        512, 512, 0, 0);
    // LN2 -> h
    ln_kernel<false><<<ROWS / 4, 256, 0, stream>>>(x, ln2g + l * 512, ln2b + l * 512, hbuf);
    // ff = gelu(h @ W1^T + b1)  [8-phase 256²]
    gemm8p<3, 1><<<dim3(32, 8), 512, 131072, stream>>>(hbuf, w1, big, b1 + (long long)l * 2048,
        512, 2048);
    // ff2 partials = ff @ W2^T  [8-phase 256², split-K=4]
    gemm8p<5, 4><<<dim3(32, 2, 4), 512, 131072, stream>>>((u16*)big, w2, ff2part, nullptr,
        2048, 512);
    // x += sum(partials) + b2
    ff2red<<<2048, 256, 0, stream>>>(ff2part, b2 + (long long)l * 512, x);
  }

  ln_kernel<true><<<ROWS / 4, 256, 0, stream>>>(x, lnfg, lnfb, d_out);
}

// Round 7
// 1584.485 us; speedup vs baseline: 1.5032x; 1.0186x over previous
//
#include <hip/hip_runtime.h>
#include <hip/hip_bf16.h>
#include <cstdint>

typedef float v4f __attribute__((ext_vector_type(4)));
typedef short v8s __attribute__((ext_vector_type(8)));
typedef unsigned short u16;

#define N_SEQ 2048
#define D_MODEL 512
#define N_LAYER 6
#define N_HEAD 8
#define D_HEAD 64
#define M_FEAT 266
#define M_PAD 288
#define M_ALLOC 384
#define FF_DIM 2048
#define BATCH 4
#define ROWS 8192
#define BHN 65536   // B*H*N

__device__ __forceinline__ float b2f(u16 u) {
  return __uint_as_float(((uint32_t)u) << 16);
}
__device__ __forceinline__ u16 f2b(float f) {
  union { __hip_bfloat16 h; u16 u; } c;
  c.h = __float2bfloat16(f);
  return c.u;
}
__device__ __forceinline__ float wave_sum(float v) {
#pragma unroll
  for (int o = 1; o < 64; o <<= 1) v += __shfl_xor(v, o);
  return v;
}
__device__ __forceinline__ float wave_max(float v) {
#pragma unroll
  for (int o = 1; o < 64; o <<= 1) v = fmaxf(v, __shfl_xor(v, o));
  return v;
}

__device__ __forceinline__ void mfma_bf16(v4f& d, v8s a, v8s b) {
  asm volatile("v_mfma_f32_16x16x32_bf16 %0, %1, %2, %0" : "+v"(d) : "v"(a), "v"(b));
}

// async global->LDS, 16B per lane. LDS dest must be wave-linear (base + lane*16).
__device__ __forceinline__ void async16(const u16* g, u16* l) {
  __builtin_amdgcn_global_load_lds(
      (const __attribute__((address_space(1))) uint32_t*)g,
      (__attribute__((address_space(3))) uint32_t*)l, 16, 0, 0);
}

// ---------------------------------------------------------------------------
// gemm3s: 128x256 tile, BK=64, 512 threads (8 waves 2Mx4N, 64x64 each),
// 3-stage LDS ring (3 x 48KB), 2-tile-ahead staging with counted vmcnt(6) —
// tile t+1's loads (issued during t-1) are guaranteed landed at end of t
// while t+2's 6 loads stay in flight. XOR-swizzled LDS both sides.
// C = A[M x K] * B^T (B stored [N x K]).
// EPI: 0 = bf16 out; 3 = bf16 gelu(acc + bias); 5 = f32 split partial.
// ---------------------------------------------------------------------------
template <int EPI, int KSPLIT>
__global__ void __launch_bounds__(512, 2)
gemm3s(const u16* __restrict__ A, const u16* __restrict__ B,
       void* __restrict__ Cv, const float* __restrict__ bias,
       int K, int ldc)
{
  extern __shared__ u16 lds[];   // stage s at s*24576: A[128*64] then B[256*64]
  const int t = threadIdx.x;
  const int lane = t & 63;
  const int w = t >> 6;
  const int wm = w >> 2;          // 0..1  (M half, 64 rows)
  const int wn = w & 3;           // 0..3  (N quarter, 64 cols)
  const int tiM = blockIdx.x << 7, tiN = blockIdx.y << 8;
  const int ks = (KSPLIT > 1) ? blockIdx.z : 0;
  const int kchunk = K / KSPLIT;
  const int NT = kchunk >> 6;

  const int rr = lane & 15;
  const int kq = (lane >> 4) << 3;          // 0,8,16,24
  const int swz = (rr & 7) << 3;            // read-side XOR (row&7)*8
  const int c0 = kq ^ swz;                  // ksub 0
  const int c1 = (32 + kq) ^ swz;           // ksub 1

  // staging: thread t covers LDS linear (t*8 + j*4096); row = t>>3 + j*64,
  // linear col (t&7)*8, source col inverse-swizzled by (row&7).
  const int prow = t >> 3;
  const int scol = (((t & 7) ^ (prow & 7)) << 3);
  const u16* Abase = A + (long long)(tiM + prow) * K + scol + (long long)ks * kchunk;
  const u16* Bbase = B + (long long)(tiN + prow) * K + scol + (long long)ks * kchunk;
  const long long r64 = 64LL * K;

  v4f acc[4][4] = {};

  auto stageA = [&](int s, int kt) {        // 2 loads
    const u16* src = Abase + (long long)kt * 64;
    u16* dst = &lds[s * 24576 + t * 8];
    async16(src, dst);
    async16(src + r64, dst + 4096);
  };
  auto stageB1 = [&](int s, int kt, int j) {  // 1 load, j = 0..3
    async16(Bbase + (long long)kt * 64 + (long long)j * r64,
            &lds[s * 24576 + 8192 + j * 4096 + t * 8]);
  };

  // prologue: stage tiles 0 and 1 (6 loads each); wait tile 0 (leave 6 in flight)
  stageA(0, 0);
#pragma unroll
  for (int j = 0; j < 4; j++) stageB1(0, 0, j);
  stageA(1, 1);
#pragma unroll
  for (int j = 0; j < 4; j++) stageB1(1, 1, j);
  asm volatile("s_waitcnt vmcnt(6)" ::: "memory");
  __builtin_amdgcn_s_barrier();

  for (int kt = 0; kt < NT; ++kt) {
    const int s = kt % 3;
    const int sp = (kt + 2) % 3;
    const bool st = (kt + 2 < NT);
    const int ab = s * 24576;
    const int bb = ab + 8192;
    v8s af[4], bf[4];

    // ---- phase 0: ksub 0 ----
#pragma unroll
    for (int i = 0; i < 4; i++) af[i] = *(const v8s*)&lds[ab + (wm * 64 + i * 16 + rr) * 64 + c0];
#pragma unroll
    for (int i = 0; i < 4; i++) bf[i] = *(const v8s*)&lds[bb + (wn * 64 + i * 16 + rr) * 64 + c0];
    if (st) { stageA(sp, kt + 2); stageB1(sp, kt + 2, 0); }
    __builtin_amdgcn_s_barrier();
    __builtin_amdgcn_s_setprio(1);
#pragma unroll
    for (int m = 0; m < 4; m++)
#pragma unroll
      for (int n = 0; n < 4; n++) mfma_bf16(acc[m][n], af[m], bf[n]);
    __builtin_amdgcn_s_setprio(0);
    __builtin_amdgcn_s_barrier();

    // ---- phase 1: ksub 1 ----
#pragma unroll
    for (int i = 0; i < 4; i++) af[i] = *(const v8s*)&lds[ab + (wm * 64 + i * 16 + rr) * 64 + c1];
#pragma unroll
    for (int i = 0; i < 4; i++) bf[i] = *(const v8s*)&lds[bb + (wn * 64 + i * 16 + rr) * 64 + c1];
    if (st) { stageB1(sp, kt + 2, 1); stageB1(sp, kt + 2, 2); stageB1(sp, kt + 2, 3); }
    __builtin_amdgcn_s_barrier();
    __builtin_amdgcn_s_setprio(1);
#pragma unroll
    for (int m = 0; m < 4; m++)
#pragma unroll
      for (int n = 0; n < 4; n++) mfma_bf16(acc[m][n], af[m], bf[n]);
    __builtin_amdgcn_s_setprio(0);
    // counted wait: tile t+1 (issued during t-1) must be landed; t+2's 6 fly on
    if (st) asm volatile("s_waitcnt vmcnt(6)" ::: "memory");
    else    asm volatile("s_waitcnt vmcnt(0)" ::: "memory");
    __builtin_amdgcn_s_barrier();
  }

  __builtin_amdgcn_sched_barrier(0);
  asm volatile("s_nop 7\ns_nop 7\ns_nop 7");
  __builtin_amdgcn_sched_barrier(0);

  const int r4 = (lane >> 4) << 2;
  const int cc = lane & 15;
#pragma unroll
  for (int mf = 0; mf < 4; mf++)
#pragma unroll
    for (int nf = 0; nf < 4; nf++)
#pragma unroll
      for (int i = 0; i < 4; i++) {
        int row = tiM + wm * 64 + mf * 16 + r4 + i;
        int col = tiN + wn * 64 + nf * 16 + cc;
        float v = acc[mf][nf][i];
        if (EPI == 0) {
          ((u16*)Cv)[(long long)row * ldc + col] = f2b(v);
        } else if (EPI == 3) {
          float hv = v + bias[col];
          float gg = 0.5f * hv * (1.0f + erff(hv * 0.70710678118f));
          ((u16*)Cv)[(long long)row * ldc + col] = f2b(gg);
        } else {  // EPI == 5: f32 split partial
          ((float*)Cv)[((long long)ks * ROWS + row) * ldc + col] = v;
        }
      }
}

// FF2 reduce: x += sum of 2 split partials + bias
__global__ void ff2red(const float* __restrict__ part, const float* __restrict__ bias,
                       float* __restrict__ x)
{
  long long i = ((long long)blockIdx.x * 256 + threadIdx.x) * 8;  // 8192*512 floats
  int col = (int)(i & 511);
  v4f s0 = {}, s1 = {};
#pragma unroll
  for (int ks = 0; ks < 2; ks++) {
    const float* p = part + (long long)ks * (ROWS * 512LL) + i;
    s0 += *(const v4f*)p;
    s1 += *(const v4f*)(p + 4);
  }
  v4f b0 = *(const v4f*)(bias + col);
  v4f b1 = *(const v4f*)(bias + col + 4);
  v4f x0 = *(const v4f*)(x + i), x1 = *(const v4f*)(x + i + 4);
  x0 += s0 + b0;
  x1 += s1 + b1;
  *(v4f*)(x + i) = x0;
  *(v4f*)(x + i + 4) = x1;
}

// ---------------------------------------------------------------------------
// gemm2: BM=128, BN in {64,128}.  (attn-path GEMMs)
// EPI: 5 = f32 split-K partial; 6 = f32 dd*scale store + fused global atomicMax
// ---------------------------------------------------------------------------
template <int EPI, int BN, int KSPLIT>
__global__ void __launch_bounds__(256, 4)
gemm2(const u16* __restrict__ A, const u16* __restrict__ B,
      void* __restrict__ Cv, const float* __restrict__ bias,
      int K, int ldc, long long sA, long long sB, long long sC,
      float scale, int Ncap, int Mcap, unsigned int* __restrict__ gmax)
{
  __shared__ u16 As[2][128 * 32];
  __shared__ u16 Bs[2][BN * 32];
  __shared__ float smax[4];
  const int zz = blockIdx.z;
  const int z = (KSPLIT > 1) ? zz / KSPLIT : zz;
  const int ks = (KSPLIT > 1) ? zz % KSPLIT : 0;
  const int kchunk = K / KSPLIT;
  const u16* Ag = A + (long long)z * sA + ks * kchunk;
  const u16* Bg = B + (long long)z * sB + ks * kchunk;
  const int t = threadIdx.x;
  const int lane = t & 63;
  const int w = t >> 6;
  constexpr int NF = BN / 32;
  const int wm = (w >> 1) << 6;
  const int wn = (w & 1) * (BN / 2);
  const int tiM = blockIdx.x << 7, tiN = blockIdx.y * BN;

  const int srow = t >> 2;
  const int scol = (t & 3) << 3;
  const u16* Ap = Ag + (long long)(tiM + srow) * K + scol;
  const u16* Bp = Bg + (long long)(tiN + srow) * K + scol;
  const long long rstride = 64LL * K;

  const int rr = lane & 15;
  const int kc = (lane >> 4) << 3;

  v4f acc[4][NF] = {};

  const int nk = kchunk >> 5;
  auto stage = [&](int buf, int k0) {
    async16(Ap + k0, &As[buf][t * 8]);
    async16(Ap + k0 + rstride, &As[buf][t * 8 + 2048]);
    async16(Bp + k0, &Bs[buf][t * 8]);
    if (BN == 128) async16(Bp + k0 + rstride, &Bs[buf][t * 8 + 2048]);
  };

  stage(0, 0);
  __syncthreads();
  int cur = 0;
  for (int kt = 0; kt < nk; ++kt) {
    if (kt + 1 < nk) stage(cur ^ 1, (kt + 1) << 5);
    v8s af[4], bf[NF];
#pragma unroll
    for (int i = 0; i < 4; i++) af[i] = *(const v8s*)&As[cur][(wm + rr + i * 16) * 32 + kc];
#pragma unroll
    for (int i = 0; i < NF; i++) bf[i] = *(const v8s*)&Bs[cur][(wn + rr + i * 16) * 32 + kc];
#pragma unroll
    for (int fm = 0; fm < 4; fm++)
#pragma unroll
      for (int fn = 0; fn < NF; fn++)
        mfma_bf16(acc[fm][fn], af[fm], bf[fn]);
    __syncthreads();
    cur ^= 1;
  }

  __builtin_amdgcn_sched_barrier(0);
  asm volatile("s_nop 7\ns_nop 7\ns_nop 7");
  __builtin_amdgcn_sched_barrier(0);

  const int r4 = (lane >> 4) << 2;
  const int cc = lane & 15;
  float lmax = -3e38f;
#pragma unroll
  for (int fm = 0; fm < 4; fm++)
#pragma unroll
    for (int fn = 0; fn < NF; fn++)
#pragma unroll
      for (int i = 0; i < 4; i++) {
        int row = tiM + wm + fm * 16 + r4 + i;
        int col = tiN + wn + fn * 16 + cc;
        float v = acc[fm][fn][i];
        if (EPI == 5) {
          if (row < Mcap && col < Ncap)
            ((float*)Cv)[((long long)zz * M_ALLOC + row) * 64 + col] = v;
        } else if (EPI == 6) {
          float sv = v * scale;
          if (col < Ncap) ((float*)Cv)[(long long)row * ldc + col] = sv;
          if (col < M_FEAT) lmax = fmaxf(lmax, sv);
        }
      }

  if (EPI == 6) {
    lmax = wave_max(lmax);
    if (lane == 0) smax[w] = lmax;
    __syncthreads();
    if (t == 0) {
      float m = fmaxf(fmaxf(smax[0], smax[1]), fmaxf(smax[2], smax[3]));
      unsigned int u = __float_as_uint(m);
      unsigned int key = (u & 0x80000000u) ? ~u : (u | 0x80000000u);
      atomicMax(gmax, key);
    }
  }
}

// ---------------------------------------------------------------------------
// gemm_small: BM=64, BN=64, BK=32, high-occupancy variant.
// EPI: 0 bf16; 2 f32 residual += acc + bias; 3 bf16 gelu; 4 head-scatter.
// ---------------------------------------------------------------------------
template <int EPI>
__global__ void __launch_bounds__(256, 6)
gemm_small(const u16* __restrict__ A, const u16* __restrict__ B,
           void* __restrict__ Cv, const float* __restrict__ bias,
           int K, int ldc, long long sA, long long sB)
{
  __shared__ u16 As[2][64 * 32];
  __shared__ u16 Bs[2][64 * 32];
  const int z = blockIdx.z;
  const u16* Ag = A + (long long)z * sA;
  const u16* Bg = B + (long long)z * sB;
  const int t = threadIdx.x;
  const int lane = t & 63;
  const int w = t >> 6;
  const int wm = (w >> 1) << 5;
  const int wn = (w & 1) << 5;
  const int tiM = blockIdx.x << 6, tiN = blockIdx.y << 6;

  const int srow = t >> 2;
  const int scol = (t & 3) << 3;
  const u16* Ap = Ag + (long long)(tiM + srow) * K + scol;
  const u16* Bp = Bg + (long long)(tiN + srow) * K + scol;

  const int rr = lane & 15;
  const int kc = (lane >> 4) << 3;

  v4f acc[2][2] = {};

  const int nk = K >> 5;
  auto stage = [&](int buf, int k0) {
    async16(Ap + k0, &As[buf][t * 8]);
    async16(Bp + k0, &Bs[buf][t * 8]);
  };

  stage(0, 0);
  __syncthreads();
  int cur = 0;
  for (int kt = 0; kt < nk; ++kt) {
    if (kt + 1 < nk) stage(cur ^ 1, (kt + 1) << 5);
    v8s af[2], bf[2];
#pragma unroll
    for (int i = 0; i < 2; i++) af[i] = *(const v8s*)&As[cur][(wm + rr + i * 16) * 32 + kc];
#pragma unroll
    for (int i = 0; i < 2; i++) bf[i] = *(const v8s*)&Bs[cur][(wn + rr + i * 16) * 32 + kc];
#pragma unroll
    for (int fm = 0; fm < 2; fm++)
#pragma unroll
      for (int fn = 0; fn < 2; fn++)
        mfma_bf16(acc[fm][fn], af[fm], bf[fn]);
    __syncthreads();
    cur ^= 1;
  }

  __builtin_amdgcn_sched_barrier(0);
  asm volatile("s_nop 7\ns_nop 7\ns_nop 7");
  __builtin_amdgcn_sched_barrier(0);

  const int r4 = (lane >> 4) << 2;
  const int cc = lane & 15;
#pragma unroll
  for (int fm = 0; fm < 2; fm++)
#pragma unroll
    for (int fn = 0; fn < 2; fn++)
#pragma unroll
      for (int i = 0; i < 4; i++) {
        int row = tiM + wm + fm * 16 + r4 + i;
        int col = tiN + wn + fn * 16 + cc;
        float v = acc[fm][fn][i];
        if (EPI == 0) {
          ((u16*)Cv)[(long long)row * ldc + col] = f2b(v);
        } else if (EPI == 2) {
          long long idx = (long long)row * ldc + col;
          float bb = bias ? bias[col] : 0.0f;
          ((float*)Cv)[idx] += v + bb;
        } else if (EPI == 3) {
          float hv = v + bias[col];
          float gg = 0.5f * hv * (1.0f + erff(hv * 0.70710678118f));
          ((u16*)Cv)[(long long)row * ldc + col] = f2b(gg);
        } else {  // EPI == 4: head scatter (N=64 per z)
          int b_ = z >> 3, h_ = z & 7;
          ((u16*)Cv)[(long long)(b_ * N_SEQ + row) * 512 + h_ * 64 + col] = f2b(v);
        }
      }
}

// ---------------------------------------------------------------------------
// Fused dd_q -> row-max -> exp -> denominator -> qf (bf16, d_inv folded).
// 384 threads = 6 waves x 48 cols = 288; cooperative cross-wave reduces.
// ---------------------------------------------------------------------------
__global__ void __launch_bounds__(384, 3)
ddq_qf(const u16* __restrict__ qr, const u16* __restrict__ proj,
       const float* __restrict__ diag, const float* __restrict__ ksum,
       u16* __restrict__ qf)
{
  __shared__ u16 As[2][64 * 32];
  __shared__ u16 Bs[2][288 * 32];
  __shared__ float redw[6][64];
  __shared__ float rowv[64];
  __shared__ float sdg[64];
  const int bh = blockIdx.z;
  const int tiM = blockIdx.x << 6;
  const int t = threadIdx.x;
  const int lane = t & 63;
  const int w = t >> 6;          // 0..5
  const u16* Ag = qr + (long long)bh * (N_SEQ * 64);
  const int srow = t >> 2, scol = (t & 3) << 3;
  const u16* Ap = Ag + (long long)(tiM + srow) * 64 + scol;
  const int rr = lane & 15, kc = (lane >> 4) << 3;
  const int wn = w * 48;

  if (t < 64) sdg[t] = diag[(long long)bh * N_SEQ + tiM + t];

  v4f acc[4][3] = {};
  auto stage = [&](int buf, int k0) {
    if (t < 256) async16(Ap + k0, &As[buf][t * 8]);
#pragma unroll
    for (int j = 0; j < 3; j++) {
      int idx = j * 384 + t;
      async16(proj + (long long)(idx >> 2) * 64 + ((idx & 3) << 3) + k0,
              &Bs[buf][j * 3072 + t * 8]);
    }
  };

  stage(0, 0);
  __syncthreads();
  for (int kt = 0; kt < 2; ++kt) {
    if (kt == 0) stage(1, 32);
    v8s af[4], bf[3];
#pragma unroll
    for (int i = 0; i < 4; i++) af[i] = *(const v8s*)&As[kt][(rr + i * 16) * 32 + kc];
#pragma unroll
    for (int i = 0; i < 3; i++) bf[i] = *(const v8s*)&Bs[kt][(wn + i * 16 + rr) * 32 + kc];
#pragma unroll
    for (int fm = 0; fm < 4; fm++)
#pragma unroll
      for (int fn = 0; fn < 3; fn++)
        mfma_bf16(acc[fm][fn], af[fm], bf[fn]);
    __syncthreads();
  }

  __builtin_amdgcn_sched_barrier(0);
  asm volatile("s_nop 7\ns_nop 7\ns_nop 7");
  __builtin_amdgcn_sched_barrier(0);

  const int r4 = (lane >> 4) << 2;
  const int cc = lane & 15;
  const float sc = 0.35355339f;

  // phase A: per-wave row max over its 48 cols (valid cols only)
#pragma unroll
  for (int fm = 0; fm < 4; fm++)
#pragma unroll
    for (int i = 0; i < 4; i++) {
      float m = -3e38f;
#pragma unroll
      for (int fn = 0; fn < 3; fn++) {
        int col = wn + fn * 16 + cc;
        float v = acc[fm][fn][i] * sc;
        if (col < M_FEAT) m = fmaxf(m, v);
      }
#pragma unroll
      for (int o = 1; o < 16; o <<= 1) m = fmaxf(m, __shfl_xor(m, o));
      if (cc == 0) redw[w][fm * 16 + r4 + i] = m;
    }
  __syncthreads();
  if (t < 64) {
    float g = redw[0][t];
#pragma unroll
    for (int ww = 1; ww < 6; ww++) g = fmaxf(g, redw[ww][t]);
    rowv[t] = g;
  }
  __syncthreads();

  // phase B: e = ratio*(exp(dd-diag-gm)+eps); per-wave dot with ksum
  float ksv[3];
#pragma unroll
  for (int fn = 0; fn < 3; fn++) ksv[fn] = ksum[bh * M_PAD + wn + fn * 16 + cc];

#pragma unroll
  for (int fm = 0; fm < 4; fm++)
#pragma unroll
    for (int i = 0; i < 4; i++) {
      int row = fm * 16 + r4 + i;
      float gm = rowv[row];
      float dg = sdg[row];
      float s = 0.0f;
#pragma unroll
      for (int fn = 0; fn < 3; fn++) {
        float e = 0.06131389f * (expf(acc[fm][fn][i] * sc - dg - gm) + 1e-4f);
        acc[fm][fn][i] = e;
        s += e * ksv[fn];
      }
#pragma unroll
      for (int o = 1; o < 16; o <<= 1) s += __shfl_xor(s, o);
      if (cc == 0) redw[w][row] = s;
    }
  __syncthreads();
  if (t < 64) {
    float s = redw[0][t];
#pragma unroll
    for (int ww = 1; ww < 6; ww++) s += redw[ww][t];
    rowv[t] = 1.0f / s;
  }
  __syncthreads();

  // phase C: write qf * dinv (cols 266..287 garbage x ctx=0 — inert)
#pragma unroll
  for (int fm = 0; fm < 4; fm++)
#pragma unroll
    for (int i = 0; i < 4; i++) {
      int row = fm * 16 + r4 + i;
      float dinv = rowv[row];
#pragma unroll
      for (int fn = 0; fn < 3; fn++) {
        int col = wn + fn * 16 + cc;
        qf[((long long)bh * N_SEQ + tiM + row) * M_PAD + col] =
            f2b(acc[fm][fn][i] * dinv);
      }
    }
}

// ---------------------------------------------------------------------------
template <bool F32OUT>
__global__ void ln_kernel(const float* __restrict__ x, const float* __restrict__ g,
                          const float* __restrict__ b, void* __restrict__ out)
{
  const int row = blockIdx.x * 4 + (threadIdx.x >> 6);
  const int lane = threadIdx.x & 63;
  const float* xr = x + (long long)row * D_MODEL + lane * 8;
  v4f v0 = *(const v4f*)xr;
  v4f v1 = *(const v4f*)(xr + 4);
  float s = v0[0] + v0[1] + v0[2] + v0[3] + v1[0] + v1[1] + v1[2] + v1[3];
  float sq = v0[0]*v0[0] + v0[1]*v0[1] + v0[2]*v0[2] + v0[3]*v0[3]
           + v1[0]*v1[0] + v1[1]*v1[1] + v1[2]*v1[2] + v1[3]*v1[3];
  s = wave_sum(s);
  sq = wave_sum(sq);
  float mu = s * (1.0f / D_MODEL);
  float var = sq * (1.0f / D_MODEL) - mu * mu;
  float rstd = rsqrtf(var + 1e-5f);
  v4f g0 = *(const v4f*)(g + lane * 8), g1 = *(const v4f*)(g + lane * 8 + 4);
  v4f bb0 = *(const v4f*)(b + lane * 8), bb1 = *(const v4f*)(b + lane * 8 + 4);
  float y[8];
#pragma unroll
  for (int j = 0; j < 4; j++) y[j] = (v0[j] - mu) * rstd * g0[j] + bb0[j];
#pragma unroll
  for (int j = 0; j < 4; j++) y[4 + j] = (v1[j] - mu) * rstd * g1[j] + bb1[j];
  if (F32OUT) {
    float* op = (float*)out + (long long)row * D_MODEL + lane * 8;
    v4f o0 = {y[0], y[1], y[2], y[3]}, o1 = {y[4], y[5], y[6], y[7]};
    *(v4f*)op = o0;
    *(v4f*)(op + 4) = o1;
  } else {
    u16* op = (u16*)out + (long long)row * D_MODEL + lane * 8;
    alignas(16) u16 tmp[8];
#pragma unroll
    for (int j = 0; j < 8; j++) tmp[j] = f2b(y[j]);
    *(v8s*)op = *(v8s*)tmp;
  }
}

__global__ void posadd(const float* __restrict__ xin, float* __restrict__ x)
{
  long long i = (long long)blockIdx.x * 256 + threadIdx.x;
  int d = (int)(i & 511);
  int n = (int)((i >> 9) & 2047);
  int j = d & 255;
  float sarg = (float)n * expf(-0.035977892f * (float)j);
  float pe = (d < 256) ? sinf(sarg) : cosf(sarg);
  x[i] = xin[i] + pe;
}

__global__ void rotab(float* __restrict__ ts, float* __restrict__ tc)
{
  int i = blockIdx.x * 64 + threadIdx.x;  // 2048*32
  int n = i >> 5, j = i & 31;
  float sarg = (float)n * expf(-0.28782314f * (float)j);
  float s, c;
  sincosf(sarg, &s, &c);
  ts[i] = s;
  tc[i] = c;
}

__global__ void rotary_kernel(const u16* __restrict__ qkv,
                              const float* __restrict__ ts, const float* __restrict__ tc,
                              u16* __restrict__ qr, u16* __restrict__ kr,
                              float* __restrict__ dq, float* __restrict__ dk)
{
  int bid = blockIdx.x * 4 + (threadIdx.x >> 6);
  int n = bid & 2047;
  int h = (bid >> 11) & 7;
  int b = bid >> 14;
  int lane = threadIdx.x & 63;
  long long src = ((long long)(b * N_SEQ + n)) * 1536 + h * 64 + lane;
  float qv = b2f(qkv[src]);
  float kv = b2f(qkv[src + 512]);
  int j = lane >> 1;
  float sn = ts[n * 32 + j], cn = tc[n * 32 + j];
  float qp = __shfl_xor(qv, 1), kp = __shfl_xor(kv, 1);
  float qrv = (lane & 1) ? (qv * cn + qp * sn) : (qv * cn - qp * sn);
  float krv = (lane & 1) ? (kv * cn + kp * sn) : (kv * cn - kp * sn);
  u16 qb = f2b(qrv), kb = f2b(krv);
  long long dst = ((long long)bid) * 64 + lane;
  qr[dst] = qb;
  kr[dst] = kb;
  float q2 = b2f(qb); q2 *= q2;
  float k2 = b2f(kb); k2 *= k2;
  q2 = wave_sum(q2);
  k2 = wave_sum(k2);
  if (lane == 0) { dq[bid] = q2 * 0.0625f; dk[bid] = k2 * 0.0625f; }
}

__global__ void vtrans(const u16* __restrict__ qkv, u16* __restrict__ vT)
{
  int bid = blockIdx.x;  // B*H*32
  int nt = bid & 31;
  int h = (bid >> 5) & 7;
  int b = bid >> 8;
  __shared__ u16 st[64][72];
  int t = threadIdx.x;
  int r = t >> 2, c = (t & 3) << 4;
  long long src = ((long long)(b * N_SEQ + nt * 64 + r)) * 1536 + 1024 + h * 64 + c;
  *(v8s*)&st[r][c] = *(const v8s*)(qkv + src);
  *(v8s*)&st[r][c + 8] = *(const v8s*)(qkv + src + 8);
  __syncthreads();
  alignas(16) u16 tmp[16];
#pragma unroll
  for (int jj = 0; jj < 16; jj++) tmp[jj] = st[c + jj][r];
  long long dst = ((long long)((b * 8 + h) * 64 + r)) * N_SEQ + nt * 64 + c;
  *(v8s*)(vT + dst) = *(v8s*)&tmp[0];
  *(v8s*)(vT + dst + 8) = *(v8s*)&tmp[8];
}

__global__ void wtrans(const float* __restrict__ src, u16* __restrict__ dst,
                       int Ks, int Ns, long long sSrc, long long sDst)
{
  int l = blockIdx.z;
  src += (long long)l * sSrc;
  dst += (long long)l * sDst;
  int n0 = blockIdx.x << 6, k0 = blockIdx.y << 6;
  __shared__ float st[64][68];
  int t = threadIdx.x;
  int r = t >> 2, c = (t & 3) << 4;
  const float* sp = src + (long long)(k0 + r) * Ns + n0 + c;
#pragma unroll
  for (int jj = 0; jj < 16; jj += 4) *(v4f*)&st[r][c + jj] = *(const v4f*)(sp + jj);
  __syncthreads();
  alignas(16) u16 tmp[16];
#pragma unroll
  for (int jj = 0; jj < 16; jj++) tmp[jj] = f2b(st[c + jj][r]);
  u16* dp = dst + (long long)(n0 + r) * Ks + k0 + c;
  *(v8s*)(dp) = *(v8s*)&tmp[0];
  *(v8s*)(dp + 8) = *(v8s*)&tmp[8];
}

__global__ void projconv(const float* __restrict__ proj, u16* __restrict__ out)
{
  int i = blockIdx.x * 256 + threadIdx.x;  // 6*384*64
  int dh = i & 63;
  int m = (i >> 6) % M_ALLOC;
  int l = i / (M_ALLOC * 64);
  float v = (m < M_FEAT) ? proj[((long long)l * M_FEAT + m) * 64 + dh] : 0.0f;
  out[i] = f2b(v);
}

__global__ void resetmax(unsigned int* p) { *p = 0u; }

// ---------------------------------------------------------------------------
// kfprep: dd_k (bh,n,288) f32 -> kfT (bh,384,2048) bf16 + per-tile ksum partials.
// ---------------------------------------------------------------------------
__global__ void kfprep(const float* __restrict__ dd, const float* __restrict__ diag,
                       const unsigned int* __restrict__ kmax,
                       u16* __restrict__ kfT, float* __restrict__ part)
{
  int ntile = blockIdx.x;          // 32
  int m0 = blockIdx.y << 6;        // 5 tiles (0..319, cap 288)
  int bh = blockIdx.z;             // 32
  int n0 = ntile << 6;
  __shared__ float st[64][65];
  unsigned int kk = kmax[0];
  float km = (kk & 0x80000000u) ? __uint_as_float(kk ^ 0x80000000u)
                                : __uint_as_float(~kk);
  int t = threadIdx.x;
  int r = t >> 2, c = (t & 3) << 4;
  const float* dp = dd + ((long long)bh * N_SEQ + n0 + r) * M_PAD + m0 + c;
  float dg = diag[(long long)bh * N_SEQ + n0 + r];
  float vals[16];
  if (m0 + c + 16 <= M_PAD) {
#pragma unroll
    for (int j = 0; j < 16; j += 4) *(v4f*)&vals[j] = *(const v4f*)(dp + j);
  } else {
#pragma unroll
    for (int j = 0; j < 16; j++) vals[j] = (m0 + c + j < M_PAD) ? dp[j] : 0.0f;
  }
#pragma unroll
  for (int j = 0; j < 16; j++) {
    int m = m0 + c + j;
    float e = (m < M_FEAT) ? 0.06131389f * (expf(vals[j] - dg - km) + 1e-4f) : 0.0f;
    st[r][c + j] = e;
  }
  __syncthreads();
  int mr = t >> 2, nc = (t & 3) << 4;
  float s = 0.0f;
  alignas(16) u16 tmp[16];
#pragma unroll
  for (int j = 0; j < 16; j++) {
    float e = st[nc + j][mr];
    s += e;
    tmp[j] = f2b(e);
  }
  s += __shfl_xor(s, 1);
  s += __shfl_xor(s, 2);
  int m = m0 + mr;
  if (m < M_PAD) {
    u16* op = kfT + ((long long)bh * M_ALLOC + m) * N_SEQ + n0 + nc;
    *(v8s*)op = *(v8s*)&tmp[0];
    *(v8s*)(op + 8) = *(v8s*)&tmp[8];
    if ((t & 3) == 0)
      part[((long long)bh * M_PAD + m) * 32 + ntile] = s;
  }
}

__global__ void ksumred(const float* __restrict__ part, float* __restrict__ ksum)
{
  int i = blockIdx.x * 256 + threadIdx.x;  // 32*288
  if (i >= 32 * M_PAD) return;
  const float* p = part + (long long)i * 32;
  float s = 0.0f;
#pragma unroll
  for (int j = 0; j < 32; j += 4) {
    v4f v = *(const v4f*)(p + j);
    s += v[0] + v[1] + v[2] + v[3];
  }
  ksum[i] = s;
}

// reduce split-K ctx partials (8) + transpose -> ctxT (bh,64,288) bf16
__global__ void ctxred(const float* __restrict__ part, u16* __restrict__ ctxT)
{
  int bh = blockIdx.y;
  int m0 = blockIdx.x << 6;   // 5 tiles
  __shared__ float st[64][65];
  int t = threadIdx.x;
  int r = t >> 2, c = (t & 3) << 4;
  int m = m0 + r;
  v4f s[4] = {};
  if (m < M_PAD) {
    for (int ks = 0; ks < 8; ks++) {
      const float* p = part + (((long long)bh * 8 + ks) * M_ALLOC + m) * 64 + c;
#pragma unroll
      for (int j = 0; j < 4; j++) s[j] += *(const v4f*)(p + j * 4);
    }
  }
#pragma unroll
  for (int j = 0; j < 4; j++)
#pragma unroll
    for (int e = 0; e < 4; e++) st[r][c + j * 4 + e] = s[j][e];
  __syncthreads();
  int e = t >> 2, mc = (t & 3) << 4;
  if (m0 + mc < M_PAD) {
    alignas(16) u16 tmp[16];
#pragma unroll
    for (int j = 0; j < 16; j++) tmp[j] = f2b(st[mc + j][e]);
    u16* op = ctxT + ((long long)bh * 64 + e) * M_PAD + m0 + mc;
    *(v8s*)op = *(v8s*)&tmp[0];
    *(v8s*)(op + 8) = *(v8s*)&tmp[8];
  }
}

// ---------------------------------------------------------------------------
extern "C" void kernel_launch(void* const* d_in, const int* in_sizes, int n_in,
                              void* d_out, int out_size, void* d_ws, size_t ws_size,
                              hipStream_t stream)
{
  const float* x_in = (const float*)d_in[0];
  const float* Wq  = (const float*)d_in[1];
  const float* Wk  = (const float*)d_in[2];
  const float* Wv  = (const float*)d_in[3];
  const float* Wo  = (const float*)d_in[4];
  const float* Pr  = (const float*)d_in[5];
  const float* ln1g = (const float*)d_in[6];
  const float* ln1b = (const float*)d_in[7];
  const float* W1  = (const float*)d_in[8];
  const float* b1  = (const float*)d_in[9];
  const float* W2  = (const float*)d_in[10];
  const float* b2  = (const float*)d_in[11];
  const float* ln2g = (const float*)d_in[12];
  const float* ln2b = (const float*)d_in[13];
  const float* lnfg = (const float*)d_in[14];
  const float* lnfb = (const float*)d_in[15];

  // allow 144 KiB dynamic LDS for the 3-stage GEMMs
  hipFuncSetAttribute(reinterpret_cast<const void*>(&gemm3s<0, 1>),
                      hipFuncAttributeMaxDynamicSharedMemorySize, 147456);
  hipFuncSetAttribute(reinterpret_cast<const void*>(&gemm3s<3, 1>),
                      hipFuncAttributeMaxDynamicSharedMemorySize, 147456);
  hipFuncSetAttribute(reinterpret_cast<const void*>(&gemm3s<5, 2>),
                      hipFuncAttributeMaxDynamicSharedMemorySize, 147456);

  char* ws = (char*)d_ws;
  size_t off = 0;
  auto alloc = [&](size_t bytes) -> void* {
    void* p = ws + off;
    off = (off + bytes + 255) & ~(size_t)255;
    return p;
  };

  float* x      = (float*)alloc((size_t)ROWS * D_MODEL * 4);
  float* tsin   = (float*)alloc((size_t)N_SEQ * 32 * 4);
  float* tcos   = (float*)alloc((size_t)N_SEQ * 32 * 4);
  u16*   wqkvT  = (u16*)alloc((size_t)N_LAYER * 1536 * 512 * 2);
  u16*   woT    = (u16*)alloc((size_t)N_LAYER * 512 * 512 * 2);
  u16*   w1T    = (u16*)alloc((size_t)N_LAYER * 2048 * 512 * 2);
  u16*   w2T    = (u16*)alloc((size_t)N_LAYER * 512 * 2048 * 2);
  u16*   projT  = (u16*)alloc((size_t)N_LAYER * M_ALLOC * 64 * 2);
  u16*   hbuf   = (u16*)alloc((size_t)ROWS * D_MODEL * 2);
  u16*   obuf   = (u16*)alloc((size_t)ROWS * D_MODEL * 2);
  float* big    = (float*)alloc((size_t)32 * N_SEQ * M_PAD * 4);   // qkv_pre bf16 / dd f32
  u16*   qrbuf  = (u16*)alloc((size_t)BHN * 64 * 2);
  u16*   krbuf  = (u16*)alloc((size_t)BHN * 64 * 2);
  u16*   vTbuf  = (u16*)alloc((size_t)BHN * 64 * 2);
  float* diagq  = (float*)alloc((size_t)BHN * 4);
  float* diagk  = (float*)alloc((size_t)BHN * 4);
  unsigned int* kmaxu = (unsigned int*)alloc(256);
  u16*   kfT    = (u16*)alloc((size_t)32 * M_ALLOC * N_SEQ * 2);   // also qf buffer
  float* part   = (float*)alloc((size_t)32 * 8 * M_ALLOC * 64 * 4);
  float* kspart = (float*)alloc((size_t)32 * M_PAD * 32 * 4);
  u16*   ctxT   = (u16*)alloc((size_t)32 * 64 * M_PAD * 2);
  float* ksum   = (float*)alloc((size_t)32 * M_PAD * 4);
  (void)alloc(1 << 20);  // guard region for benign OOB tile reads
  (void)ws_size; (void)in_sizes; (void)n_in; (void)out_size;
  // FF2 split-K partials (2 x 16 MB) alias kfT+part: qf/ctx partials are dead
  // by FF2 time each layer, and both regions are rewritten next layer.
  float* ff2part = (float*)kfT;

  // ---- setup ----
  posadd<<<16384, 256, 0, stream>>>(x_in, x);
  rotab<<<1024, 64, 0, stream>>>(tsin, tcos);
  wtrans<<<dim3(8, 8, 6), 256, 0, stream>>>(Wq, wqkvT, 512, 512, 512LL * 512, 1536LL * 512);
  wtrans<<<dim3(8, 8, 6), 256, 0, stream>>>(Wk, wqkvT + 512LL * 512, 512, 512, 512LL * 512, 1536LL * 512);
  wtrans<<<dim3(8, 8, 6), 256, 0, stream>>>(Wv, wqkvT + 1024LL * 512, 512, 512, 512LL * 512, 1536LL * 512);
  wtrans<<<dim3(8, 8, 6), 256, 0, stream>>>(Wo, woT, 512, 512, 512LL * 512, 512LL * 512);
  wtrans<<<dim3(32, 8, 6), 256, 0, stream>>>(W1, w1T, 512, 2048, 512LL * 2048, 2048LL * 512);
  wtrans<<<dim3(8, 32, 6), 256, 0, stream>>>(W2, w2T, 2048, 512, 2048LL * 512, 512LL * 2048);
  projconv<<<(N_LAYER * M_ALLOC * 64) / 256, 256, 0, stream>>>(Pr, projT);

  for (int l = 0; l < N_LAYER; l++) {
    const u16* wq = wqkvT + (long long)l * 1536 * 512;
    const u16* wo = woT + (long long)l * 512 * 512;
    const u16* w1 = w1T + (long long)l * 2048 * 512;
    const u16* w2 = w2T + (long long)l * 512 * 2048;
    const u16* pj = projT + (long long)l * M_ALLOC * 64;

    resetmax<<<1, 1, 0, stream>>>(kmaxu);
    // LN1 -> h
    ln_kernel<false><<<ROWS / 4, 256, 0, stream>>>(x, ln1g + l * 512, ln1b + l * 512, hbuf);
    // qkv_pre = h @ Wqkv^T  (8192 x 1536, K=512)  [3-stage 128x256]
    gemm3s<0, 1><<<dim3(64, 6), 512, 147456, stream>>>(hbuf, wq, big, nullptr, 512, 1536);
    rotary_kernel<<<BHN / 4, 256, 0, stream>>>((u16*)big, tsin, tcos, qrbuf, krbuf, diagq, diagk);
    vtrans<<<1024, 256, 0, stream>>>((u16*)big, vTbuf);
    // dd_k (65536 x 288, K=64) + fused global max
    gemm2<6, 128, 1><<<dim3(512, 3, 1), 256, 0, stream>>>(krbuf, pj, big, nullptr,
        64, M_PAD, 0, 0, 0, 0.35355339f, M_PAD, BHN, kmaxu);
    // kf^T + ksum partials
    kfprep<<<dim3(32, 5, 32), 256, 0, stream>>>(big, diagk, kmaxu, kfT, kspart);
    ksumred<<<(32 * M_PAD + 255) / 256, 256, 0, stream>>>(kspart, ksum);
    // ctx = kf^T @ v  split-K=8
    gemm2<5, 64, 8><<<dim3(3, 1, 256), 256, 0, stream>>>(kfT, vTbuf, part, nullptr,
        2048, 64, (long long)M_ALLOC * N_SEQ, 64LL * N_SEQ, 0, 1.0f, 64, M_PAD, nullptr);
    ctxred<<<dim3(5, 32), 256, 0, stream>>>(part, ctxT);
    // fused dd_q -> qf
    ddq_qf<<<dim3(32, 1, 32), 384, 0, stream>>>(qrbuf, pj, diagq, ksum, kfT);
    // o = qf @ ctx^T -> head scatter
    gemm_small<4><<<dim3(32, 1, 32), 256, 0, stream>>>(kfT, ctxT, obuf, nullptr,
        M_PAD, 0, (long long)N_SEQ * M_PAD, 64LL * M_PAD);
    // x += o @ Wo^T
    gemm_small<2><<<dim3(128, 8, 1), 256, 0, stream>>>(obuf, wo, x, nullptr,
        512, 512, 0, 0);
    // LN2 -> h
    ln_kernel<false><<<ROWS / 4, 256, 0, stream>>>(x, ln2g + l * 512, ln2b + l * 512, hbuf);
    // ff = gelu(h @ W1^T + b1)  [3-stage 128x256]
    gemm3s<3, 1><<<dim3(64, 8), 512, 147456, stream>>>(hbuf, w1, big, b1 + (long long)l * 2048,
        512, 2048);
    // ff2 partials = ff @ W2^T  [3-stage 128x256, split-K=2]
    gemm3s<5, 2><<<dim3(64, 2, 2), 512, 147456, stream>>>((u16*)big, w2, ff2part, nullptr,
        2048, 512);
    // x += sum(partials) + b2
    ff2red<<<2048, 256, 0, stream>>>(ff2part, b2 + (long long)l * 512, x);
  }

  ln_kernel<true><<<ROWS / 4, 256, 0, stream>>>(x, lnfg, lnfb, d_out);
}

// Round 8
// 1525.776 us; speedup vs baseline: 1.5610x; 1.0385x over previous
//
#include <hip/hip_runtime.h>
#include <hip/hip_bf16.h>
#include <cstdint>

typedef float v4f __attribute__((ext_vector_type(4)));
typedef short v8s __attribute__((ext_vector_type(8)));
typedef unsigned short u16;

#define N_SEQ 2048
#define D_MODEL 512
#define N_LAYER 6
#define N_HEAD 8
#define D_HEAD 64
#define M_FEAT 266
#define M_PAD 288
#define M_ALLOC 384
#define FF_DIM 2048
#define BATCH 4
#define ROWS 8192
#define BHN 65536   // B*H*N

__device__ __forceinline__ float b2f(u16 u) {
  return __uint_as_float(((uint32_t)u) << 16);
}
__device__ __forceinline__ u16 f2b(float f) {
  union { __hip_bfloat16 h; u16 u; } c;
  c.h = __float2bfloat16(f);
  return c.u;
}
__device__ __forceinline__ float wave_sum(float v) {
#pragma unroll
  for (int o = 1; o < 64; o <<= 1) v += __shfl_xor(v, o);
  return v;
}
__device__ __forceinline__ float wave_max(float v) {
#pragma unroll
  for (int o = 1; o < 64; o <<= 1) v = fmaxf(v, __shfl_xor(v, o));
  return v;
}

// exact-erf gelu via Abramowitz-Stegun 7.1.26 (|erf err| <= 1.5e-7):
// ~12 VALU + v_exp vs libm erff's ~40 branchy ops.
__device__ __forceinline__ float gelu_f(float x) {
  float ax = fabsf(x) * 0.70710678118f;
  float tt = __builtin_amdgcn_rcpf(fmaf(0.3275911f, ax, 1.0f));
  float poly = tt * fmaf(tt, fmaf(tt, fmaf(tt, fmaf(tt, 1.061405429f, -1.453152027f),
                                           1.421413741f), -0.284496736f), 0.254829592f);
  float er = 1.0f - poly * __expf(-ax * ax);
  er = copysignf(er, x);
  return 0.5f * x * (1.0f + er);
}

__device__ __forceinline__ void mfma_bf16(v4f& d, v8s a, v8s b) {
  asm volatile("v_mfma_f32_16x16x32_bf16 %0, %1, %2, %0" : "+v"(d) : "v"(a), "v"(b));
}

// async global->LDS, 16B per lane. LDS dest must be wave-linear (base + lane*16).
__device__ __forceinline__ void async16(const u16* g, u16* l) {
  __builtin_amdgcn_global_load_lds(
      (const __attribute__((address_space(1))) uint32_t*)g,
      (__attribute__((address_space(3))) uint32_t*)l, 16, 0, 0);
}

// ---------------------------------------------------------------------------
// gemm3s: 128x256 tile, BK=64, 512 threads (8 waves 2Mx4N, 64x64 each),
// 3-stage LDS ring (3 x 48KB), 2-tile-ahead staging, counted vmcnt(6),
// ONE barrier per K-tile (no intra-tile lockstep: nothing writes the stage
// being read; slot-reuse hazards are covered by the end-of-tile sync).
// XOR-swizzled LDS both sides.  C = A[M x K] * B^T (B stored [N x K]).
// EPI: 0 = bf16 out; 3 = bf16 gelu(acc + bias); 5 = f32 split partial.
// ---------------------------------------------------------------------------
template <int EPI, int KSPLIT>
__global__ void __launch_bounds__(512, 2)
gemm3s(const u16* __restrict__ A, const u16* __restrict__ B,
       void* __restrict__ Cv, const float* __restrict__ bias,
       int K, int ldc)
{
  extern __shared__ u16 lds[];   // stage s at s*24576: A[128*64] then B[256*64]
  const int t = threadIdx.x;
  const int lane = t & 63;
  const int w = t >> 6;
  const int wm = w >> 2;          // 0..1  (M half, 64 rows)
  const int wn = w & 3;           // 0..3  (N quarter, 64 cols)
  const int tiM = blockIdx.x << 7, tiN = blockIdx.y << 8;
  const int ks = (KSPLIT > 1) ? blockIdx.z : 0;
  const int kchunk = K / KSPLIT;
  const int NT = kchunk >> 6;

  const int rr = lane & 15;
  const int kq = (lane >> 4) << 3;          // 0,8,16,24
  const int swz = (rr & 7) << 3;            // read-side XOR (row&7)*8
  const int c0 = kq ^ swz;                  // ksub 0
  const int c1 = (32 + kq) ^ swz;           // ksub 1

  // staging: thread t covers LDS linear (t*8 + j*4096); row = t>>3 + j*64,
  // linear col (t&7)*8, source col inverse-swizzled by (row&7).
  const int prow = t >> 3;
  const int scol = (((t & 7) ^ (prow & 7)) << 3);
  const u16* Abase = A + (long long)(tiM + prow) * K + scol + (long long)ks * kchunk;
  const u16* Bbase = B + (long long)(tiN + prow) * K + scol + (long long)ks * kchunk;
  const long long r64 = 64LL * K;

  v4f acc[4][4] = {};

  auto stage6 = [&](int s, int kt) {        // 6 loads: 2 A-halves + 4 B-quarters
    const u16* sa = Abase + (long long)kt * 64;
    u16* da = &lds[s * 24576 + t * 8];
    async16(sa, da);
    async16(sa + r64, da + 4096);
    const u16* sb = Bbase + (long long)kt * 64;
    u16* db = &lds[s * 24576 + 8192 + t * 8];
#pragma unroll
    for (int j = 0; j < 4; j++) async16(sb + (long long)j * r64, db + j * 4096);
  };

  // prologue: stage tiles 0 and 1; wait tile 0 (leave tile 1's 6 in flight)
  stage6(0, 0);
  stage6(1, 1);
  asm volatile("s_waitcnt vmcnt(6)" ::: "memory");
  __builtin_amdgcn_s_barrier();

  for (int kt = 0; kt < NT; ++kt) {
    const int s = kt % 3;
    const int sp = (kt + 2) % 3;
    const bool st = (kt + 2 < NT);
    const int ab = s * 24576;
    const int bb = ab + 8192;
    v8s a0[4], a1[4], b0[4], b1[4];
#pragma unroll
    for (int i = 0; i < 4; i++) {
      a0[i] = *(const v8s*)&lds[ab + (wm * 64 + i * 16 + rr) * 64 + c0];
      a1[i] = *(const v8s*)&lds[ab + (wm * 64 + i * 16 + rr) * 64 + c1];
      b0[i] = *(const v8s*)&lds[bb + (wn * 64 + i * 16 + rr) * 64 + c0];
      b1[i] = *(const v8s*)&lds[bb + (wn * 64 + i * 16 + rr) * 64 + c1];
    }
    if (st) stage6(sp, kt + 2);
    __builtin_amdgcn_s_setprio(1);
#pragma unroll
    for (int m = 0; m < 4; m++)
#pragma unroll
      for (int n = 0; n < 4; n++) {
        mfma_bf16(acc[m][n], a0[m], b0[n]);
        mfma_bf16(acc[m][n], a1[m], b1[n]);
      }
    __builtin_amdgcn_s_setprio(0);
    // counted wait: tile t+1 (issued during t-1) landed; t+2's 6 stay in flight
    if (st) asm volatile("s_waitcnt vmcnt(6)" ::: "memory");
    else    asm volatile("s_waitcnt vmcnt(0)" ::: "memory");
    __builtin_amdgcn_s_barrier();
  }

  __builtin_amdgcn_sched_barrier(0);
  asm volatile("s_nop 7\ns_nop 7\ns_nop 7");
  __builtin_amdgcn_sched_barrier(0);

  const int r4 = (lane >> 4) << 2;
  const int cc = lane & 15;
#pragma unroll
  for (int mf = 0; mf < 4; mf++)
#pragma unroll
    for (int nf = 0; nf < 4; nf++)
#pragma unroll
      for (int i = 0; i < 4; i++) {
        int row = tiM + wm * 64 + mf * 16 + r4 + i;
        int col = tiN + wn * 64 + nf * 16 + cc;
        float v = acc[mf][nf][i];
        if (EPI == 0) {
          ((u16*)Cv)[(long long)row * ldc + col] = f2b(v);
        } else if (EPI == 3) {
          ((u16*)Cv)[(long long)row * ldc + col] = f2b(gelu_f(v + bias[col]));
        } else {  // EPI == 5: f32 split partial
          ((float*)Cv)[((long long)ks * ROWS + row) * ldc + col] = v;
        }
      }
}

// FF2 reduce: x += sum of 2 split partials + bias
__global__ void ff2red(const float* __restrict__ part, const float* __restrict__ bias,
                       float* __restrict__ x)
{
  long long i = ((long long)blockIdx.x * 256 + threadIdx.x) * 8;  // 8192*512 floats
  int col = (int)(i & 511);
  v4f s0 = {}, s1 = {};
#pragma unroll
  for (int ks = 0; ks < 2; ks++) {
    const float* p = part + (long long)ks * (ROWS * 512LL) + i;
    s0 += *(const v4f*)p;
    s1 += *(const v4f*)(p + 4);
  }
  v4f b0 = *(const v4f*)(bias + col);
  v4f b1 = *(const v4f*)(bias + col + 4);
  v4f x0 = *(const v4f*)(x + i), x1 = *(const v4f*)(x + i + 4);
  x0 += s0 + b0;
  x1 += s1 + b1;
  *(v4f*)(x + i) = x0;
  *(v4f*)(x + i + 4) = x1;
}

// ---------------------------------------------------------------------------
// gemm2: BM=128, BN in {64,128}.  (attn-path GEMMs)
// EPI: 5 = f32 split-K partial; 6 = f32 dd*scale store + fused global atomicMax
// ---------------------------------------------------------------------------
template <int EPI, int BN, int KSPLIT>
__global__ void __launch_bounds__(256, 4)
gemm2(const u16* __restrict__ A, const u16* __restrict__ B,
      void* __restrict__ Cv, const float* __restrict__ bias,
      int K, int ldc, long long sA, long long sB, long long sC,
      float scale, int Ncap, int Mcap, unsigned int* __restrict__ gmax)
{
  __shared__ u16 As[2][128 * 32];
  __shared__ u16 Bs[2][BN * 32];
  __shared__ float smax[4];
  const int zz = blockIdx.z;
  const int z = (KSPLIT > 1) ? zz / KSPLIT : zz;
  const int ks = (KSPLIT > 1) ? zz % KSPLIT : 0;
  const int kchunk = K / KSPLIT;
  const u16* Ag = A + (long long)z * sA + ks * kchunk;
  const u16* Bg = B + (long long)z * sB + ks * kchunk;
  const int t = threadIdx.x;
  const int lane = t & 63;
  const int w = t >> 6;
  constexpr int NF = BN / 32;
  const int wm = (w >> 1) << 6;
  const int wn = (w & 1) * (BN / 2);
  const int tiM = blockIdx.x << 7, tiN = blockIdx.y * BN;

  const int srow = t >> 2;
  const int scol = (t & 3) << 3;
  const u16* Ap = Ag + (long long)(tiM + srow) * K + scol;
  const u16* Bp = Bg + (long long)(tiN + srow) * K + scol;
  const long long rstride = 64LL * K;

  const int rr = lane & 15;
  const int kc = (lane >> 4) << 3;

  v4f acc[4][NF] = {};

  const int nk = kchunk >> 5;
  auto stage = [&](int buf, int k0) {
    async16(Ap + k0, &As[buf][t * 8]);
    async16(Ap + k0 + rstride, &As[buf][t * 8 + 2048]);
    async16(Bp + k0, &Bs[buf][t * 8]);
    if (BN == 128) async16(Bp + k0 + rstride, &Bs[buf][t * 8 + 2048]);
  };

  stage(0, 0);
  __syncthreads();
  int cur = 0;
  for (int kt = 0; kt < nk; ++kt) {
    if (kt + 1 < nk) stage(cur ^ 1, (kt + 1) << 5);
    v8s af[4], bf[NF];
#pragma unroll
    for (int i = 0; i < 4; i++) af[i] = *(const v8s*)&As[cur][(wm + rr + i * 16) * 32 + kc];
#pragma unroll
    for (int i = 0; i < NF; i++) bf[i] = *(const v8s*)&Bs[cur][(wn + rr + i * 16) * 32 + kc];
#pragma unroll
    for (int fm = 0; fm < 4; fm++)
#pragma unroll
      for (int fn = 0; fn < NF; fn++)
        mfma_bf16(acc[fm][fn], af[fm], bf[fn]);
    __syncthreads();
    cur ^= 1;
  }

  __builtin_amdgcn_sched_barrier(0);
  asm volatile("s_nop 7\ns_nop 7\ns_nop 7");
  __builtin_amdgcn_sched_barrier(0);

  const int r4 = (lane >> 4) << 2;
  const int cc = lane & 15;
  float lmax = -3e38f;
#pragma unroll
  for (int fm = 0; fm < 4; fm++)
#pragma unroll
    for (int fn = 0; fn < NF; fn++)
#pragma unroll
      for (int i = 0; i < 4; i++) {
        int row = tiM + wm + fm * 16 + r4 + i;
        int col = tiN + wn + fn * 16 + cc;
        float v = acc[fm][fn][i];
        if (EPI == 5) {
          if (row < Mcap && col < Ncap)
            ((float*)Cv)[((long long)zz * M_ALLOC + row) * 64 + col] = v;
        } else if (EPI == 6) {
          float sv = v * scale;
          if (col < Ncap) ((float*)Cv)[(long long)row * ldc + col] = sv;
          if (col < M_FEAT) lmax = fmaxf(lmax, sv);
        }
      }

  if (EPI == 6) {
    lmax = wave_max(lmax);
    if (lane == 0) smax[w] = lmax;
    __syncthreads();
    if (t == 0) {
      float m = fmaxf(fmaxf(smax[0], smax[1]), fmaxf(smax[2], smax[3]));
      unsigned int u = __float_as_uint(m);
      unsigned int key = (u & 0x80000000u) ? ~u : (u | 0x80000000u);
      atomicMax(gmax, key);
    }
  }
}

// ---------------------------------------------------------------------------
// gemm_small: BM=64, BN=64, BK=32, high-occupancy variant.
// EPI: 0 bf16; 2 f32 residual += acc + bias; 3 bf16 gelu; 4 head-scatter.
// ---------------------------------------------------------------------------
template <int EPI>
__global__ void __launch_bounds__(256, 6)
gemm_small(const u16* __restrict__ A, const u16* __restrict__ B,
           void* __restrict__ Cv, const float* __restrict__ bias,
           int K, int ldc, long long sA, long long sB)
{
  __shared__ u16 As[2][64 * 32];
  __shared__ u16 Bs[2][64 * 32];
  const int z = blockIdx.z;
  const u16* Ag = A + (long long)z * sA;
  const u16* Bg = B + (long long)z * sB;
  const int t = threadIdx.x;
  const int lane = t & 63;
  const int w = t >> 6;
  const int wm = (w >> 1) << 5;
  const int wn = (w & 1) << 5;
  const int tiM = blockIdx.x << 6, tiN = blockIdx.y << 6;

  const int srow = t >> 2;
  const int scol = (t & 3) << 3;
  const u16* Ap = Ag + (long long)(tiM + srow) * K + scol;
  const u16* Bp = Bg + (long long)(tiN + srow) * K + scol;

  const int rr = lane & 15;
  const int kc = (lane >> 4) << 3;

  v4f acc[2][2] = {};

  const int nk = K >> 5;
  auto stage = [&](int buf, int k0) {
    async16(Ap + k0, &As[buf][t * 8]);
    async16(Bp + k0, &Bs[buf][t * 8]);
  };

  stage(0, 0);
  __syncthreads();
  int cur = 0;
  for (int kt = 0; kt < nk; ++kt) {
    if (kt + 1 < nk) stage(cur ^ 1, (kt + 1) << 5);
    v8s af[2], bf[2];
#pragma unroll
    for (int i = 0; i < 2; i++) af[i] = *(const v8s*)&As[cur][(wm + rr + i * 16) * 32 + kc];
#pragma unroll
    for (int i = 0; i < 2; i++) bf[i] = *(const v8s*)&Bs[cur][(wn + rr + i * 16) * 32 + kc];
#pragma unroll
    for (int fm = 0; fm < 2; fm++)
#pragma unroll
      for (int fn = 0; fn < 2; fn++)
        mfma_bf16(acc[fm][fn], af[fm], bf[fn]);
    __syncthreads();
    cur ^= 1;
  }

  __builtin_amdgcn_sched_barrier(0);
  asm volatile("s_nop 7\ns_nop 7\ns_nop 7");
  __builtin_amdgcn_sched_barrier(0);

  const int r4 = (lane >> 4) << 2;
  const int cc = lane & 15;
#pragma unroll
  for (int fm = 0; fm < 2; fm++)
#pragma unroll
    for (int fn = 0; fn < 2; fn++)
#pragma unroll
      for (int i = 0; i < 4; i++) {
        int row = tiM + wm + fm * 16 + r4 + i;
        int col = tiN + wn + fn * 16 + cc;
        float v = acc[fm][fn][i];
        if (EPI == 0) {
          ((u16*)Cv)[(long long)row * ldc + col] = f2b(v);
        } else if (EPI == 2) {
          long long idx = (long long)row * ldc + col;
          float bb = bias ? bias[col] : 0.0f;
          ((float*)Cv)[idx] += v + bb;
        } else if (EPI == 3) {
          ((u16*)Cv)[(long long)row * ldc + col] = f2b(gelu_f(v + bias[col]));
        } else {  // EPI == 4: head scatter (N=64 per z)
          int b_ = z >> 3, h_ = z & 7;
          ((u16*)Cv)[(long long)(b_ * N_SEQ + row) * 512 + h_ * 64 + col] = f2b(v);
        }
      }
}

// ---------------------------------------------------------------------------
// Fused dd_q -> row-max -> exp -> denominator -> qf (bf16, d_inv folded).
// 384 threads = 6 waves x 48 cols = 288; cooperative cross-wave reduces.
// ---------------------------------------------------------------------------
__global__ void __launch_bounds__(384, 3)
ddq_qf(const u16* __restrict__ qr, const u16* __restrict__ proj,
       const float* __restrict__ diag, const float* __restrict__ ksum,
       u16* __restrict__ qf)
{
  __shared__ u16 As[2][64 * 32];
  __shared__ u16 Bs[2][288 * 32];
  __shared__ float redw[6][64];
  __shared__ float rowv[64];
  __shared__ float sdg[64];
  const int bh = blockIdx.z;
  const int tiM = blockIdx.x << 6;
  const int t = threadIdx.x;
  const int lane = t & 63;
  const int w = t >> 6;          // 0..5
  const u16* Ag = qr + (long long)bh * (N_SEQ * 64);
  const int srow = t >> 2, scol = (t & 3) << 3;
  const u16* Ap = Ag + (long long)(tiM + srow) * 64 + scol;
  const int rr = lane & 15, kc = (lane >> 4) << 3;
  const int wn = w * 48;

  if (t < 64) sdg[t] = diag[(long long)bh * N_SEQ + tiM + t];

  v4f acc[4][3] = {};
  auto stage = [&](int buf, int k0) {
    if (t < 256) async16(Ap + k0, &As[buf][t * 8]);
#pragma unroll
    for (int j = 0; j < 3; j++) {
      int idx = j * 384 + t;
      async16(proj + (long long)(idx >> 2) * 64 + ((idx & 3) << 3) + k0,
              &Bs[buf][j * 3072 + t * 8]);
    }
  };

  stage(0, 0);
  __syncthreads();
  for (int kt = 0; kt < 2; ++kt) {
    if (kt == 0) stage(1, 32);
    v8s af[4], bf[3];
#pragma unroll
    for (int i = 0; i < 4; i++) af[i] = *(const v8s*)&As[kt][(rr + i * 16) * 32 + kc];
#pragma unroll
    for (int i = 0; i < 3; i++) bf[i] = *(const v8s*)&Bs[kt][(wn + i * 16 + rr) * 32 + kc];
#pragma unroll
    for (int fm = 0; fm < 4; fm++)
#pragma unroll
      for (int fn = 0; fn < 3; fn++)
        mfma_bf16(acc[fm][fn], af[fm], bf[fn]);
    __syncthreads();
  }

  __builtin_amdgcn_sched_barrier(0);
  asm volatile("s_nop 7\ns_nop 7\ns_nop 7");
  __builtin_amdgcn_sched_barrier(0);

  const int r4 = (lane >> 4) << 2;
  const int cc = lane & 15;
  const float sc = 0.35355339f;

  // phase A: per-wave row max over its 48 cols (valid cols only)
#pragma unroll
  for (int fm = 0; fm < 4; fm++)
#pragma unroll
    for (int i = 0; i < 4; i++) {
      float m = -3e38f;
#pragma unroll
      for (int fn = 0; fn < 3; fn++) {
        int col = wn + fn * 16 + cc;
        float v = acc[fm][fn][i] * sc;
        if (col < M_FEAT) m = fmaxf(m, v);
      }
#pragma unroll
      for (int o = 1; o < 16; o <<= 1) m = fmaxf(m, __shfl_xor(m, o));
      if (cc == 0) redw[w][fm * 16 + r4 + i] = m;
    }
  __syncthreads();
  if (t < 64) {
    float g = redw[0][t];
#pragma unroll
    for (int ww = 1; ww < 6; ww++) g = fmaxf(g, redw[ww][t]);
    rowv[t] = g;
  }
  __syncthreads();

  // phase B: e = ratio*(exp(dd-diag-gm)+eps); per-wave dot with ksum
  float ksv[3];
#pragma unroll
  for (int fn = 0; fn < 3; fn++) ksv[fn] = ksum[bh * M_PAD + wn + fn * 16 + cc];

#pragma unroll
  for (int fm = 0; fm < 4; fm++)
#pragma unroll
    for (int i = 0; i < 4; i++) {
      int row = fm * 16 + r4 + i;
      float gm = rowv[row];
      float dg = sdg[row];
      float s = 0.0f;
#pragma unroll
      for (int fn = 0; fn < 3; fn++) {
        float e = 0.06131389f * (expf(acc[fm][fn][i] * sc - dg - gm) + 1e-4f);
        acc[fm][fn][i] = e;
        s += e * ksv[fn];
      }
#pragma unroll
      for (int o = 1; o < 16; o <<= 1) s += __shfl_xor(s, o);
      if (cc == 0) redw[w][row] = s;
    }
  __syncthreads();
  if (t < 64) {
    float s = redw[0][t];
#pragma unroll
    for (int ww = 1; ww < 6; ww++) s += redw[ww][t];
    rowv[t] = 1.0f / s;
  }
  __syncthreads();

  // phase C: write qf * dinv (cols 266..287 garbage x ctx=0 — inert)
#pragma unroll
  for (int fm = 0; fm < 4; fm++)
#pragma unroll
    for (int i = 0; i < 4; i++) {
      int row = fm * 16 + r4 + i;
      float dinv = rowv[row];
#pragma unroll
      for (int fn = 0; fn < 3; fn++) {
        int col = wn + fn * 16 + cc;
        qf[((long long)bh * N_SEQ + tiM + row) * M_PAD + col] =
            f2b(acc[fm][fn][i] * dinv);
      }
    }
}

// ---------------------------------------------------------------------------
template <bool F32OUT>
__global__ void ln_kernel(const float* __restrict__ x, const float* __restrict__ g,
                          const float* __restrict__ b, void* __restrict__ out)
{
  const int row = blockIdx.x * 4 + (threadIdx.x >> 6);
  const int lane = threadIdx.x & 63;
  const float* xr = x + (long long)row * D_MODEL + lane * 8;
  v4f v0 = *(const v4f*)xr;
  v4f v1 = *(const v4f*)(xr + 4);
  float s = v0[0] + v0[1] + v0[2] + v0[3] + v1[0] + v1[1] + v1[2] + v1[3];
  float sq = v0[0]*v0[0] + v0[1]*v0[1] + v0[2]*v0[2] + v0[3]*v0[3]
           + v1[0]*v1[0] + v1[1]*v1[1] + v1[2]*v1[2] + v1[3]*v1[3];
  s = wave_sum(s);
  sq = wave_sum(sq);
  float mu = s * (1.0f / D_MODEL);
  float var = sq * (1.0f / D_MODEL) - mu * mu;
  float rstd = rsqrtf(var + 1e-5f);
  v4f g0 = *(const v4f*)(g + lane * 8), g1 = *(const v4f*)(g + lane * 8 + 4);
  v4f bb0 = *(const v4f*)(b + lane * 8), bb1 = *(const v4f*)(b + lane * 8 + 4);
  float y[8];
#pragma unroll
  for (int j = 0; j < 4; j++) y[j] = (v0[j] - mu) * rstd * g0[j] + bb0[j];
#pragma unroll
  for (int j = 0; j < 4; j++) y[4 + j] = (v1[j] - mu) * rstd * g1[j] + bb1[j];
  if (F32OUT) {
    float* op = (float*)out + (long long)row * D_MODEL + lane * 8;
    v4f o0 = {y[0], y[1], y[2], y[3]}, o1 = {y[4], y[5], y[6], y[7]};
    *(v4f*)op = o0;
    *(v4f*)(op + 4) = o1;
  } else {
    u16* op = (u16*)out + (long long)row * D_MODEL + lane * 8;
    alignas(16) u16 tmp[8];
#pragma unroll
    for (int j = 0; j < 8; j++) tmp[j] = f2b(y[j]);
    *(v8s*)op = *(v8s*)tmp;
  }
}

__global__ void posadd(const float* __restrict__ xin, float* __restrict__ x)
{
  long long i = (long long)blockIdx.x * 256 + threadIdx.x;
  int d = (int)(i & 511);
  int n = (int)((i >> 9) & 2047);
  int j = d & 255;
  float sarg = (float)n * expf(-0.035977892f * (float)j);
  float pe = (d < 256) ? sinf(sarg) : cosf(sarg);
  x[i] = xin[i] + pe;
}

__global__ void rotab(float* __restrict__ ts, float* __restrict__ tc)
{
  int i = blockIdx.x * 64 + threadIdx.x;  // 2048*32
  int n = i >> 5, j = i & 31;
  float sarg = (float)n * expf(-0.28782314f * (float)j);
  float s, c;
  sincosf(sarg, &s, &c);
  ts[i] = s;
  tc[i] = c;
}

__global__ void rotary_kernel(const u16* __restrict__ qkv,
                              const float* __restrict__ ts, const float* __restrict__ tc,
                              u16* __restrict__ qr, u16* __restrict__ kr,
                              float* __restrict__ dq, float* __restrict__ dk)
{
  int bid = blockIdx.x * 4 + (threadIdx.x >> 6);
  int n = bid & 2047;
  int h = (bid >> 11) & 7;
  int b = bid >> 14;
  int lane = threadIdx.x & 63;
  long long src = ((long long)(b * N_SEQ + n)) * 1536 + h * 64 + lane;
  float qv = b2f(qkv[src]);
  float kv = b2f(qkv[src + 512]);
  int j = lane >> 1;
  float sn = ts[n * 32 + j], cn = tc[n * 32 + j];
  float qp = __shfl_xor(qv, 1), kp = __shfl_xor(kv, 1);
  float qrv = (lane & 1) ? (qv * cn + qp * sn) : (qv * cn - qp * sn);
  float krv = (lane & 1) ? (kv * cn + kp * sn) : (kv * cn - kp * sn);
  u16 qb = f2b(qrv), kb = f2b(krv);
  long long dst = ((long long)bid) * 64 + lane;
  qr[dst] = qb;
  kr[dst] = kb;
  float q2 = b2f(qb); q2 *= q2;
  float k2 = b2f(kb); k2 *= k2;
  q2 = wave_sum(q2);
  k2 = wave_sum(k2);
  if (lane == 0) { dq[bid] = q2 * 0.0625f; dk[bid] = k2 * 0.0625f; }
}

__global__ void vtrans(const u16* __restrict__ qkv, u16* __restrict__ vT)
{
  int bid = blockIdx.x;  // B*H*32
  int nt = bid & 31;
  int h = (bid >> 5) & 7;
  int b = bid >> 8;
  __shared__ u16 st[64][72];
  int t = threadIdx.x;
  int r = t >> 2, c = (t & 3) << 4;
  long long src = ((long long)(b * N_SEQ + nt * 64 + r)) * 1536 + 1024 + h * 64 + c;
  *(v8s*)&st[r][c] = *(const v8s*)(qkv + src);
  *(v8s*)&st[r][c + 8] = *(const v8s*)(qkv + src + 8);
  __syncthreads();
  alignas(16) u16 tmp[16];
#pragma unroll
  for (int jj = 0; jj < 16; jj++) tmp[jj] = st[c + jj][r];
  long long dst = ((long long)((b * 8 + h) * 64 + r)) * N_SEQ + nt * 64 + c;
  *(v8s*)(vT + dst) = *(v8s*)&tmp[0];
  *(v8s*)(vT + dst + 8) = *(v8s*)&tmp[8];
}

__global__ void wtrans(const float* __restrict__ src, u16* __restrict__ dst,
                       int Ks, int Ns, long long sSrc, long long sDst)
{
  int l = blockIdx.z;
  src += (long long)l * sSrc;
  dst += (long long)l * sDst;
  int n0 = blockIdx.x << 6, k0 = blockIdx.y << 6;
  __shared__ float st[64][68];
  int t = threadIdx.x;
  int r = t >> 2, c = (t & 3) << 4;
  const float* sp = src + (long long)(k0 + r) * Ns + n0 + c;
#pragma unroll
  for (int jj = 0; jj < 16; jj += 4) *(v4f*)&st[r][c + jj] = *(const v4f*)(sp + jj);
  __syncthreads();
  alignas(16) u16 tmp[16];
#pragma unroll
  for (int jj = 0; jj < 16; jj++) tmp[jj] = f2b(st[c + jj][r]);
  u16* dp = dst + (long long)(n0 + r) * Ks + k0 + c;
  *(v8s*)(dp) = *(v8s*)&tmp[0];
  *(v8s*)(dp + 8) = *(v8s*)&tmp[8];
}

__global__ void projconv(const float* __restrict__ proj, u16* __restrict__ out)
{
  int i = blockIdx.x * 256 + threadIdx.x;  // 6*384*64
  int dh = i & 63;
  int m = (i >> 6) % M_ALLOC;
  int l = i / (M_ALLOC * 64);
  float v = (m < M_FEAT) ? proj[((long long)l * M_FEAT + m) * 64 + dh] : 0.0f;
  out[i] = f2b(v);
}

__global__ void resetmax(unsigned int* p) { *p = 0u; }

// ---------------------------------------------------------------------------
// kfprep: dd_k (bh,n,288) f32 -> kfT (bh,384,2048) bf16 + per-tile ksum partials.
// ---------------------------------------------------------------------------
__global__ void kfprep(const float* __restrict__ dd, const float* __restrict__ diag,
                       const unsigned int* __restrict__ kmax,
                       u16* __restrict__ kfT, float* __restrict__ part)
{
  int ntile = blockIdx.x;          // 32
  int m0 = blockIdx.y << 6;        // 5 tiles (0..319, cap 288)
  int bh = blockIdx.z;             // 32
  int n0 = ntile << 6;
  __shared__ float st[64][65];
  unsigned int kk = kmax[0];
  float km = (kk & 0x80000000u) ? __uint_as_float(kk ^ 0x80000000u)
                                : __uint_as_float(~kk);
  int t = threadIdx.x;
  int r = t >> 2, c = (t & 3) << 4;
  const float* dp = dd + ((long long)bh * N_SEQ + n0 + r) * M_PAD + m0 + c;
  float dg = diag[(long long)bh * N_SEQ + n0 + r];
  float vals[16];
  if (m0 + c + 16 <= M_PAD) {
#pragma unroll
    for (int j = 0; j < 16; j += 4) *(v4f*)&vals[j] = *(const v4f*)(dp + j);
  } else {
#pragma unroll
    for (int j = 0; j < 16; j++) vals[j] = (m0 + c + j < M_PAD) ? dp[j] : 0.0f;
  }
#pragma unroll
  for (int j = 0; j < 16; j++) {
    int m = m0 + c + j;
    float e = (m < M_FEAT) ? 0.06131389f * (expf(vals[j] - dg - km) + 1e-4f) : 0.0f;
    st[r][c + j] = e;
  }
  __syncthreads();
  int mr = t >> 2, nc = (t & 3) << 4;
  float s = 0.0f;
  alignas(16) u16 tmp[16];
#pragma unroll
  for (int j = 0; j < 16; j++) {
    float e = st[nc + j][mr];
    s += e;
    tmp[j] = f2b(e);
  }
  s += __shfl_xor(s, 1);
  s += __shfl_xor(s, 2);
  int m = m0 + mr;
  if (m < M_PAD) {
    u16* op = kfT + ((long long)bh * M_ALLOC + m) * N_SEQ + n0 + nc;
    *(v8s*)op = *(v8s*)&tmp[0];
    *(v8s*)(op + 8) = *(v8s*)&tmp[8];
    if ((t & 3) == 0)
      part[((long long)bh * M_PAD + m) * 32 + ntile] = s;
  }
}

__global__ void ksumred(const float* __restrict__ part, float* __restrict__ ksum)
{
  int i = blockIdx.x * 256 + threadIdx.x;  // 32*288
  if (i >= 32 * M_PAD) return;
  const float* p = part + (long long)i * 32;
  float s = 0.0f;
#pragma unroll
  for (int j = 0; j < 32; j += 4) {
    v4f v = *(const v4f*)(p + j);
    s += v[0] + v[1] + v[2] + v[3];
  }
  ksum[i] = s;
}

// reduce split-K ctx partials (8) + transpose -> ctxT (bh,64,288) bf16
__global__ void ctxred(const float* __restrict__ part, u16* __restrict__ ctxT)
{
  int bh = blockIdx.y;
  int m0 = blockIdx.x << 6;   // 5 tiles
  __shared__ float st[64][65];
  int t = threadIdx.x;
  int r = t >> 2, c = (t & 3) << 4;
  int m = m0 + r;
  v4f s[4] = {};
  if (m < M_PAD) {
    for (int ks = 0; ks < 8; ks++) {
      const float* p = part + (((long long)bh * 8 + ks) * M_ALLOC + m) * 64 + c;
#pragma unroll
      for (int j = 0; j < 4; j++) s[j] += *(const v4f*)(p + j * 4);
    }
  }
#pragma unroll
  for (int j = 0; j < 4; j++)
#pragma unroll
    for (int e = 0; e < 4; e++) st[r][c + j * 4 + e] = s[j][e];
  __syncthreads();
  int e = t >> 2, mc = (t & 3) << 4;
  if (m0 + mc < M_PAD) {
    alignas(16) u16 tmp[16];
#pragma unroll
    for (int j = 0; j < 16; j++) tmp[j] = f2b(st[mc + j][e]);
    u16* op = ctxT + ((long long)bh * 64 + e) * M_PAD + m0 + mc;
    *(v8s*)op = *(v8s*)&tmp[0];
    *(v8s*)(op + 8) = *(v8s*)&tmp[8];
  }
}

// ---------------------------------------------------------------------------
extern "C" void kernel_launch(void* const* d_in, const int* in_sizes, int n_in,
                              void* d_out, int out_size, void* d_ws, size_t ws_size,
                              hipStream_t stream)
{
  const float* x_in = (const float*)d_in[0];
  const float* Wq  = (const float*)d_in[1];
  const float* Wk  = (const float*)d_in[2];
  const float* Wv  = (const float*)d_in[3];
  const float* Wo  = (const float*)d_in[4];
  const float* Pr  = (const float*)d_in[5];
  const float* ln1g = (const float*)d_in[6];
  const float* ln1b = (const float*)d_in[7];
  const float* W1  = (const float*)d_in[8];
  const float* b1  = (const float*)d_in[9];
  const float* W2  = (const float*)d_in[10];
  const float* b2  = (const float*)d_in[11];
  const float* ln2g = (const float*)d_in[12];
  const float* ln2b = (const float*)d_in[13];
  const float* lnfg = (const float*)d_in[14];
  const float* lnfb = (const float*)d_in[15];

  // allow 144 KiB dynamic LDS for the 3-stage GEMMs
  hipFuncSetAttribute(reinterpret_cast<const void*>(&gemm3s<0, 1>),
                      hipFuncAttributeMaxDynamicSharedMemorySize, 147456);
  hipFuncSetAttribute(reinterpret_cast<const void*>(&gemm3s<3, 1>),
                      hipFuncAttributeMaxDynamicSharedMemorySize, 147456);
  hipFuncSetAttribute(reinterpret_cast<const void*>(&gemm3s<5, 2>),
                      hipFuncAttributeMaxDynamicSharedMemorySize, 147456);

  char* ws = (char*)d_ws;
  size_t off = 0;
  auto alloc = [&](size_t bytes) -> void* {
    void* p = ws + off;
    off = (off + bytes + 255) & ~(size_t)255;
    return p;
  };

  float* x      = (float*)alloc((size_t)ROWS * D_MODEL * 4);
  float* tsin   = (float*)alloc((size_t)N_SEQ * 32 * 4);
  float* tcos   = (float*)alloc((size_t)N_SEQ * 32 * 4);
  u16*   wqkvT  = (u16*)alloc((size_t)N_LAYER * 1536 * 512 * 2);
  u16*   woT    = (u16*)alloc((size_t)N_LAYER * 512 * 512 * 2);
  u16*   w1T    = (u16*)alloc((size_t)N_LAYER * 2048 * 512 * 2);
  u16*   w2T    = (u16*)alloc((size_t)N_LAYER * 512 * 2048 * 2);
  u16*   projT  = (u16*)alloc((size_t)N_LAYER * M_ALLOC * 64 * 2);
  u16*   hbuf   = (u16*)alloc((size_t)ROWS * D_MODEL * 2);
  u16*   obuf   = (u16*)alloc((size_t)ROWS * D_MODEL * 2);
  float* big    = (float*)alloc((size_t)32 * N_SEQ * M_PAD * 4);   // qkv_pre bf16 / dd f32
  u16*   qrbuf  = (u16*)alloc((size_t)BHN * 64 * 2);
  u16*   krbuf  = (u16*)alloc((size_t)BHN * 64 * 2);
  u16*   vTbuf  = (u16*)alloc((size_t)BHN * 64 * 2);
  float* diagq  = (float*)alloc((size_t)BHN * 4);
  float* diagk  = (float*)alloc((size_t)BHN * 4);
  unsigned int* kmaxu = (unsigned int*)alloc(256);
  u16*   kfT    = (u16*)alloc((size_t)32 * M_ALLOC * N_SEQ * 2);   // also qf buffer
  float* part   = (float*)alloc((size_t)32 * 8 * M_ALLOC * 64 * 4);
  float* kspart = (float*)alloc((size_t)32 * M_PAD * 32 * 4);
  u16*   ctxT   = (u16*)alloc((size_t)32 * 64 * M_PAD * 2);
  float* ksum   = (float*)alloc((size_t)32 * M_PAD * 4);
  (void)alloc(1 << 20);  // guard region for benign OOB tile reads
  (void)ws_size; (void)in_sizes; (void)n_in; (void)out_size;
  // FF2 split-K partials (2 x 16 MB) alias kfT+part: qf/ctx partials are dead
  // by FF2 time each layer, and both regions are rewritten next layer.
  float* ff2part = (float*)kfT;

  // ---- setup ----
  posadd<<<16384, 256, 0, stream>>>(x_in, x);
  rotab<<<1024, 64, 0, stream>>>(tsin, tcos);
  wtrans<<<dim3(8, 8, 6), 256, 0, stream>>>(Wq, wqkvT, 512, 512, 512LL * 512, 1536LL * 512);
  wtrans<<<dim3(8, 8, 6), 256, 0, stream>>>(Wk, wqkvT + 512LL * 512, 512, 512, 512LL * 512, 1536LL * 512);
  wtrans<<<dim3(8, 8, 6), 256, 0, stream>>>(Wv, wqkvT + 1024LL * 512, 512, 512, 512LL * 512, 1536LL * 512);
  wtrans<<<dim3(8, 8, 6), 256, 0, stream>>>(Wo, woT, 512, 512, 512LL * 512, 512LL * 512);
  wtrans<<<dim3(32, 8, 6), 256, 0, stream>>>(W1, w1T, 512, 2048, 512LL * 2048, 2048LL * 512);
  wtrans<<<dim3(8, 32, 6), 256, 0, stream>>>(W2, w2T, 2048, 512, 2048LL * 512, 512LL * 2048);
  projconv<<<(N_LAYER * M_ALLOC * 64) / 256, 256, 0, stream>>>(Pr, projT);

  for (int l = 0; l < N_LAYER; l++) {
    const u16* wq = wqkvT + (long long)l * 1536 * 512;
    const u16* wo = woT + (long long)l * 512 * 512;
    const u16* w1 = w1T + (long long)l * 2048 * 512;
    const u16* w2 = w2T + (long long)l * 512 * 2048;
    const u16* pj = projT + (long long)l * M_ALLOC * 64;

    resetmax<<<1, 1, 0, stream>>>(kmaxu);
    // LN1 -> h
    ln_kernel<false><<<ROWS / 4, 256, 0, stream>>>(x, ln1g + l * 512, ln1b + l * 512, hbuf);
    // qkv_pre = h @ Wqkv^T  (8192 x 1536, K=512)  [3-stage 128x256]
    gemm3s<0, 1><<<dim3(64, 6), 512, 147456, stream>>>(hbuf, wq, big, nullptr, 512, 1536);
    rotary_kernel<<<BHN / 4, 256, 0, stream>>>((u16*)big, tsin, tcos, qrbuf, krbuf, diagq, diagk);
    vtrans<<<1024, 256, 0, stream>>>((u16*)big, vTbuf);
    // dd_k (65536 x 288, K=64) + fused global max
    gemm2<6, 128, 1><<<dim3(512, 3, 1), 256, 0, stream>>>(krbuf, pj, big, nullptr,
        64, M_PAD, 0, 0, 0, 0.35355339f, M_PAD, BHN, kmaxu);
    // kf^T + ksum partials
    kfprep<<<dim3(32, 5, 32), 256, 0, stream>>>(big, diagk, kmaxu, kfT, kspart);
    ksumred<<<(32 * M_PAD + 255) / 256, 256, 0, stream>>>(kspart, ksum);
    // ctx = kf^T @ v  split-K=8
    gemm2<5, 64, 8><<<dim3(3, 1, 256), 256, 0, stream>>>(kfT, vTbuf, part, nullptr,
        2048, 64, (long long)M_ALLOC * N_SEQ, 64LL * N_SEQ, 0, 1.0f, 64, M_PAD, nullptr);
    ctxred<<<dim3(5, 32), 256, 0, stream>>>(part, ctxT);
    // fused dd_q -> qf
    ddq_qf<<<dim3(32, 1, 32), 384, 0, stream>>>(qrbuf, pj, diagq, ksum, kfT);
    // o = qf @ ctx^T -> head scatter
    gemm_small<4><<<dim3(32, 1, 32), 256, 0, stream>>>(kfT, ctxT, obuf, nullptr,
        M_PAD, 0, (long long)N_SEQ * M_PAD, 64LL * M_PAD);
    // x += o @ Wo^T
    gemm_small<2><<<dim3(128, 8, 1), 256, 0, stream>>>(obuf, wo, x, nullptr,
        512, 512, 0, 0);
    // LN2 -> h
    ln_kernel<false><<<ROWS / 4, 256, 0, stream>>>(x, ln2g + l * 512, ln2b + l * 512, hbuf);
    // ff = gelu(h @ W1^T + b1)  [3-stage 128x256]
    gemm3s<3, 1><<<dim3(64, 8), 512, 147456, stream>>>(hbuf, w1, big, b1 + (long long)l * 2048,
        512, 2048);
    // ff2 partials = ff @ W2^T  [3-stage 128x256, split-K=2]
    gemm3s<5, 2><<<dim3(64, 2, 2), 512, 147456, stream>>>((u16*)big, w2, ff2part, nullptr,
        2048, 512);
    // x += sum(partials) + b2
    ff2red<<<2048, 256, 0, stream>>>(ff2part, b2 + (long long)l * 512, x);
  }

  ln_kernel<true><<<ROWS / 4, 256, 0, stream>>>(x, lnfg, lnfb, d_out);
}